// Round 1
// baseline (5560.426 us; speedup 1.0000x reference)
//
#include <hip/hip_runtime.h>
#include <math.h>

// Problem constants (fixed by setup_inputs)
constexpr int NB = 8;        // batch
constexpr int NS = 1024;     // seq
constexpr int ND = 1024;     // d_model
constexpr int NIN = 256;     // n_input
constexpr int NPROC = 512;   // n_process
constexpr int KIN = 128;     // k_input
constexpr int KPROC = 256;   // k_process

__device__ inline float gelu_f(float x) {
    return 0.5f * x * (1.0f + erff(x * 0.7071067811865476f));
}

// ---------------------------------------------------------------------------
// Generic tiled fp32 GEMM: C[b] = act(A[b] @ op(B[b]) + bias) + resid[b]
// A: [M,K] row-major (lda). transB=1: B is [N,K] (W layout, C=A@W^T).
// transB=0: B is [K,N]. act: 0 none, 1 gelu.
// ---------------------------------------------------------------------------
__global__ __launch_bounds__(256)
void gemm_kernel(const float* __restrict__ A, long sA, int lda,
                 const float* __restrict__ Bm, long sB, int ldb, int transB,
                 const float* __restrict__ bias,
                 const float* __restrict__ resid, long sR, int ldr,
                 float* __restrict__ C, long sC, int ldc,
                 int M, int N, int K, int act)
{
    __shared__ float As[16][68];
    __shared__ float Bs[16][68];
    int bz = blockIdx.z;
    const float* Ab = A + (long)bz * sA;
    const float* Bb = Bm + (long)bz * sB;
    float* Cb = C + (long)bz * sC;
    int row0 = blockIdx.y * 64, col0 = blockIdx.x * 64;
    int t = threadIdx.x;
    int tx = t & 15, ty = t >> 4;
    float acc[4][4];
#pragma unroll
    for (int i = 0; i < 4; ++i)
#pragma unroll
        for (int j = 0; j < 4; ++j) acc[i][j] = 0.f;

    for (int k0 = 0; k0 < K; k0 += 16) {
#pragma unroll
        for (int l = 0; l < 4; ++l) {
            int idx = t + l * 256;
            int r = idx >> 4, c = idx & 15;
            int gr = row0 + r;
            As[c][r] = (gr < M) ? Ab[(long)gr * lda + (k0 + c)] : 0.f;
        }
        if (transB) {
#pragma unroll
            for (int l = 0; l < 4; ++l) {
                int idx = t + l * 256;
                int r = idx >> 4, c = idx & 15;
                int gn = col0 + r;
                Bs[c][r] = (gn < N) ? Bb[(long)gn * ldb + (k0 + c)] : 0.f;
            }
        } else {
#pragma unroll
            for (int l = 0; l < 4; ++l) {
                int idx = t + l * 256;
                int kk = idx >> 6, n = idx & 63;
                int gn = col0 + n;
                Bs[kk][n] = (gn < N) ? Bb[(long)(k0 + kk) * ldb + gn] : 0.f;
            }
        }
        __syncthreads();
#pragma unroll
        for (int kk = 0; kk < 16; ++kk) {
            float4 a4 = *(const float4*)&As[kk][ty * 4];
            float4 b4 = *(const float4*)&Bs[kk][tx * 4];
            float a[4] = {a4.x, a4.y, a4.z, a4.w};
            float b[4] = {b4.x, b4.y, b4.z, b4.w};
#pragma unroll
            for (int i = 0; i < 4; ++i)
#pragma unroll
                for (int j = 0; j < 4; ++j) acc[i][j] += a[i] * b[j];
        }
        __syncthreads();
    }

#pragma unroll
    for (int i = 0; i < 4; ++i) {
        int row = row0 + ty * 4 + i;
        if (row >= M) continue;
#pragma unroll
        for (int j = 0; j < 4; ++j) {
            int col = col0 + tx * 4 + j;
            if (col >= N) continue;
            float v = acc[i][j];
            if (bias) v += bias[col];
            if (act == 1) v = gelu_f(v);
            if (resid) v += resid[(long)bz * sR + (long)row * ldr + col];
            Cb[(long)row * ldc + col] = v;
        }
    }
}

// ---------------------------------------------------------------------------
// Self-attention over a packed qkv buffer [B*S, stride]; q at col 0, k at
// koff, v at voff (per-head slice h*DH). Output written over the q slots.
// One block = (b, h, 8 q-rows). 256 threads.
// ---------------------------------------------------------------------------
template <int DH, int TQ>
__global__ __launch_bounds__(256)
void attn_kernel(float* __restrict__ qkv, int stride, int koff, int voff, float scale)
{
    constexpr int NSL = 256 / DH;
    int b = blockIdx.z, h = blockIdx.y;
    int q0 = blockIdx.x * TQ;
    int t = threadIdx.x;
    __shared__ float qs[TQ][DH];
    __shared__ float p[TQ][NS];
    __shared__ float red[256];
    long hbase = ((long)b * NS) * stride + (long)h * DH;

    for (int i = t; i < TQ * DH; i += 256) {
        int r = i / DH, d = i % DH;
        qs[r][d] = qkv[hbase + (long)(q0 + r) * stride + d];
    }
    __syncthreads();

    // phase 1: scores for 4 k-positions per thread, all TQ rows
    float lmax[TQ];
#pragma unroll
    for (int r = 0; r < TQ; ++r) lmax[r] = -INFINITY;
    for (int k = t; k < NS; k += 256) {
        const float* krow = qkv + hbase + (long)k * stride + koff;
        float sacc[TQ];
#pragma unroll
        for (int r = 0; r < TQ; ++r) sacc[r] = 0.f;
        for (int d0 = 0; d0 < DH; d0 += 4) {
            float4 kv = *(const float4*)&krow[d0];
#pragma unroll
            for (int r = 0; r < TQ; ++r) {
                float4 qv = *(const float4*)&qs[r][d0];
                sacc[r] += qv.x * kv.x + qv.y * kv.y + qv.z * kv.z + qv.w * kv.w;
            }
        }
#pragma unroll
        for (int r = 0; r < TQ; ++r) {
            float v = sacc[r] * scale;
            p[r][k] = v;
            lmax[r] = fmaxf(lmax[r], v);
        }
    }

    // softmax per row (max, exp, sum)
    float Z[TQ];
#pragma unroll
    for (int r = 0; r < TQ; ++r) {
        __syncthreads();
        red[t] = lmax[r];
        __syncthreads();
        for (int off = 128; off; off >>= 1) {
            if (t < off) red[t] = fmaxf(red[t], red[t + off]);
            __syncthreads();
        }
        float mx = red[0];
        float ls = 0.f;
        for (int k = t; k < NS; k += 256) {
            float e = expf(p[r][k] - mx);
            p[r][k] = e;
            ls += e;
        }
        __syncthreads();
        red[t] = ls;
        __syncthreads();
        for (int off = 128; off; off >>= 1) {
            if (t < off) red[t] += red[t + off];
            __syncthreads();
        }
        Z[r] = red[0];
    }

    // phase 2: out[r, d] = sum_k p[r,k] * V[k,d]
    int d = t % DH, sl = t / DH;
    float oacc[TQ];
#pragma unroll
    for (int r = 0; r < TQ; ++r) oacc[r] = 0.f;
    for (int k = sl; k < NS; k += NSL) {
        float vv = qkv[hbase + (long)k * stride + voff + d];
#pragma unroll
        for (int r = 0; r < TQ; ++r) oacc[r] += p[r][k] * vv;
    }
#pragma unroll
    for (int r = 0; r < TQ; ++r) {
        __syncthreads();
        red[t] = oacc[r];
        __syncthreads();
        if (t < DH) {
            float o = red[t];
#pragma unroll
            for (int s2 = 1; s2 < NSL; ++s2) o += red[s2 * DH + t];
            qkv[hbase + (long)(q0 + r) * stride + t] = o / Z[r];
        }
    }
}

// ---------------------------------------------------------------------------
// scores[b,n] = max over s of affinity[b,s,n]. One block per b, 1024 threads.
// ---------------------------------------------------------------------------
__global__ __launch_bounds__(1024)
void rowmax_kernel(const float* __restrict__ aff, float* __restrict__ scores)
{
    int b = blockIdx.x, t = threadIdx.x;
    int n = t & 255, sc = t >> 8;  // 4 s-chunks of 256
    float m = -INFINITY;
    for (int s = sc * 256; s < (sc + 1) * 256; ++s)
        m = fmaxf(m, aff[((long)(b * NS + s)) * NIN + n]);
    __shared__ float pm[1024];
    pm[t] = m;
    __syncthreads();
    if (t < 256) {
        float mm = fmaxf(fmaxf(pm[t], pm[t + 256]), fmaxf(pm[t + 512], pm[t + 768]));
        scores[b * NIN + t] = mm;
    }
}

// ---------------------------------------------------------------------------
// top-128 of 256 logits + routing weights. One block per b, 256 threads.
// ---------------------------------------------------------------------------
__global__ __launch_bounds__(256)
void topk_input_kernel(const float* __restrict__ scores, int* __restrict__ idx_out,
                       float* __restrict__ w_out)
{
    int b = blockIdx.x, t = threadIdx.x;
    __shared__ float soft[256], work[256], rv[256];
    __shared__ int ri[256], sel[KIN];
    float l = scores[b * 256 + t] * 0.5f;  // /TEMP
    work[t] = l;
    rv[t] = l;
    __syncthreads();
    for (int off = 128; off; off >>= 1) {
        if (t < off) rv[t] = fmaxf(rv[t], rv[t + off]);
        __syncthreads();
    }
    float mx = rv[0];
    __syncthreads();
    float e = expf(l - mx);
    rv[t] = e;
    __syncthreads();
    for (int off = 128; off; off >>= 1) {
        if (t < off) rv[t] += rv[t + off];
        __syncthreads();
    }
    float Zs = rv[0];
    __syncthreads();
    soft[t] = e / Zs;

    for (int it = 0; it < KIN; ++it) {
        __syncthreads();
        rv[t] = work[t];
        ri[t] = t;
        __syncthreads();
        for (int off = 128; off; off >>= 1) {
            if (t < off) {
                float v2 = rv[t + off];
                int i2 = ri[t + off];
                if (v2 > rv[t] || (v2 == rv[t] && i2 < ri[t])) { rv[t] = v2; ri[t] = i2; }
            }
            __syncthreads();
        }
        if (t == 0) {
            sel[it] = ri[0];
            work[ri[0]] = -INFINITY;
        }
    }
    __syncthreads();
    rv[t] = (t < KIN) ? soft[sel[t]] : 0.f;
    __syncthreads();
    for (int off = 128; off; off >>= 1) {
        if (t < off) rv[t] += rv[t + off];
        __syncthreads();
    }
    float msum = rv[0];
    if (t < KIN) {
        int id = sel[t];
        idx_out[b * KIN + t] = id;
        w_out[b * KIN + t] = soft[id] / (msum + 1e-8f);
    }
}

// ---------------------------------------------------------------------------
// top-256 of 512. One block per b, 256 threads.
// ---------------------------------------------------------------------------
__global__ __launch_bounds__(256)
void topk_proc_kernel(const float* __restrict__ finals, int* __restrict__ pidx)
{
    int b = blockIdx.x, t = threadIdx.x;
    __shared__ float work[512], rv[256];
    __shared__ int ri[256];
    work[t] = finals[b * 512 + t];
    work[t + 256] = finals[b * 512 + t + 256];
    __syncthreads();
    for (int it = 0; it < KPROC; ++it) {
        float v1 = work[t];
        int i1 = t;
        float v2 = work[t + 256];
        if (v2 > v1) { v1 = v2; i1 = t + 256; }
        rv[t] = v1;
        ri[t] = i1;
        __syncthreads();
        for (int off = 128; off; off >>= 1) {
            if (t < off) {
                float v2b = rv[t + off];
                int i2 = ri[t + off];
                if (v2b > rv[t] || (v2b == rv[t] && i2 < ri[t])) { rv[t] = v2b; ri[t] = i2; }
            }
            __syncthreads();
        }
        if (t == 0) {
            pidx[b * KPROC + it] = ri[0];
            work[ri[0]] = -INFINITY;
        }
        __syncthreads();
    }
}

// ---------------------------------------------------------------------------
// acts = LN(a + b) over 256 features. One block per row.
// ---------------------------------------------------------------------------
__global__ __launch_bounds__(256)
void ln_kernel(const float* __restrict__ a, const float* __restrict__ bsrc,
               const float* __restrict__ g, const float* __restrict__ be,
               float* __restrict__ out)
{
    long row = blockIdx.x;
    int t = threadIdx.x;
    float v = a[row * 256 + t] + bsrc[row * 256 + t];
    __shared__ float rv[256];
    rv[t] = v;
    __syncthreads();
    for (int off = 128; off; off >>= 1) {
        if (t < off) rv[t] += rv[t + off];
        __syncthreads();
    }
    float mean = rv[0] * (1.f / 256.f);
    __syncthreads();
    float d = v - mean;
    rv[t] = d * d;
    __syncthreads();
    for (int off = 128; off; off >>= 1) {
        if (t < off) rv[t] += rv[t + off];
        __syncthreads();
    }
    float var = rv[0] * (1.f / 256.f);
    out[row * 256 + t] = d * rsqrtf(var + 1e-5f) * g[t] + be[t];
}

// ---------------------------------------------------------------------------
// Gathers
// ---------------------------------------------------------------------------
__global__ void gather_sel_acts(const float* __restrict__ acts, const int* __restrict__ idx_in,
                                const float* __restrict__ w_sel, float* __restrict__ sel_acts)
{
    int s = blockIdx.x, b = blockIdx.y, j = threadIdx.x;  // 128 threads
    long row = (long)b * NS + s;
    int id = idx_in[b * KIN + j];
    sel_acts[row * KIN + j] = acts[row * NIN + id] * w_sel[b * KIN + j];
}

__global__ void gather_sel_cw(const float* __restrict__ comb_w, const int* __restrict__ idx_in,
                              float* __restrict__ sel_cw)
{
    int g = blockIdx.x * 256 + threadIdx.x;  // 8*512*128
    int b = g >> 16;
    int rem = g & 65535;
    int pb = rem >> 7, j = rem & 127;
    sel_cw[g] = comb_w[pb * NIN + idx_in[b * KIN + j]];
}

__global__ void gather_sel_proc(const float* __restrict__ proc_acts, const int* __restrict__ pidx,
                                float* __restrict__ sel_proc)
{
    int s = blockIdx.x, b = blockIdx.y, j = threadIdx.x;  // 256 threads
    long row = (long)b * NS + s;
    sel_proc[row * KPROC + j] = proc_acts[row * NPROC + pidx[b * KPROC + j]];
}

__global__ void gather_sel_proj(const float* __restrict__ out_proj_w, const int* __restrict__ pidx,
                                float* __restrict__ sel_proj)
{
    int g = blockIdx.x * 256 + threadIdx.x;  // 8*256*1024
    int b = g >> 18;
    int rem = g & 262143;
    int j = rem >> 10, dcol = rem & 1023;
    sel_proj[g] = out_proj_w[(long)pidx[b * KPROC + j] * ND + dcol];
}

// ---------------------------------------------------------------------------
// relevance MLP + act_scores max + sigmoid gate → final_scores. Block per b.
// ---------------------------------------------------------------------------
__global__ __launch_bounds__(512)
void relevance_kernel(const float* __restrict__ proc_acts, const int* __restrict__ idx_in,
                      const float* __restrict__ a1w, const float* __restrict__ a1b,
                      const float* __restrict__ a2w, const float* __restrict__ a2b,
                      float* __restrict__ finals)
{
    int b = blockIdx.x, t = threadIdx.x;  // 512 threads
    const float* pa = proc_acts + (long)b * NS * NPROC;
    float m = -INFINITY;
    for (int s = 0; s < NS; ++s) m = fmaxf(m, pa[(long)s * NPROC + t]);

    __shared__ float rel1[512];
    __shared__ int sidx[KIN];
    if (t < KIN) sidx[t] = idx_in[b * KIN + t];
    __syncthreads();
    float r1 = a1b[t];
    const float* a1row = a1w + (long)t * NIN;
    for (int j = 0; j < KIN; ++j) r1 += a1row[sidx[j]];
    rel1[t] = gelu_f(r1);
    __syncthreads();
    float r = a2b[t];
    const float* a2row = a2w + (long)t * 512;
    for (int h = 0; h < 512; ++h) r += rel1[h] * a2row[h];
    float sig = 1.f / (1.f + expf(-r));
    finals[b * NPROC + t] = m * sig;
}

// ---------------------------------------------------------------------------
extern "C" void kernel_launch(void* const* d_in, const int* in_sizes, int n_in,
                              void* d_out, int out_size, void* d_ws, size_t ws_size,
                              hipStream_t stream)
{
    const float* x       = (const float*)d_in[0];
    const float* r_in_w  = (const float*)d_in[1];
    const float* r_in_b  = (const float*)d_in[2];
    const float* r_out_w = (const float*)d_in[3];
    const float* r_out_b = (const float*)d_in[4];
    const float* aff_w   = (const float*)d_in[5];
    const float* aff_b   = (const float*)d_in[6];
    const float* patterns= (const float*)d_in[7];
    const float* i_in_w  = (const float*)d_in[8];
    const float* i_in_b  = (const float*)d_in[9];
    const float* i_out_w = (const float*)d_in[10];
    const float* i_out_b = (const float*)d_in[11];
    const float* ln_g    = (const float*)d_in[12];
    const float* ln_b    = (const float*)d_in[13];
    const float* comb_w  = (const float*)d_in[14];
    const float* out_proj_w = (const float*)d_in[15];
    const float* a1w     = (const float*)d_in[16];
    const float* a1b     = (const float*)d_in[17];
    const float* a2w     = (const float*)d_in[18];
    const float* a2b     = (const float*)d_in[19];
    float* out = (float*)d_out;

    float* ws = (float*)d_ws;
    // Arena (floats). Peak = 33,554,432 floats = 128 MiB.
    float* qkv1    = ws;                       // 8192*3072 = 25,165,824 (region 0)
    float* context = ws + 25165824;            // 8192*1024 = 8,388,608
    // region 0 reuse (after context is computed):
    float* affin     = ws + 0;                 // 2,097,152
    float* acts0     = ws + 2097152;           // 2,097,152
    float* qkv2      = ws + 4194304;           // 6,291,456
    float* attn2proj = ws + 10485760;          // 2,097,152
    float* acts      = ws + 12582912;          // 2,097,152
    float* sel_acts  = ws + 14680064;          // 1,048,576
    float* sel_cw    = ws + 15728640;          //   524,288
    float* proc_acts = ws + 16252928;          // 4,194,304
    float* sel_proc  = ws + 20447232;          // 2,097,152
    float* sel_proj  = ws + 22544384;          // 2,097,152 (ends 24,641,536)
    float* scoresb   = ws + 24641536;          // 2048
    float* w_sel     = ws + 24643584;          // 1024
    float* finals    = ws + 24644608;          // 4096
    int*   idx_in    = (int*)(ws + 24648704);  // 1024
    int*   pidx      = (int*)(ws + 24649728);  // 2048

    // 1. qkv1 = x @ r_in_w^T + r_in_b  [8192,3072]
    gemm_kernel<<<dim3(48, 128, 1), 256, 0, stream>>>(
        x, 0, ND, r_in_w, 0, ND, 1, r_in_b, nullptr, 0, 0,
        qkv1, 0, 3 * ND, NB * NS, 3 * ND, ND, 0);
    // 2. MHA-1 (dh=128, 8 heads): writes over q slots
    attn_kernel<128, 8><<<dim3(NS / 8, 8, NB), 256, 0, stream>>>(
        qkv1, 3 * ND, ND, 2 * ND, 0.088388347648318447f);
    // 3. context = attn_out @ r_out_w^T + r_out_b
    gemm_kernel<<<dim3(16, 128, 1), 256, 0, stream>>>(
        qkv1, 0, 3 * ND, r_out_w, 0, ND, 1, r_out_b, nullptr, 0, 0,
        context, 0, ND, NB * NS, ND, ND, 0);
    // 4. affinity = context @ aff_w^T + aff_b  [8192,256]
    gemm_kernel<<<dim3(4, 128, 1), 256, 0, stream>>>(
        context, 0, ND, aff_w, 0, ND, 1, aff_b, nullptr, 0, 0,
        affin, 0, NIN, NB * NS, NIN, ND, 0);
    // 5. scores = max over S
    rowmax_kernel<<<NB, 1024, 0, stream>>>(affin, scoresb);
    // 6. routing top-k + weights
    topk_input_kernel<<<NB, 256, 0, stream>>>(scoresb, idx_in, w_sel);
    // 7. acts0 = gelu(context @ patterns^T)
    gemm_kernel<<<dim3(4, 128, 1), 256, 0, stream>>>(
        context, 0, ND, patterns, 0, ND, 1, nullptr, nullptr, 0, 0,
        acts0, 0, NIN, NB * NS, NIN, ND, 1);
    // 8. qkv2 = acts0 @ i_in_w^T + i_in_b  [8192,768]
    gemm_kernel<<<dim3(12, 128, 1), 256, 0, stream>>>(
        acts0, 0, NIN, i_in_w, 0, NIN, 1, i_in_b, nullptr, 0, 0,
        qkv2, 0, 3 * NIN, NB * NS, 3 * NIN, NIN, 0);
    // 9. MHA-2 (dh=64, 4 heads)
    attn_kernel<64, 8><<<dim3(NS / 8, 4, NB), 256, 0, stream>>>(
        qkv2, 3 * NIN, NIN, 2 * NIN, 0.125f);
    // 10. attn2proj = attn2_out @ i_out_w^T + i_out_b
    gemm_kernel<<<dim3(4, 128, 1), 256, 0, stream>>>(
        qkv2, 0, 3 * NIN, i_out_w, 0, NIN, 1, i_out_b, nullptr, 0, 0,
        attn2proj, 0, NIN, NB * NS, NIN, NIN, 0);
    // 11. acts = LN(acts0 + attn2proj)
    ln_kernel<<<NB * NS, 256, 0, stream>>>(acts0, attn2proj, ln_g, ln_b, acts);
    // 12-13. gathers for process GEMM
    gather_sel_acts<<<dim3(NS, NB), KIN, 0, stream>>>(acts, idx_in, w_sel, sel_acts);
    gather_sel_cw<<<2048, 256, 0, stream>>>(comb_w, idx_in, sel_cw);
    // 14. proc_acts = gelu(sel_acts @ sel_cw^T)  batched [1024,512] per b
    gemm_kernel<<<dim3(8, 16, NB), 256, 0, stream>>>(
        sel_acts, (long)NS * KIN, KIN, sel_cw, (long)NPROC * KIN, KIN, 1,
        nullptr, nullptr, 0, 0,
        proc_acts, (long)NS * NPROC, NPROC, NS, NPROC, KIN, 1);
    // 15. final_scores = max_s(proc_acts) * sigmoid(relevance)
    relevance_kernel<<<NB, 512, 0, stream>>>(proc_acts, idx_in, a1w, a1b, a2w, a2b, finals);
    // 16. top-256 process neurons
    topk_proc_kernel<<<NB, 256, 0, stream>>>(finals, pidx);
    // 17. gathers for output GEMM
    gather_sel_proc<<<dim3(NS, NB), KPROC, 0, stream>>>(proc_acts, pidx, sel_proc);
    gather_sel_proj<<<8192, 256, 0, stream>>>(out_proj_w, pidx, sel_proj);
    // 18. out = x + sel_proc @ sel_proj  batched [1024,1024] per b
    gemm_kernel<<<dim3(16, 16, NB), 256, 0, stream>>>(
        sel_proc, (long)NS * KPROC, KPROC, sel_proj, (long)KPROC * ND, ND, 0,
        nullptr, x, (long)NS * ND, ND,
        out, (long)NS * ND, ND, NS, ND, KPROC, 0);
    (void)in_sizes; (void)n_in; (void)out_size; (void)ws_size;
}

// Round 3
// 1058.886 us; speedup vs baseline: 5.2512x; 5.2512x over previous
//
#include <hip/hip_runtime.h>
#include <hip/hip_bf16.h>
#include <math.h>

constexpr int NB = 8, NS = 1024, ND = 1024, NIN = 256, NPROC = 512, KIN = 128, KPROC = 256;

typedef __attribute__((ext_vector_type(8))) short bf16x8;
typedef __attribute__((ext_vector_type(4))) float f32x4;

__device__ inline float gelu_f(float x) {
    return 0.5f * x * (1.0f + erff(x * 0.7071067811865476f));
}
__device__ inline unsigned short f2b(float f) {
    __hip_bfloat16 h = __float2bfloat16(f);
    return *reinterpret_cast<unsigned short*>(&h);
}

// ---------------------------------------------------------------------------
// f32 -> bf16 convert (n multiple of 4)
// ---------------------------------------------------------------------------
__global__ void cvt_kernel(const float* __restrict__ in, unsigned short* __restrict__ out, long n4)
{
    long i = (long)blockIdx.x * blockDim.x + threadIdx.x;
    long stride = (long)gridDim.x * blockDim.x;
    for (; i < n4; i += stride) {
        float4 v = ((const float4*)in)[i];
        ushort4 o;
        o.x = f2b(v.x); o.y = f2b(v.y); o.z = f2b(v.z); o.w = f2b(v.w);
        ((ushort4*)out)[i] = o;
    }
}

// ---------------------------------------------------------------------------
// bf16 MFMA GEMM: C = act(A @ B^T + bias) + resid.  A:[M,K] lda, B:[N,K] ldb.
// 128x128 tile, BK=64, 4 waves (2x2), 16x16x32 MFMA. M%128==0, N%128==0, K%64==0.
// ---------------------------------------------------------------------------
__global__ __launch_bounds__(256)
void gemm_bf16(const unsigned short* __restrict__ A, long sA, int lda,
               const unsigned short* __restrict__ B, long sB, int ldb,
               const float* __restrict__ bias,
               const float* __restrict__ resid, long sR, int ldr,
               float* __restrict__ C32, long sC32, int ldc32,
               unsigned short* __restrict__ C16, long sC16, int ldc16,
               int M, int N, int K, int act)
{
    __shared__ unsigned short As[128 * 72];
    __shared__ unsigned short Bs[128 * 72];
    int bz = blockIdx.z;
    const unsigned short* Ab = A + (long)bz * sA;
    const unsigned short* Bb = B + (long)bz * sB;
    int row0 = blockIdx.y * 128, col0 = blockIdx.x * 128;
    int t = threadIdx.x;
    int w = t >> 6, l = t & 63, l15 = l & 15, g = l >> 4;
    int wr = w >> 1, wc = w & 1;
    f32x4 zero4 = {0.f, 0.f, 0.f, 0.f};
    f32x4 acc[4][4];
#pragma unroll
    for (int i = 0; i < 4; ++i)
#pragma unroll
        for (int j = 0; j < 4; ++j) acc[i][j] = zero4;

    for (int k0 = 0; k0 < K; k0 += 64) {
        __syncthreads();
#pragma unroll
        for (int i = 0; i < 4; ++i) {
            int gi = t + i * 256;
            int r = gi >> 3, sg = gi & 7;
            *(uint4*)&As[r * 72 + sg * 8] = *(const uint4*)&Ab[(long)(row0 + r) * lda + k0 + sg * 8];
            *(uint4*)&Bs[r * 72 + sg * 8] = *(const uint4*)&Bb[(long)(col0 + r) * ldb + k0 + sg * 8];
        }
        __syncthreads();
        bf16x8 af[4][2], bfr[4][2];
#pragma unroll
        for (int mi = 0; mi < 4; ++mi)
#pragma unroll
            for (int ks = 0; ks < 2; ++ks) {
                af[mi][ks] = *(const bf16x8*)&As[(wr * 64 + mi * 16 + l15) * 72 + g * 8 + ks * 32];
                bfr[mi][ks] = *(const bf16x8*)&Bs[(wc * 64 + mi * 16 + l15) * 72 + g * 8 + ks * 32];
            }
#pragma unroll
        for (int ks = 0; ks < 2; ++ks)
#pragma unroll
            for (int mi = 0; mi < 4; ++mi)
#pragma unroll
                for (int ni = 0; ni < 4; ++ni)
                    acc[mi][ni] = __builtin_amdgcn_mfma_f32_16x16x32_bf16(af[mi][ks], bfr[ni][ks], acc[mi][ni], 0, 0, 0);
    }

#pragma unroll
    for (int mi = 0; mi < 4; ++mi) {
#pragma unroll
        for (int ni = 0; ni < 4; ++ni) {
#pragma unroll
            for (int r = 0; r < 4; ++r) {
                int row = row0 + wr * 64 + mi * 16 + g * 4 + r;
                int col = col0 + wc * 64 + ni * 16 + l15;
                float v = acc[mi][ni][r];
                if (bias) v += bias[col];
                if (act == 1) v = gelu_f(v);
                if (resid) v += resid[(long)bz * sR + (long)row * ldr + col];
                if (C32) C32[(long)bz * sC32 + (long)row * ldc32 + col] = v;
                if (C16) C16[(long)bz * sC16 + (long)row * ldc16 + col] = f2b(v);
            }
        }
    }
}

// ---------------------------------------------------------------------------
// Flash-style MFMA attention on packed bf16 qkv [B*S, stride]. Q at h*D,
// K at koff+h*D, V at voff+h*D. Output overwrites the q slots (bf16).
// Block: 64 q-rows, 4 waves (one 16-q strip each). KT=64 kv-tile.
// ---------------------------------------------------------------------------
template <int D>
__global__ __launch_bounds__(256)
void attn_mfma(unsigned short* __restrict__ qkv, int stride, int koff, int voff, float scale)
{
    constexpr int LQ = D + 8;
    constexpr int LK = D + 8;
    constexpr int LV = 64 + 8;
    constexpr int LP = 64 + 8;
    constexpr int NKS = D / 32;
    constexpr int NF = D / 16;
    constexpr int GR = D / 8;

    __shared__ unsigned short Ks[64 * LK];
    __shared__ unsigned short Vt[D * LV];
    __shared__ unsigned short QP[64 * LQ];

    int b = blockIdx.z, h = blockIdx.y, qt = blockIdx.x;
    int t = threadIdx.x, w = t >> 6, l = t & 63, l15 = l & 15, g = l >> 4;
    long qbase = ((long)b * NS + qt * 64) * stride + h * D;
    long kvbase = (long)b * NS * stride + h * D;

    for (int gi = t; gi < 64 * GR; gi += 256) {
        int r = gi / GR, sg = gi % GR;
        *(uint4*)&QP[r * LQ + sg * 8] = *(const uint4*)&qkv[qbase + (long)r * stride + sg * 8];
    }
    __syncthreads();
    bf16x8 qreg[NKS];
#pragma unroll
    for (int ks = 0; ks < NKS; ++ks)
        qreg[ks] = *(const bf16x8*)&QP[(w * 16 + l15) * LQ + g * 8 + ks * 32];
    __syncthreads();

    float m_run = -INFINITY, l_run = 0.f;
    f32x4 zero4 = {0.f, 0.f, 0.f, 0.f};
    f32x4 oacc[NF];
#pragma unroll
    for (int nf = 0; nf < NF; ++nf) oacc[nf] = zero4;

    for (int kt = 0; kt < NS / 64; ++kt) {
        __syncthreads();
        for (int gi = t; gi < 64 * GR; gi += 256) {
            int r = gi / GR, sg = gi % GR;
            *(uint4*)&Ks[r * LK + sg * 8] =
                *(const uint4*)&qkv[kvbase + (long)(kt * 64 + r) * stride + koff + sg * 8];
        }
        for (int gi = t; gi < 64 * GR; gi += 256) {
            int kc = gi & 63, sg = gi >> 6;
            uint4 v = *(const uint4*)&qkv[kvbase + (long)(kt * 64 + kc) * stride + voff + sg * 8];
            Vt[(sg * 8 + 0) * LV + kc] = (unsigned short)(v.x & 0xffff);
            Vt[(sg * 8 + 1) * LV + kc] = (unsigned short)(v.x >> 16);
            Vt[(sg * 8 + 2) * LV + kc] = (unsigned short)(v.y & 0xffff);
            Vt[(sg * 8 + 3) * LV + kc] = (unsigned short)(v.y >> 16);
            Vt[(sg * 8 + 4) * LV + kc] = (unsigned short)(v.z & 0xffff);
            Vt[(sg * 8 + 5) * LV + kc] = (unsigned short)(v.z >> 16);
            Vt[(sg * 8 + 6) * LV + kc] = (unsigned short)(v.w & 0xffff);
            Vt[(sg * 8 + 7) * LV + kc] = (unsigned short)(v.w >> 16);
        }
        __syncthreads();

        f32x4 st[4];
#pragma unroll
        for (int f = 0; f < 4; ++f) st[f] = zero4;
#pragma unroll
        for (int ks = 0; ks < NKS; ++ks) {
#pragma unroll
            for (int f = 0; f < 4; ++f) {
                bf16x8 a = *(const bf16x8*)&Ks[(f * 16 + l15) * LK + g * 8 + ks * 32];
                st[f] = __builtin_amdgcn_mfma_f32_16x16x32_bf16(a, qreg[ks], st[f], 0, 0, 0);
            }
        }
        float stv[4][4];
        float pm = -INFINITY;
#pragma unroll
        for (int f = 0; f < 4; ++f)
#pragma unroll
            for (int r = 0; r < 4; ++r) {
                float v = st[f][r] * scale;
                stv[f][r] = v;
                pm = fmaxf(pm, v);
            }
        pm = fmaxf(pm, __shfl_xor(pm, 16));
        pm = fmaxf(pm, __shfl_xor(pm, 32));
        float m_new = fmaxf(m_run, pm);
        float corr = __expf(m_run - m_new);
        float rs = 0.f;
        float pv[4][4];
#pragma unroll
        for (int f = 0; f < 4; ++f)
#pragma unroll
            for (int r = 0; r < 4; ++r) {
                float p = __expf(stv[f][r] - m_new);
                pv[f][r] = p;
                rs += p;
            }
        rs += __shfl_xor(rs, 16);
        rs += __shfl_xor(rs, 32);
        l_run = l_run * corr + rs;
        m_run = m_new;
#pragma unroll
        for (int f = 0; f < 4; ++f) {
            ushort4 pw;
            pw.x = f2b(pv[f][0]); pw.y = f2b(pv[f][1]);
            pw.z = f2b(pv[f][2]); pw.w = f2b(pv[f][3]);
            *(ushort4*)&QP[(w * 16 + l15) * LP + f * 16 + g * 4] = pw;
        }
        float corrO[4];
#pragma unroll
        for (int r = 0; r < 4; ++r) corrO[r] = __shfl(corr, g * 4 + r);
#pragma unroll
        for (int nf = 0; nf < NF; ++nf)
#pragma unroll
            for (int r = 0; r < 4; ++r) oacc[nf][r] *= corrO[r];
#pragma unroll
        for (int ks2 = 0; ks2 < 2; ++ks2) {
            bf16x8 pa = *(const bf16x8*)&QP[(w * 16 + l15) * LP + ks2 * 32 + g * 8];
#pragma unroll
            for (int nf = 0; nf < NF; ++nf) {
                bf16x8 vb = *(const bf16x8*)&Vt[(nf * 16 + l15) * LV + ks2 * 32 + g * 8];
                oacc[nf] = __builtin_amdgcn_mfma_f32_16x16x32_bf16(pa, vb, oacc[nf], 0, 0, 0);
            }
        }
    }
    float lo[4];
#pragma unroll
    for (int r = 0; r < 4; ++r) lo[r] = __shfl(l_run, g * 4 + r);
#pragma unroll
    for (int nf = 0; nf < NF; ++nf)
#pragma unroll
        for (int r = 0; r < 4; ++r) {
            float o = oacc[nf][r] / lo[r];
            qkv[qbase + (long)(w * 16 + g * 4 + r) * stride + nf * 16 + l15] = f2b(o);
        }
}

// ---------------------------------------------------------------------------
__global__ __launch_bounds__(1024)
void rowmax_kernel(const float* __restrict__ aff, float* __restrict__ scores)
{
    int b = blockIdx.x, t = threadIdx.x;
    int n = t & 255, sc = t >> 8;
    float m = -INFINITY;
    for (int s = sc * 256; s < (sc + 1) * 256; ++s)
        m = fmaxf(m, aff[((long)(b * NS + s)) * NIN + n]);
    __shared__ float pm[1024];
    pm[t] = m;
    __syncthreads();
    if (t < 256) {
        float mm = fmaxf(fmaxf(pm[t], pm[t + 256]), fmaxf(pm[t + 512], pm[t + 768]));
        scores[b * NIN + t] = mm;
    }
}

__global__ __launch_bounds__(256)
void topk_input_kernel(const float* __restrict__ scores, int* __restrict__ idx_out,
                       float* __restrict__ w_out)
{
    int b = blockIdx.x, t = threadIdx.x;
    __shared__ float soft[256], work[256], rv[256];
    __shared__ int ri[256], sel[KIN];
    float lg = scores[b * 256 + t] * 0.5f;
    work[t] = lg;
    rv[t] = lg;
    __syncthreads();
    for (int off = 128; off; off >>= 1) {
        if (t < off) rv[t] = fmaxf(rv[t], rv[t + off]);
        __syncthreads();
    }
    float mx = rv[0];
    __syncthreads();
    float e = expf(lg - mx);
    rv[t] = e;
    __syncthreads();
    for (int off = 128; off; off >>= 1) {
        if (t < off) rv[t] += rv[t + off];
        __syncthreads();
    }
    float Zs = rv[0];
    __syncthreads();
    soft[t] = e / Zs;
    for (int it = 0; it < KIN; ++it) {
        __syncthreads();
        rv[t] = work[t];
        ri[t] = t;
        __syncthreads();
        for (int off = 128; off; off >>= 1) {
            if (t < off) {
                float v2 = rv[t + off]; int i2 = ri[t + off];
                if (v2 > rv[t] || (v2 == rv[t] && i2 < ri[t])) { rv[t] = v2; ri[t] = i2; }
            }
            __syncthreads();
        }
        if (t == 0) { sel[it] = ri[0]; work[ri[0]] = -INFINITY; }
    }
    __syncthreads();
    rv[t] = (t < KIN) ? soft[sel[t]] : 0.f;
    __syncthreads();
    for (int off = 128; off; off >>= 1) {
        if (t < off) rv[t] += rv[t + off];
        __syncthreads();
    }
    float msum = rv[0];
    if (t < KIN) {
        int id = sel[t];
        idx_out[b * KIN + t] = id;
        w_out[b * KIN + t] = soft[id] / (msum + 1e-8f);
    }
}

__global__ __launch_bounds__(256)
void topk_proc_kernel(const float* __restrict__ finals, int* __restrict__ pidx)
{
    int b = blockIdx.x, t = threadIdx.x;
    __shared__ float work[512], rv[256];
    __shared__ int ri[256];
    work[t] = finals[b * 512 + t];
    work[t + 256] = finals[b * 512 + t + 256];
    __syncthreads();
    for (int it = 0; it < KPROC; ++it) {
        float v1 = work[t]; int i1 = t;
        float v2 = work[t + 256];
        if (v2 > v1) { v1 = v2; i1 = t + 256; }
        rv[t] = v1; ri[t] = i1;
        __syncthreads();
        for (int off = 128; off; off >>= 1) {
            if (t < off) {
                float v2b = rv[t + off]; int i2 = ri[t + off];
                if (v2b > rv[t] || (v2b == rv[t] && i2 < ri[t])) { rv[t] = v2b; ri[t] = i2; }
            }
            __syncthreads();
        }
        if (t == 0) { pidx[b * KPROC + it] = ri[0]; work[ri[0]] = -INFINITY; }
        __syncthreads();
    }
}

__global__ __launch_bounds__(256)
void ln_kernel(const float* __restrict__ a, const float* __restrict__ bsrc,
               const float* __restrict__ gg, const float* __restrict__ be,
               float* __restrict__ out)
{
    long row = blockIdx.x;
    int t = threadIdx.x;
    float v = a[row * 256 + t] + bsrc[row * 256 + t];
    __shared__ float rv[256];
    rv[t] = v;
    __syncthreads();
    for (int off = 128; off; off >>= 1) {
        if (t < off) rv[t] += rv[t + off];
        __syncthreads();
    }
    float mean = rv[0] * (1.f / 256.f);
    __syncthreads();
    float d = v - mean;
    rv[t] = d * d;
    __syncthreads();
    for (int off = 128; off; off >>= 1) {
        if (t < off) rv[t] += rv[t + off];
        __syncthreads();
    }
    float var = rv[0] * (1.f / 256.f);
    out[row * 256 + t] = d * rsqrtf(var + 1e-5f) * gg[t] + be[t];
}

__global__ void gather_sel_acts_b(const float* __restrict__ acts, const int* __restrict__ idx_in,
                                  const float* __restrict__ w_sel, unsigned short* __restrict__ sel_acts)
{
    int s = blockIdx.x, b = blockIdx.y, j = threadIdx.x;
    long row = (long)b * NS + s;
    int id = idx_in[b * KIN + j];
    sel_acts[row * KIN + j] = f2b(acts[row * NIN + id] * w_sel[b * KIN + j]);
}

__global__ void gather_sel_cw_b(const float* __restrict__ comb_w, const int* __restrict__ idx_in,
                                unsigned short* __restrict__ sel_cw)
{
    int gidx = blockIdx.x * 256 + threadIdx.x;
    int b = gidx >> 16;
    int rem = gidx & 65535;
    int pb = rem >> 7, j = rem & 127;
    sel_cw[gidx] = f2b(comb_w[pb * NIN + idx_in[b * KIN + j]]);
}

__global__ void gather_sel_proc_b(const float* __restrict__ proc_acts, const int* __restrict__ pidx,
                                  unsigned short* __restrict__ sel_proc)
{
    int s = blockIdx.x, b = blockIdx.y, j = threadIdx.x;
    long row = (long)b * NS + s;
    sel_proc[row * KPROC + j] = f2b(proc_acts[row * NPROC + pidx[b * KPROC + j]]);
}

__global__ void gather_sel_projT(const float* __restrict__ out_proj_w, const int* __restrict__ pidx,
                                 unsigned short* __restrict__ selT)
{
    int gidx = blockIdx.x * 256 + threadIdx.x;
    int b = gidx >> 15;
    int rem = gidx & 32767;
    int d = rem >> 5;
    int kp0 = (rem & 31) * 8;
    unsigned int u[4];
#pragma unroll
    for (int i = 0; i < 4; ++i) {
        unsigned short e0 = f2b(out_proj_w[(long)pidx[b * KPROC + kp0 + 2 * i] * ND + d]);
        unsigned short e1 = f2b(out_proj_w[(long)pidx[b * KPROC + kp0 + 2 * i + 1] * ND + d]);
        u[i] = (unsigned int)e0 | ((unsigned int)e1 << 16);
    }
    uint4 o; o.x = u[0]; o.y = u[1]; o.z = u[2]; o.w = u[3];
    *(uint4*)&selT[((long)b * ND + d) * KPROC + kp0] = o;
}

__global__ __launch_bounds__(512)
void maxpart_kernel(const float* __restrict__ proc, float* __restrict__ part)
{
    int sc = blockIdx.x, b = blockIdx.y, t = threadIdx.x;
    float m = -INFINITY;
    for (int s = sc * 128; s < (sc + 1) * 128; ++s)
        m = fmaxf(m, proc[((long)b * NS + s) * NPROC + t]);
    part[(b * 8 + sc) * NPROC + t] = m;
}

__global__ __launch_bounds__(512)
void relevance_kernel(const float* __restrict__ part, const int* __restrict__ idx_in,
                      const float* __restrict__ a1w, const float* __restrict__ a1b,
                      const float* __restrict__ a2w, const float* __restrict__ a2b,
                      float* __restrict__ finals)
{
    int b = blockIdx.x, t = threadIdx.x;
    float m = part[(b * 8) * NPROC + t];
#pragma unroll
    for (int sc = 1; sc < 8; ++sc) m = fmaxf(m, part[(b * 8 + sc) * NPROC + t]);
    __shared__ float rel1[512];
    __shared__ int sidx[KIN];
    if (t < KIN) sidx[t] = idx_in[b * KIN + t];
    __syncthreads();
    float r1 = a1b[t];
    const float* a1row = a1w + (long)t * NIN;
    for (int j = 0; j < KIN; ++j) r1 += a1row[sidx[j]];
    rel1[t] = gelu_f(r1);
    __syncthreads();
    float r = a2b[t];
    const float* a2row = a2w + (long)t * 512;
    for (int hh = 0; hh < 512; ++hh) r += rel1[hh] * a2row[hh];
    float sig = 1.f / (1.f + expf(-r));
    finals[b * NPROC + t] = m * sig;
}

// ---------------------------------------------------------------------------
extern "C" void kernel_launch(void* const* d_in, const int* in_sizes, int n_in,
                              void* d_out, int out_size, void* d_ws, size_t ws_size,
                              hipStream_t stream)
{
    const float* x       = (const float*)d_in[0];
    const float* r_in_w  = (const float*)d_in[1];
    const float* r_in_b  = (const float*)d_in[2];
    const float* r_out_w = (const float*)d_in[3];
    const float* r_out_b = (const float*)d_in[4];
    const float* aff_w   = (const float*)d_in[5];
    const float* aff_b   = (const float*)d_in[6];
    const float* patterns= (const float*)d_in[7];
    const float* i_in_w  = (const float*)d_in[8];
    const float* i_in_b  = (const float*)d_in[9];
    const float* i_out_w = (const float*)d_in[10];
    const float* i_out_b = (const float*)d_in[11];
    const float* ln_g    = (const float*)d_in[12];
    const float* ln_b    = (const float*)d_in[13];
    const float* comb_w  = (const float*)d_in[14];
    const float* out_proj_w = (const float*)d_in[15];
    const float* a1w     = (const float*)d_in[16];
    const float* a1b     = (const float*)d_in[17];
    const float* a2w     = (const float*)d_in[18];
    const float* a2b     = (const float*)d_in[19];
    float* out = (float*)d_out;

    char* ws = (char*)d_ws;
    unsigned short* qkv1b    = (unsigned short*)(ws + 0);
    unsigned short* contextb = (unsigned short*)(ws + 50331648);
    unsigned short* xb       = (unsigned short*)(ws + 67108864);
    unsigned short* w_rin_b  = (unsigned short*)(ws + 83886080);
    unsigned short* w_rout_b = (unsigned short*)(ws + 90177536);
    unsigned short* w_aff_b  = (unsigned short*)(ws + 92274688);
    unsigned short* patt_b   = (unsigned short*)(ws + 92798976);
    unsigned short* w_iin_b  = (unsigned short*)(ws + 93323264);
    unsigned short* w_iout_b = (unsigned short*)(ws + 93716480);
    float* scoresb = (float*)(ws + 93847552);
    float* w_sel   = (float*)(ws + 93855744);
    int*   idx_in  = (int*)(ws + 93859840);
    float* finals  = (float*)(ws + 93863936);
    int*   pidx    = (int*)(ws + 93880320);
    float* maxpart = (float*)(ws + 93888512);
    float* affin   = (float*)(ws + 94019584);
    float* acts0   = (float*)(ws + 102408192);
    unsigned short* acts0b = (unsigned short*)(ws + 110796800);
    unsigned short* qkv2b  = (unsigned short*)(ws + 114991104);
    float* attn2proj = (float*)(ws + 0);
    float* acts      = (float*)(ws + 8388608);
    float* proc_acts = (float*)(ws + 16777216);
    unsigned short* sel_actsb = (unsigned short*)(ws + 33554432);
    unsigned short* sel_cwb   = (unsigned short*)(ws + 35651584);
    unsigned short* sel_procb = (unsigned short*)(ws + 36700160);
    unsigned short* sel_projT = (unsigned short*)(ws + 40894464);

    cvt_kernel<<<2048, 256, 0, stream>>>(x, xb, (long)NB * NS * ND / 4);
    cvt_kernel<<<1024, 256, 0, stream>>>(r_in_w, w_rin_b, (long)3 * ND * ND / 4);
    cvt_kernel<<<512, 256, 0, stream>>>(r_out_w, w_rout_b, (long)ND * ND / 4);
    cvt_kernel<<<128, 256, 0, stream>>>(aff_w, w_aff_b, (long)NIN * ND / 4);
    cvt_kernel<<<128, 256, 0, stream>>>(patterns, patt_b, (long)NIN * ND / 4);
    cvt_kernel<<<96, 256, 0, stream>>>(i_in_w, w_iin_b, (long)3 * NIN * NIN / 4);
    cvt_kernel<<<32, 256, 0, stream>>>(i_out_w, w_iout_b, (long)NIN * NIN / 4);

    gemm_bf16<<<dim3(24, 64, 1), 256, 0, stream>>>(
        xb, 0, ND, w_rin_b, 0, ND, r_in_b, nullptr, 0, 0,
        nullptr, 0, 0, qkv1b, 0, 3 * ND, NB * NS, 3 * ND, ND, 0);
    attn_mfma<128><<<dim3(16, 8, 8), 256, 0, stream>>>(qkv1b, 3 * ND, ND, 2 * ND, 0.088388347648318447f);
    gemm_bf16<<<dim3(8, 64, 1), 256, 0, stream>>>(
        qkv1b, 0, 3 * ND, w_rout_b, 0, ND, r_out_b, nullptr, 0, 0,
        nullptr, 0, 0, contextb, 0, ND, NB * NS, ND, ND, 0);
    gemm_bf16<<<dim3(2, 64, 1), 256, 0, stream>>>(
        contextb, 0, ND, w_aff_b, 0, ND, aff_b, nullptr, 0, 0,
        affin, 0, NIN, nullptr, 0, 0, NB * NS, NIN, ND, 0);
    rowmax_kernel<<<NB, 1024, 0, stream>>>(affin, scoresb);
    topk_input_kernel<<<NB, 256, 0, stream>>>(scoresb, idx_in, w_sel);
    gemm_bf16<<<dim3(2, 64, 1), 256, 0, stream>>>(
        contextb, 0, ND, patt_b, 0, ND, nullptr, nullptr, 0, 0,
        acts0, 0, NIN, acts0b, 0, NIN, NB * NS, NIN, ND, 1);
    gemm_bf16<<<dim3(6, 64, 1), 256, 0, stream>>>(
        acts0b, 0, NIN, w_iin_b, 0, NIN, i_in_b, nullptr, 0, 0,
        nullptr, 0, 0, qkv2b, 0, 3 * NIN, NB * NS, 3 * NIN, NIN, 0);
    attn_mfma<64><<<dim3(16, 4, 8), 256, 0, stream>>>(qkv2b, 3 * NIN, NIN, 2 * NIN, 0.125f);
    gemm_bf16<<<dim3(2, 64, 1), 256, 0, stream>>>(
        qkv2b, 0, 3 * NIN, w_iout_b, 0, NIN, i_out_b, nullptr, 0, 0,
        attn2proj, 0, NIN, nullptr, 0, 0, NB * NS, NIN, NIN, 0);
    ln_kernel<<<NB * NS, 256, 0, stream>>>(acts0, attn2proj, ln_g, ln_b, acts);
    gather_sel_acts_b<<<dim3(NS, NB), KIN, 0, stream>>>(acts, idx_in, w_sel, sel_actsb);
    gather_sel_cw_b<<<2048, 256, 0, stream>>>(comb_w, idx_in, sel_cwb);
    gemm_bf16<<<dim3(4, 8, NB), 256, 0, stream>>>(
        sel_actsb, (long)NS * KIN, KIN, sel_cwb, (long)NPROC * KIN, KIN,
        nullptr, nullptr, 0, 0,
        proc_acts, (long)NS * NPROC, NPROC, nullptr, 0, 0, NS, NPROC, KIN, 1);
    maxpart_kernel<<<dim3(8, NB), 512, 0, stream>>>(proc_acts, maxpart);
    relevance_kernel<<<NB, 512, 0, stream>>>(maxpart, idx_in, a1w, a1b, a2w, a2b, finals);
    topk_proc_kernel<<<NB, 256, 0, stream>>>(finals, pidx);
    gather_sel_proc_b<<<dim3(NS, NB), KPROC, 0, stream>>>(proc_acts, pidx, sel_procb);
    gather_sel_projT<<<1024, 256, 0, stream>>>(out_proj_w, pidx, sel_projT);
    gemm_bf16<<<dim3(8, 8, NB), 256, 0, stream>>>(
        sel_procb, (long)NS * KPROC, KPROC, sel_projT, (long)ND * KPROC, KPROC,
        nullptr, x, (long)NS * ND, ND,
        out, (long)NS * ND, ND, nullptr, 0, 0, NS, ND, KPROC, 0);
    (void)in_sizes; (void)n_in; (void)out_size; (void)ws_size;
}

// Round 4
// 656.882 us; speedup vs baseline: 8.4649x; 1.6120x over previous
//
#include <hip/hip_runtime.h>
#include <hip/hip_bf16.h>
#include <math.h>

constexpr int NB = 8, NS = 1024, ND = 1024, NIN = 256, NPROC = 512, KIN = 128, KPROC = 256;

typedef __attribute__((ext_vector_type(8))) short bf16x8;
typedef __attribute__((ext_vector_type(4))) float f32x4;

__device__ inline float gelu_f(float x) {
    return 0.5f * x * (1.0f + erff(x * 0.7071067811865476f));
}
__device__ inline unsigned short f2b(float f) {
    __hip_bfloat16 h = __float2bfloat16(f);
    return *reinterpret_cast<unsigned short*>(&h);
}

// ---------------------------------------------------------------------------
__global__ void cvt_kernel(const float* __restrict__ in, unsigned short* __restrict__ out, long n4)
{
    long i = (long)blockIdx.x * blockDim.x + threadIdx.x;
    long stride = (long)gridDim.x * blockDim.x;
    for (; i < n4; i += stride) {
        float4 v = ((const float4*)in)[i];
        ushort4 o;
        o.x = f2b(v.x); o.y = f2b(v.y); o.z = f2b(v.z); o.w = f2b(v.w);
        ((ushort4*)out)[i] = o;
    }
}

// ---------------------------------------------------------------------------
// bf16 MFMA GEMM: C = act(A @ B^T + bias) + resid.  A:[M,K] lda, B:[N,K] ldb.
// 128x128 tile, BK=64, 4 waves (2x2), 16x16x32 MFMA.
// ---------------------------------------------------------------------------
__global__ __launch_bounds__(256)
void gemm_bf16(const unsigned short* __restrict__ A, long sA, int lda,
               const unsigned short* __restrict__ B, long sB, int ldb,
               const float* __restrict__ bias,
               const float* __restrict__ resid, long sR, int ldr,
               float* __restrict__ C32, long sC32, int ldc32,
               unsigned short* __restrict__ C16, long sC16, int ldc16,
               int M, int N, int K, int act)
{
    __shared__ unsigned short As[128 * 72];
    __shared__ unsigned short Bs[128 * 72];
    int bz = blockIdx.z;
    const unsigned short* Ab = A + (long)bz * sA;
    const unsigned short* Bb = B + (long)bz * sB;
    int row0 = blockIdx.y * 128, col0 = blockIdx.x * 128;
    int t = threadIdx.x;
    int w = t >> 6, l = t & 63, l15 = l & 15, g = l >> 4;
    int wr = w >> 1, wc = w & 1;
    f32x4 zero4 = {0.f, 0.f, 0.f, 0.f};
    f32x4 acc[4][4];
#pragma unroll
    for (int i = 0; i < 4; ++i)
#pragma unroll
        for (int j = 0; j < 4; ++j) acc[i][j] = zero4;

    for (int k0 = 0; k0 < K; k0 += 64) {
        __syncthreads();
#pragma unroll
        for (int i = 0; i < 4; ++i) {
            int gi = t + i * 256;
            int r = gi >> 3, sg = gi & 7;
            *(uint4*)&As[r * 72 + sg * 8] = *(const uint4*)&Ab[(long)(row0 + r) * lda + k0 + sg * 8];
            *(uint4*)&Bs[r * 72 + sg * 8] = *(const uint4*)&Bb[(long)(col0 + r) * ldb + k0 + sg * 8];
        }
        __syncthreads();
        bf16x8 af[4][2], bfr[4][2];
#pragma unroll
        for (int mi = 0; mi < 4; ++mi)
#pragma unroll
            for (int ks = 0; ks < 2; ++ks) {
                af[mi][ks] = *(const bf16x8*)&As[(wr * 64 + mi * 16 + l15) * 72 + g * 8 + ks * 32];
                bfr[mi][ks] = *(const bf16x8*)&Bs[(wc * 64 + mi * 16 + l15) * 72 + g * 8 + ks * 32];
            }
#pragma unroll
        for (int ks = 0; ks < 2; ++ks)
#pragma unroll
            for (int mi = 0; mi < 4; ++mi)
#pragma unroll
                for (int ni = 0; ni < 4; ++ni)
                    acc[mi][ni] = __builtin_amdgcn_mfma_f32_16x16x32_bf16(af[mi][ks], bfr[ni][ks], acc[mi][ni], 0, 0, 0);
    }

#pragma unroll
    for (int mi = 0; mi < 4; ++mi) {
#pragma unroll
        for (int ni = 0; ni < 4; ++ni) {
#pragma unroll
            for (int r = 0; r < 4; ++r) {
                int row = row0 + wr * 64 + mi * 16 + g * 4 + r;
                int col = col0 + wc * 64 + ni * 16 + l15;
                float v = acc[mi][ni][r];
                if (bias) v += bias[col];
                if (act == 1) v = gelu_f(v);
                if (resid) v += resid[(long)bz * sR + (long)row * ldr + col];
                if (C32) C32[(long)bz * sC32 + (long)row * ldc32 + col] = v;
                if (C16) C16[(long)bz * sC16 + (long)row * ldc16 + col] = f2b(v);
            }
        }
    }
}

// ---------------------------------------------------------------------------
// Flash-style MFMA attention (see round 2 description).
// ---------------------------------------------------------------------------
template <int D>
__global__ __launch_bounds__(256)
void attn_mfma(unsigned short* __restrict__ qkv, int stride, int koff, int voff, float scale)
{
    constexpr int LQ = D + 8;
    constexpr int LK = D + 8;
    constexpr int LV = 64 + 8;
    constexpr int LP = 64 + 8;
    constexpr int NKS = D / 32;
    constexpr int NF = D / 16;
    constexpr int GR = D / 8;

    __shared__ unsigned short Ks[64 * LK];
    __shared__ unsigned short Vt[D * LV];
    __shared__ unsigned short QP[64 * LQ];

    int b = blockIdx.z, h = blockIdx.y, qt = blockIdx.x;
    int t = threadIdx.x, w = t >> 6, l = t & 63, l15 = l & 15, g = l >> 4;
    long qbase = ((long)b * NS + qt * 64) * stride + h * D;
    long kvbase = (long)b * NS * stride + h * D;

    for (int gi = t; gi < 64 * GR; gi += 256) {
        int r = gi / GR, sg = gi % GR;
        *(uint4*)&QP[r * LQ + sg * 8] = *(const uint4*)&qkv[qbase + (long)r * stride + sg * 8];
    }
    __syncthreads();
    bf16x8 qreg[NKS];
#pragma unroll
    for (int ks = 0; ks < NKS; ++ks)
        qreg[ks] = *(const bf16x8*)&QP[(w * 16 + l15) * LQ + g * 8 + ks * 32];
    __syncthreads();

    float m_run = -INFINITY, l_run = 0.f;
    f32x4 zero4 = {0.f, 0.f, 0.f, 0.f};
    f32x4 oacc[NF];
#pragma unroll
    for (int nf = 0; nf < NF; ++nf) oacc[nf] = zero4;

    for (int kt = 0; kt < NS / 64; ++kt) {
        __syncthreads();
        for (int gi = t; gi < 64 * GR; gi += 256) {
            int r = gi / GR, sg = gi % GR;
            *(uint4*)&Ks[r * LK + sg * 8] =
                *(const uint4*)&qkv[kvbase + (long)(kt * 64 + r) * stride + koff + sg * 8];
        }
        for (int gi = t; gi < 64 * GR; gi += 256) {
            int kc = gi & 63, sg = gi >> 6;
            uint4 v = *(const uint4*)&qkv[kvbase + (long)(kt * 64 + kc) * stride + voff + sg * 8];
            Vt[(sg * 8 + 0) * LV + kc] = (unsigned short)(v.x & 0xffff);
            Vt[(sg * 8 + 1) * LV + kc] = (unsigned short)(v.x >> 16);
            Vt[(sg * 8 + 2) * LV + kc] = (unsigned short)(v.y & 0xffff);
            Vt[(sg * 8 + 3) * LV + kc] = (unsigned short)(v.y >> 16);
            Vt[(sg * 8 + 4) * LV + kc] = (unsigned short)(v.z & 0xffff);
            Vt[(sg * 8 + 5) * LV + kc] = (unsigned short)(v.z >> 16);
            Vt[(sg * 8 + 6) * LV + kc] = (unsigned short)(v.w & 0xffff);
            Vt[(sg * 8 + 7) * LV + kc] = (unsigned short)(v.w >> 16);
        }
        __syncthreads();

        f32x4 st[4];
#pragma unroll
        for (int f = 0; f < 4; ++f) st[f] = zero4;
#pragma unroll
        for (int ks = 0; ks < NKS; ++ks) {
#pragma unroll
            for (int f = 0; f < 4; ++f) {
                bf16x8 a = *(const bf16x8*)&Ks[(f * 16 + l15) * LK + g * 8 + ks * 32];
                st[f] = __builtin_amdgcn_mfma_f32_16x16x32_bf16(a, qreg[ks], st[f], 0, 0, 0);
            }
        }
        float stv[4][4];
        float pm = -INFINITY;
#pragma unroll
        for (int f = 0; f < 4; ++f)
#pragma unroll
            for (int r = 0; r < 4; ++r) {
                float v = st[f][r] * scale;
                stv[f][r] = v;
                pm = fmaxf(pm, v);
            }
        pm = fmaxf(pm, __shfl_xor(pm, 16));
        pm = fmaxf(pm, __shfl_xor(pm, 32));
        float m_new = fmaxf(m_run, pm);
        float corr = __expf(m_run - m_new);
        float rs = 0.f;
        float pv[4][4];
#pragma unroll
        for (int f = 0; f < 4; ++f)
#pragma unroll
            for (int r = 0; r < 4; ++r) {
                float p = __expf(stv[f][r] - m_new);
                pv[f][r] = p;
                rs += p;
            }
        rs += __shfl_xor(rs, 16);
        rs += __shfl_xor(rs, 32);
        l_run = l_run * corr + rs;
        m_run = m_new;
#pragma unroll
        for (int f = 0; f < 4; ++f) {
            ushort4 pw;
            pw.x = f2b(pv[f][0]); pw.y = f2b(pv[f][1]);
            pw.z = f2b(pv[f][2]); pw.w = f2b(pv[f][3]);
            *(ushort4*)&QP[(w * 16 + l15) * LP + f * 16 + g * 4] = pw;
        }
        float corrO[4];
#pragma unroll
        for (int r = 0; r < 4; ++r) corrO[r] = __shfl(corr, g * 4 + r);
#pragma unroll
        for (int nf = 0; nf < NF; ++nf)
#pragma unroll
            for (int r = 0; r < 4; ++r) oacc[nf][r] *= corrO[r];
#pragma unroll
        for (int ks2 = 0; ks2 < 2; ++ks2) {
            bf16x8 pa = *(const bf16x8*)&QP[(w * 16 + l15) * LP + ks2 * 32 + g * 8];
#pragma unroll
            for (int nf = 0; nf < NF; ++nf) {
                bf16x8 vb = *(const bf16x8*)&Vt[(nf * 16 + l15) * LV + ks2 * 32 + g * 8];
                oacc[nf] = __builtin_amdgcn_mfma_f32_16x16x32_bf16(pa, vb, oacc[nf], 0, 0, 0);
            }
        }
    }
    float lo[4];
#pragma unroll
    for (int r = 0; r < 4; ++r) lo[r] = __shfl(l_run, g * 4 + r);
#pragma unroll
    for (int nf = 0; nf < NF; ++nf)
#pragma unroll
        for (int r = 0; r < 4; ++r) {
            float o = oacc[nf][r] / lo[r];
            qkv[qbase + (long)(w * 16 + g * 4 + r) * stride + nf * 16 + l15] = f2b(o);
        }
}

// ---------------------------------------------------------------------------
// part_aff[(b*8+sc)*256+n] = max over 128 s of affin[b, sc*128+s, n]
// ---------------------------------------------------------------------------
__global__ __launch_bounds__(256)
void maxpart_aff_kernel(const float* __restrict__ aff, float* __restrict__ part)
{
    int sc = blockIdx.x, b = blockIdx.y, t = threadIdx.x;
    float m = -INFINITY;
    for (int s = sc * 128; s < (sc + 1) * 128; ++s)
        m = fmaxf(m, aff[((long)b * NS + s) * NIN + t]);
    part[(b * 8 + sc) * NIN + t] = m;
}

// ---------------------------------------------------------------------------
// Fused routing: combine partial maxes -> logits -> softmax -> rank-select
// top-128 -> weights. Slot = rank (unique) => output order == jax top_k.
// ---------------------------------------------------------------------------
__global__ __launch_bounds__(256)
void rank_input_kernel(const float* __restrict__ part, int* __restrict__ idx_out,
                       float* __restrict__ w_out)
{
    int b = blockIdx.x, t = threadIdx.x;
    __shared__ float lg[256], rv[256];
    float m = part[(b * 8) * NIN + t];
#pragma unroll
    for (int sc = 1; sc < 8; ++sc) m = fmaxf(m, part[(b * 8 + sc) * NIN + t]);
    float l = m * 0.5f;  // / TEMP
    lg[t] = l;
    rv[t] = l;
    __syncthreads();
    for (int off = 128; off; off >>= 1) {
        if (t < off) rv[t] = fmaxf(rv[t], rv[t + off]);
        __syncthreads();
    }
    float mx = rv[0];
    __syncthreads();
    float e = expf(l - mx);
    rv[t] = e;
    __syncthreads();
    for (int off = 128; off; off >>= 1) {
        if (t < off) rv[t] += rv[t + off];
        __syncthreads();
    }
    float Zs = rv[0];
    float soft = e / Zs;
    __syncthreads();
    int rank = 0;
    for (int j = 0; j < 256; ++j) {
        float vj = lg[j];
        rank += (vj > l) || (vj == l && j < t);
    }
    rv[t] = (rank < KIN) ? soft : 0.f;
    __syncthreads();
    for (int off = 128; off; off >>= 1) {
        if (t < off) rv[t] += rv[t + off];
        __syncthreads();
    }
    float msum = rv[0];
    if (rank < KIN) {
        idx_out[b * KIN + rank] = t;
        w_out[b * KIN + rank] = soft / (msum + 1e-8f);
    }
}

// ---------------------------------------------------------------------------
// rank-select top-256 of 512 (set + jax ordering via slot=rank)
// ---------------------------------------------------------------------------
__global__ __launch_bounds__(512)
void rank_proc_kernel(const float* __restrict__ finals, int* __restrict__ pidx)
{
    int b = blockIdx.x, t = threadIdx.x;
    __shared__ float v[512];
    float xv = finals[b * NPROC + t];
    v[t] = xv;
    __syncthreads();
    int rank = 0;
    for (int j = 0; j < 512; ++j) {
        float vj = v[j];
        rank += (vj > xv) || (vj == xv && j < t);
    }
    if (rank < KPROC) pidx[b * KPROC + rank] = t;
}

__global__ __launch_bounds__(256)
void ln_kernel(const float* __restrict__ a, const float* __restrict__ bsrc,
               const float* __restrict__ gg, const float* __restrict__ be,
               float* __restrict__ out)
{
    long row = blockIdx.x;
    int t = threadIdx.x;
    float v = a[row * 256 + t] + bsrc[row * 256 + t];
    __shared__ float rv[256];
    rv[t] = v;
    __syncthreads();
    for (int off = 128; off; off >>= 1) {
        if (t < off) rv[t] += rv[t + off];
        __syncthreads();
    }
    float mean = rv[0] * (1.f / 256.f);
    __syncthreads();
    float d = v - mean;
    rv[t] = d * d;
    __syncthreads();
    for (int off = 128; off; off >>= 1) {
        if (t < off) rv[t] += rv[t + off];
        __syncthreads();
    }
    float var = rv[0] * (1.f / 256.f);
    out[row * 256 + t] = d * rsqrtf(var + 1e-5f) * gg[t] + be[t];
}

__global__ void gather_sel_acts_b(const float* __restrict__ acts, const int* __restrict__ idx_in,
                                  const float* __restrict__ w_sel, unsigned short* __restrict__ sel_acts)
{
    int s = blockIdx.x, b = blockIdx.y, j = threadIdx.x;
    long row = (long)b * NS + s;
    int id = idx_in[b * KIN + j];
    sel_acts[row * KIN + j] = f2b(acts[row * NIN + id] * w_sel[b * KIN + j]);
}

__global__ void gather_sel_cw_b(const float* __restrict__ comb_w, const int* __restrict__ idx_in,
                                unsigned short* __restrict__ sel_cw)
{
    int gidx = blockIdx.x * 256 + threadIdx.x;
    int b = gidx >> 16;
    int rem = gidx & 65535;
    int pb = rem >> 7, j = rem & 127;
    sel_cw[gidx] = f2b(comb_w[pb * NIN + idx_in[b * KIN + j]]);
}

__global__ void gather_sel_proc_b(const float* __restrict__ proc_acts, const int* __restrict__ pidx,
                                  unsigned short* __restrict__ sel_proc)
{
    int s = blockIdx.x, b = blockIdx.y, j = threadIdx.x;
    long row = (long)b * NS + s;
    sel_proc[row * KPROC + j] = f2b(proc_acts[row * NPROC + pidx[b * KPROC + j]]);
}

__global__ void gather_sel_projT(const float* __restrict__ out_proj_w, const int* __restrict__ pidx,
                                 unsigned short* __restrict__ selT)
{
    int gidx = blockIdx.x * 256 + threadIdx.x;
    int b = gidx >> 15;
    int rem = gidx & 32767;
    int d = rem >> 5;
    int kp0 = (rem & 31) * 8;
    unsigned int u[4];
#pragma unroll
    for (int i = 0; i < 4; ++i) {
        unsigned short e0 = f2b(out_proj_w[(long)pidx[b * KPROC + kp0 + 2 * i] * ND + d]);
        unsigned short e1 = f2b(out_proj_w[(long)pidx[b * KPROC + kp0 + 2 * i + 1] * ND + d]);
        u[i] = (unsigned int)e0 | ((unsigned int)e1 << 16);
    }
    uint4 o; o.x = u[0]; o.y = u[1]; o.z = u[2]; o.w = u[3];
    *(uint4*)&selT[((long)b * ND + d) * KPROC + kp0] = o;
}

__global__ __launch_bounds__(512)
void maxpart_kernel(const float* __restrict__ proc, float* __restrict__ part)
{
    int sc = blockIdx.x, b = blockIdx.y, t = threadIdx.x;
    float m = -INFINITY;
    for (int s = sc * 128; s < (sc + 1) * 128; ++s)
        m = fmaxf(m, proc[((long)b * NS + s) * NPROC + t]);
    part[(b * 8 + sc) * NPROC + t] = m;
}

__global__ __launch_bounds__(512)
void relevance_kernel(const float* __restrict__ part, const int* __restrict__ idx_in,
                      const float* __restrict__ a1w, const float* __restrict__ a1b,
                      const float* __restrict__ a2w, const float* __restrict__ a2b,
                      float* __restrict__ finals)
{
    int b = blockIdx.x, t = threadIdx.x;
    float m = part[(b * 8) * NPROC + t];
#pragma unroll
    for (int sc = 1; sc < 8; ++sc) m = fmaxf(m, part[(b * 8 + sc) * NPROC + t]);
    __shared__ float rel1[512];
    __shared__ int sidx[KIN];
    if (t < KIN) sidx[t] = idx_in[b * KIN + t];
    __syncthreads();
    float r1 = a1b[t];
    const float* a1row = a1w + (long)t * NIN;
    for (int j = 0; j < KIN; ++j) r1 += a1row[sidx[j]];
    rel1[t] = gelu_f(r1);
    __syncthreads();
    float r = a2b[t];
    const float* a2row = a2w + (long)t * 512;
    for (int hh = 0; hh < 512; ++hh) r += rel1[hh] * a2row[hh];
    float sig = 1.f / (1.f + expf(-r));
    finals[b * NPROC + t] = m * sig;
}

// ---------------------------------------------------------------------------
extern "C" void kernel_launch(void* const* d_in, const int* in_sizes, int n_in,
                              void* d_out, int out_size, void* d_ws, size_t ws_size,
                              hipStream_t stream)
{
    const float* x       = (const float*)d_in[0];
    const float* r_in_w  = (const float*)d_in[1];
    const float* r_in_b  = (const float*)d_in[2];
    const float* r_out_w = (const float*)d_in[3];
    const float* r_out_b = (const float*)d_in[4];
    const float* aff_w   = (const float*)d_in[5];
    const float* aff_b   = (const float*)d_in[6];
    const float* patterns= (const float*)d_in[7];
    const float* i_in_w  = (const float*)d_in[8];
    const float* i_in_b  = (const float*)d_in[9];
    const float* i_out_w = (const float*)d_in[10];
    const float* i_out_b = (const float*)d_in[11];
    const float* ln_g    = (const float*)d_in[12];
    const float* ln_b    = (const float*)d_in[13];
    const float* comb_w  = (const float*)d_in[14];
    const float* out_proj_w = (const float*)d_in[15];
    const float* a1w     = (const float*)d_in[16];
    const float* a1b     = (const float*)d_in[17];
    const float* a2w     = (const float*)d_in[18];
    const float* a2b     = (const float*)d_in[19];
    float* out = (float*)d_out;

    char* ws = (char*)d_ws;
    unsigned short* qkv1b    = (unsigned short*)(ws + 0);
    unsigned short* contextb = (unsigned short*)(ws + 50331648);
    unsigned short* xb       = (unsigned short*)(ws + 67108864);
    unsigned short* w_rin_b  = (unsigned short*)(ws + 83886080);
    unsigned short* w_rout_b = (unsigned short*)(ws + 90177536);
    unsigned short* w_aff_b  = (unsigned short*)(ws + 92274688);
    unsigned short* patt_b   = (unsigned short*)(ws + 92798976);
    unsigned short* w_iin_b  = (unsigned short*)(ws + 93323264);
    unsigned short* w_iout_b = (unsigned short*)(ws + 93716480);
    float* scoresb = (float*)(ws + 93847552);   // unused (kept for layout)
    float* w_sel   = (float*)(ws + 93855744);
    int*   idx_in  = (int*)(ws + 93859840);
    float* finals  = (float*)(ws + 93863936);
    int*   pidx    = (int*)(ws + 93880320);
    float* maxpart = (float*)(ws + 93888512);
    float* affin   = (float*)(ws + 94019584);
    float* acts0   = (float*)(ws + 102408192);
    unsigned short* acts0b = (unsigned short*)(ws + 110796800);
    unsigned short* qkv2b  = (unsigned short*)(ws + 114991104);
    float* attn2proj = (float*)(ws + 0);
    float* acts      = (float*)(ws + 8388608);
    float* proc_acts = (float*)(ws + 16777216);
    unsigned short* sel_actsb = (unsigned short*)(ws + 33554432);
    unsigned short* sel_cwb   = (unsigned short*)(ws + 35651584);
    unsigned short* sel_procb = (unsigned short*)(ws + 36700160);
    unsigned short* sel_projT = (unsigned short*)(ws + 40894464);
    float* part_aff = (float*)(ws + 45088768);  // 8*8*256 floats = 64 KiB (free region)
    (void)scoresb;

    cvt_kernel<<<2048, 256, 0, stream>>>(x, xb, (long)NB * NS * ND / 4);
    cvt_kernel<<<1024, 256, 0, stream>>>(r_in_w, w_rin_b, (long)3 * ND * ND / 4);
    cvt_kernel<<<512, 256, 0, stream>>>(r_out_w, w_rout_b, (long)ND * ND / 4);
    cvt_kernel<<<128, 256, 0, stream>>>(aff_w, w_aff_b, (long)NIN * ND / 4);
    cvt_kernel<<<128, 256, 0, stream>>>(patterns, patt_b, (long)NIN * ND / 4);
    cvt_kernel<<<96, 256, 0, stream>>>(i_in_w, w_iin_b, (long)3 * NIN * NIN / 4);
    cvt_kernel<<<32, 256, 0, stream>>>(i_out_w, w_iout_b, (long)NIN * NIN / 4);

    gemm_bf16<<<dim3(24, 64, 1), 256, 0, stream>>>(
        xb, 0, ND, w_rin_b, 0, ND, r_in_b, nullptr, 0, 0,
        nullptr, 0, 0, qkv1b, 0, 3 * ND, NB * NS, 3 * ND, ND, 0);
    attn_mfma<128><<<dim3(16, 8, 8), 256, 0, stream>>>(qkv1b, 3 * ND, ND, 2 * ND, 0.088388347648318447f);
    gemm_bf16<<<dim3(8, 64, 1), 256, 0, stream>>>(
        qkv1b, 0, 3 * ND, w_rout_b, 0, ND, r_out_b, nullptr, 0, 0,
        nullptr, 0, 0, contextb, 0, ND, NB * NS, ND, ND, 0);
    gemm_bf16<<<dim3(2, 64, 1), 256, 0, stream>>>(
        contextb, 0, ND, w_aff_b, 0, ND, aff_b, nullptr, 0, 0,
        affin, 0, NIN, nullptr, 0, 0, NB * NS, NIN, ND, 0);
    maxpart_aff_kernel<<<dim3(8, NB), 256, 0, stream>>>(affin, part_aff);
    rank_input_kernel<<<NB, 256, 0, stream>>>(part_aff, idx_in, w_sel);
    gemm_bf16<<<dim3(2, 64, 1), 256, 0, stream>>>(
        contextb, 0, ND, patt_b, 0, ND, nullptr, nullptr, 0, 0,
        acts0, 0, NIN, acts0b, 0, NIN, NB * NS, NIN, ND, 1);
    gemm_bf16<<<dim3(6, 64, 1), 256, 0, stream>>>(
        acts0b, 0, NIN, w_iin_b, 0, NIN, i_in_b, nullptr, 0, 0,
        nullptr, 0, 0, qkv2b, 0, 3 * NIN, NB * NS, 3 * NIN, NIN, 0);
    attn_mfma<64><<<dim3(16, 4, 8), 256, 0, stream>>>(qkv2b, 3 * NIN, NIN, 2 * NIN, 0.125f);
    gemm_bf16<<<dim3(2, 64, 1), 256, 0, stream>>>(
        qkv2b, 0, 3 * NIN, w_iout_b, 0, NIN, i_out_b, nullptr, 0, 0,
        attn2proj, 0, NIN, nullptr, 0, 0, NB * NS, NIN, NIN, 0);
    ln_kernel<<<NB * NS, 256, 0, stream>>>(acts0, attn2proj, ln_g, ln_b, acts);
    gather_sel_acts_b<<<dim3(NS, NB), KIN, 0, stream>>>(acts, idx_in, w_sel, sel_actsb);
    gather_sel_cw_b<<<2048, 256, 0, stream>>>(comb_w, idx_in, sel_cwb);
    gemm_bf16<<<dim3(4, 8, NB), 256, 0, stream>>>(
        sel_actsb, (long)NS * KIN, KIN, sel_cwb, (long)NPROC * KIN, KIN,
        nullptr, nullptr, 0, 0,
        proc_acts, (long)NS * NPROC, NPROC, nullptr, 0, 0, NS, NPROC, KIN, 1);
    maxpart_kernel<<<dim3(8, NB), 512, 0, stream>>>(proc_acts, maxpart);
    relevance_kernel<<<NB, 512, 0, stream>>>(maxpart, idx_in, a1w, a1b, a2w, a2b, finals);
    rank_proc_kernel<<<NB, 512, 0, stream>>>(finals, pidx);
    gather_sel_proc_b<<<dim3(NS, NB), KPROC, 0, stream>>>(proc_acts, pidx, sel_procb);
    gather_sel_projT<<<1024, 256, 0, stream>>>(out_proj_w, pidx, sel_projT);
    gemm_bf16<<<dim3(8, 8, NB), 256, 0, stream>>>(
        sel_procb, (long)NS * KPROC, KPROC, sel_projT, (long)ND * KPROC, KPROC,
        nullptr, x, (long)NS * ND, ND,
        out, (long)NS * ND, ND, nullptr, 0, 0, NS, ND, KPROC, 0);
    (void)in_sizes; (void)n_in; (void)out_size; (void)ws_size;
}

// Round 5
// 603.645 us; speedup vs baseline: 9.2114x; 1.0882x over previous
//
#include <hip/hip_runtime.h>
#include <hip/hip_bf16.h>
#include <math.h>

constexpr int NB = 8, NS = 1024, ND = 1024, NIN = 256, NPROC = 512, KIN = 128, KPROC = 256;

typedef __attribute__((ext_vector_type(8))) short bf16x8;
typedef __attribute__((ext_vector_type(4))) float f32x4;

__device__ inline float gelu_f(float x) {
    return 0.5f * x * (1.0f + erff(x * 0.7071067811865476f));
}
__device__ inline unsigned short f2b(float f) {
    __hip_bfloat16 h = __float2bfloat16(f);
    return *reinterpret_cast<unsigned short*>(&h);
}
__device__ inline void gload16(const void* g, void* l) {
    __builtin_amdgcn_global_load_lds(
        (const __attribute__((address_space(1))) void*)g,
        (__attribute__((address_space(3))) void*)l, 16, 0, 0);
}

// ---------------------------------------------------------------------------
__global__ void cvt_kernel(const float* __restrict__ in, unsigned short* __restrict__ out, long n4)
{
    long i = (long)blockIdx.x * blockDim.x + threadIdx.x;
    long stride = (long)gridDim.x * blockDim.x;
    for (; i < n4; i += stride) {
        float4 v = ((const float4*)in)[i];
        ushort4 o;
        o.x = f2b(v.x); o.y = f2b(v.y); o.z = f2b(v.z); o.w = f2b(v.w);
        ((ushort4*)out)[i] = o;
    }
}

// ---------------------------------------------------------------------------
// bf16 MFMA GEMM, m97 structure: linear LDS + global_load_lds width 16.
// C = act(A @ B^T + bias) + resid.  A:[M,K] lda, B:[N,K] ldb.
// 128x128 tile, BK=64, 4 waves (2x2), 16x16x32 MFMA.
// ---------------------------------------------------------------------------
__global__ __launch_bounds__(256)
void gemm_bf16(const unsigned short* __restrict__ A, long sA, int lda,
               const unsigned short* __restrict__ B, long sB, int ldb,
               const float* __restrict__ bias,
               const float* __restrict__ resid, long sR, int ldr,
               float* __restrict__ C32, long sC32, int ldc32,
               unsigned short* __restrict__ C16, long sC16, int ldc16,
               int M, int N, int K, int act)
{
    __shared__ __align__(16) unsigned short As[128 * 64];
    __shared__ __align__(16) unsigned short Bs[128 * 64];
    int bz = blockIdx.z;
    const unsigned short* Ab = A + (long)bz * sA;
    const unsigned short* Bb = B + (long)bz * sB;
    int row0 = blockIdx.y * 128, col0 = blockIdx.x * 128;
    int t = threadIdx.x;
    int w = t >> 6, l = t & 63, l15 = l & 15, g = l >> 4;
    int wr = w >> 1, wc = w & 1;
    int srow = l >> 3;          // 0..7 row within chunk
    int scol = (l & 7) * 8;     // elem col offset
    f32x4 zero4 = {0.f, 0.f, 0.f, 0.f};
    f32x4 acc[4][4];
#pragma unroll
    for (int i = 0; i < 4; ++i)
#pragma unroll
        for (int j = 0; j < 4; ++j) acc[i][j] = zero4;

    for (int k0 = 0; k0 < K; k0 += 64) {
        __syncthreads();
#pragma unroll
        for (int c = 0; c < 4; ++c) {
            int r = w * 32 + c * 8;
            gload16(&Ab[(long)(row0 + r + srow) * lda + k0 + scol], &As[r * 64]);
            gload16(&Bb[(long)(col0 + r + srow) * ldb + k0 + scol], &Bs[r * 64]);
        }
        __syncthreads();
        bf16x8 af[4][2], bfr[4][2];
#pragma unroll
        for (int mi = 0; mi < 4; ++mi)
#pragma unroll
            for (int ks = 0; ks < 2; ++ks) {
                af[mi][ks] = *(const bf16x8*)&As[(wr * 64 + mi * 16 + l15) * 64 + g * 8 + ks * 32];
                bfr[mi][ks] = *(const bf16x8*)&Bs[(wc * 64 + mi * 16 + l15) * 64 + g * 8 + ks * 32];
            }
#pragma unroll
        for (int ks = 0; ks < 2; ++ks)
#pragma unroll
            for (int mi = 0; mi < 4; ++mi)
#pragma unroll
                for (int ni = 0; ni < 4; ++ni)
                    acc[mi][ni] = __builtin_amdgcn_mfma_f32_16x16x32_bf16(af[mi][ks], bfr[ni][ks], acc[mi][ni], 0, 0, 0);
    }

#pragma unroll
    for (int mi = 0; mi < 4; ++mi) {
#pragma unroll
        for (int ni = 0; ni < 4; ++ni) {
#pragma unroll
            for (int r = 0; r < 4; ++r) {
                int row = row0 + wr * 64 + mi * 16 + g * 4 + r;
                int col = col0 + wc * 64 + ni * 16 + l15;
                float v = acc[mi][ni][r];
                if (bias) v += bias[col];
                if (act == 1) v = gelu_f(v);
                if (resid) v += resid[(long)bz * sR + (long)row * ldr + col];
                if (C32) C32[(long)bz * sC32 + (long)row * ldc32 + col] = v;
                if (C16) C16[(long)bz * sC16 + (long)row * ldc16 + col] = f2b(v);
            }
        }
    }
}

// ---------------------------------------------------------------------------
// Flash-style MFMA attention, q-tile 128, 8 waves (512 thr), kv-tile 64.
// Q fragments direct from global; K/V next-tile prefetched to regs during
// compute (async-stage split); V stored transposed in LDS for the PV MFMA.
// Output overwrites the q slots (bf16).
// ---------------------------------------------------------------------------
template <int D>
__global__ __launch_bounds__(512, 4)
void attn_mfma(unsigned short* __restrict__ qkv, int stride, int koff, int voff, float scale)
{
    constexpr int LK = D + 8;    // Ks pitch (16B-aligned rows)
    constexpr int LV = 72;       // Vt pitch
    constexpr int LP = 72;       // Ps pitch
    constexpr int NKS = D / 32;
    constexpr int NF = D / 16;
    constexpr int GR = D / 8;             // 16B granules per row
    constexpr int NIT = (64 * GR) / 512;  // staging iters (2 for D=128, 1 for D=64)
    constexpr int NT = NS / 64;

    __shared__ __align__(16) unsigned short Ks[64 * LK];
    __shared__ __align__(16) unsigned short Vt[D * LV];
    __shared__ __align__(16) unsigned short Ps[128 * LP];

    int b = blockIdx.z, h = blockIdx.y, qt = blockIdx.x;
    int t = threadIdx.x, w = t >> 6, l = t & 63, l15 = l & 15, g = l >> 4;
    long qbase = ((long)b * NS + qt * 128) * stride + h * D;
    long kvbase = (long)b * NS * stride + h * D;

    // Q fragments direct to registers
    bf16x8 qreg[NKS];
#pragma unroll
    for (int ks = 0; ks < NKS; ++ks)
        qreg[ks] = *(const bf16x8*)&qkv[qbase + (long)(w * 16 + l15) * stride + g * 8 + ks * 32];

    // stage tile 0
#pragma unroll
    for (int i = 0; i < NIT; ++i) {
        int gi = t + i * 512;
        int r = gi / GR, sg = gi % GR;
        *(uint4*)&Ks[r * LK + sg * 8] = *(const uint4*)&qkv[kvbase + (long)r * stride + koff + sg * 8];
    }
#pragma unroll
    for (int i = 0; i < NIT; ++i) {
        int gi = t + i * 512;
        int kc = gi & 63, sg = gi >> 6;
        uint4 v = *(const uint4*)&qkv[kvbase + (long)kc * stride + voff + sg * 8];
        Vt[(sg * 8 + 0) * LV + kc] = (unsigned short)(v.x & 0xffff);
        Vt[(sg * 8 + 1) * LV + kc] = (unsigned short)(v.x >> 16);
        Vt[(sg * 8 + 2) * LV + kc] = (unsigned short)(v.y & 0xffff);
        Vt[(sg * 8 + 3) * LV + kc] = (unsigned short)(v.y >> 16);
        Vt[(sg * 8 + 4) * LV + kc] = (unsigned short)(v.z & 0xffff);
        Vt[(sg * 8 + 5) * LV + kc] = (unsigned short)(v.z >> 16);
        Vt[(sg * 8 + 6) * LV + kc] = (unsigned short)(v.w & 0xffff);
        Vt[(sg * 8 + 7) * LV + kc] = (unsigned short)(v.w >> 16);
    }
    __syncthreads();

    float m_run = -INFINITY, l_run = 0.f;
    f32x4 zero4 = {0.f, 0.f, 0.f, 0.f};
    f32x4 oacc[NF];
#pragma unroll
    for (int nf = 0; nf < NF; ++nf) oacc[nf] = zero4;

    for (int kt = 0; kt < NT; ++kt) {
        // prefetch next kv-tile to registers (lands during compute)
        uint4 kp[NIT], vp[NIT];
        bool pre = (kt + 1 < NT);
        if (pre) {
            long kb = (long)(kt + 1) * 64;
#pragma unroll
            for (int i = 0; i < NIT; ++i) {
                int gi = t + i * 512;
                int r = gi / GR, sg = gi % GR;
                kp[i] = *(const uint4*)&qkv[kvbase + (kb + r) * stride + koff + sg * 8];
            }
#pragma unroll
            for (int i = 0; i < NIT; ++i) {
                int gi = t + i * 512;
                int kc = gi & 63, sg = gi >> 6;
                vp[i] = *(const uint4*)&qkv[kvbase + (kb + kc) * stride + voff + sg * 8];
            }
        }

        // St = K · Q^T (col = q, row = kc)
        f32x4 st[4];
#pragma unroll
        for (int f = 0; f < 4; ++f) st[f] = zero4;
#pragma unroll
        for (int ks = 0; ks < NKS; ++ks) {
#pragma unroll
            for (int f = 0; f < 4; ++f) {
                bf16x8 a = *(const bf16x8*)&Ks[(f * 16 + l15) * LK + g * 8 + ks * 32];
                st[f] = __builtin_amdgcn_mfma_f32_16x16x32_bf16(a, qreg[ks], st[f], 0, 0, 0);
            }
        }
        // online softmax over kc for q-col (w*16+l15)
        float pm = -INFINITY;
#pragma unroll
        for (int f = 0; f < 4; ++f) {
            st[f] *= scale;
#pragma unroll
            for (int r = 0; r < 4; ++r) pm = fmaxf(pm, st[f][r]);
        }
        pm = fmaxf(pm, __shfl_xor(pm, 16));
        pm = fmaxf(pm, __shfl_xor(pm, 32));
        float m_new = fmaxf(m_run, pm);
        float corr = __expf(m_run - m_new);
        float rs = 0.f;
#pragma unroll
        for (int f = 0; f < 4; ++f) {
            float p0 = __expf(st[f][0] - m_new);
            float p1 = __expf(st[f][1] - m_new);
            float p2 = __expf(st[f][2] - m_new);
            float p3 = __expf(st[f][3] - m_new);
            rs += (p0 + p1) + (p2 + p3);
            ushort4 pw;
            pw.x = f2b(p0); pw.y = f2b(p1); pw.z = f2b(p2); pw.w = f2b(p3);
            *(ushort4*)&Ps[(w * 16 + l15) * LP + f * 16 + g * 4] = pw;
        }
        rs += __shfl_xor(rs, 16);
        rs += __shfl_xor(rs, 32);
        l_run = l_run * corr + rs;
        m_run = m_new;
        // rescale O rows (row q = 16w+4g+r; stats keyed by l15)
        float corrO[4];
#pragma unroll
        for (int r = 0; r < 4; ++r) corrO[r] = __shfl(corr, g * 4 + r);
#pragma unroll
        for (int nf = 0; nf < NF; ++nf)
#pragma unroll
            for (int r = 0; r < 4; ++r) oacc[nf][r] *= corrO[r];
        // PV: A = Ps (q rows, kc fast), B = Vt (d rows, kc fast)
#pragma unroll
        for (int ks2 = 0; ks2 < 2; ++ks2) {
            bf16x8 pa = *(const bf16x8*)&Ps[(w * 16 + l15) * LP + ks2 * 32 + g * 8];
#pragma unroll
            for (int nf = 0; nf < NF; ++nf) {
                bf16x8 vb = *(const bf16x8*)&Vt[(nf * 16 + l15) * LV + ks2 * 32 + g * 8];
                oacc[nf] = __builtin_amdgcn_mfma_f32_16x16x32_bf16(pa, vb, oacc[nf], 0, 0, 0);
            }
        }
        __syncthreads();
        if (pre) {
#pragma unroll
            for (int i = 0; i < NIT; ++i) {
                int gi = t + i * 512;
                int r = gi / GR, sg = gi % GR;
                *(uint4*)&Ks[r * LK + sg * 8] = kp[i];
            }
#pragma unroll
            for (int i = 0; i < NIT; ++i) {
                int gi = t + i * 512;
                int kc = gi & 63, sg = gi >> 6;
                uint4 v = vp[i];
                Vt[(sg * 8 + 0) * LV + kc] = (unsigned short)(v.x & 0xffff);
                Vt[(sg * 8 + 1) * LV + kc] = (unsigned short)(v.x >> 16);
                Vt[(sg * 8 + 2) * LV + kc] = (unsigned short)(v.y & 0xffff);
                Vt[(sg * 8 + 3) * LV + kc] = (unsigned short)(v.y >> 16);
                Vt[(sg * 8 + 4) * LV + kc] = (unsigned short)(v.z & 0xffff);
                Vt[(sg * 8 + 5) * LV + kc] = (unsigned short)(v.z >> 16);
                Vt[(sg * 8 + 6) * LV + kc] = (unsigned short)(v.w & 0xffff);
                Vt[(sg * 8 + 7) * LV + kc] = (unsigned short)(v.w >> 16);
            }
        }
        __syncthreads();
    }
    float lo[4];
#pragma unroll
    for (int r = 0; r < 4; ++r) lo[r] = __shfl(l_run, g * 4 + r);
#pragma unroll
    for (int nf = 0; nf < NF; ++nf)
#pragma unroll
        for (int r = 0; r < 4; ++r) {
            float o = oacc[nf][r] / lo[r];
            qkv[qbase + (long)(w * 16 + g * 4 + r) * stride + nf * 16 + l15] = f2b(o);
        }
}

// ---------------------------------------------------------------------------
__global__ __launch_bounds__(256)
void maxpart_aff_kernel(const float* __restrict__ aff, float* __restrict__ part)
{
    int sc = blockIdx.x, b = blockIdx.y, t = threadIdx.x;
    float m = -INFINITY;
    for (int s = sc * 128; s < (sc + 1) * 128; ++s)
        m = fmaxf(m, aff[((long)b * NS + s) * NIN + t]);
    part[(b * 8 + sc) * NIN + t] = m;
}

__global__ __launch_bounds__(256)
void rank_input_kernel(const float* __restrict__ part, int* __restrict__ idx_out,
                       float* __restrict__ w_out)
{
    int b = blockIdx.x, t = threadIdx.x;
    __shared__ float lg[256], rv[256];
    float m = part[(b * 8) * NIN + t];
#pragma unroll
    for (int sc = 1; sc < 8; ++sc) m = fmaxf(m, part[(b * 8 + sc) * NIN + t]);
    float l = m * 0.5f;  // / TEMP
    lg[t] = l;
    rv[t] = l;
    __syncthreads();
    for (int off = 128; off; off >>= 1) {
        if (t < off) rv[t] = fmaxf(rv[t], rv[t + off]);
        __syncthreads();
    }
    float mx = rv[0];
    __syncthreads();
    float e = expf(l - mx);
    rv[t] = e;
    __syncthreads();
    for (int off = 128; off; off >>= 1) {
        if (t < off) rv[t] += rv[t + off];
        __syncthreads();
    }
    float Zs = rv[0];
    float soft = e / Zs;
    __syncthreads();
    int rank = 0;
    for (int j = 0; j < 256; ++j) {
        float vj = lg[j];
        rank += (vj > l) || (vj == l && j < t);
    }
    rv[t] = (rank < KIN) ? soft : 0.f;
    __syncthreads();
    for (int off = 128; off; off >>= 1) {
        if (t < off) rv[t] += rv[t + off];
        __syncthreads();
    }
    float msum = rv[0];
    if (rank < KIN) {
        idx_out[b * KIN + rank] = t;
        w_out[b * KIN + rank] = soft / (msum + 1e-8f);
    }
}

__global__ __launch_bounds__(512)
void rank_proc_kernel(const float* __restrict__ finals, int* __restrict__ pidx)
{
    int b = blockIdx.x, t = threadIdx.x;
    __shared__ float v[512];
    float xv = finals[b * NPROC + t];
    v[t] = xv;
    __syncthreads();
    int rank = 0;
    for (int j = 0; j < 512; ++j) {
        float vj = v[j];
        rank += (vj > xv) || (vj == xv && j < t);
    }
    if (rank < KPROC) pidx[b * KPROC + rank] = t;
}

// ---------------------------------------------------------------------------
// Fused LN(acts0 + attn2proj) + routed gather: sel_acts[row][j] =
// bf16(LN(...)[idx[j]] * w_sel[j]). Drops the acts buffer entirely.
// ---------------------------------------------------------------------------
__global__ __launch_bounds__(256)
void ln_gather_kernel(const float* __restrict__ a, const float* __restrict__ bsrc,
                      const float* __restrict__ gg, const float* __restrict__ be,
                      const int* __restrict__ idx_in, const float* __restrict__ w_sel,
                      unsigned short* __restrict__ sel_acts)
{
    long row = blockIdx.x;
    int b = blockIdx.x >> 10;  // NS = 1024
    int t = threadIdx.x;
    float v = a[row * 256 + t] + bsrc[row * 256 + t];
    __shared__ float rv[256];
    __shared__ float lnv[256];
    rv[t] = v;
    __syncthreads();
    for (int off = 128; off; off >>= 1) {
        if (t < off) rv[t] += rv[t + off];
        __syncthreads();
    }
    float mean = rv[0] * (1.f / 256.f);
    __syncthreads();
    float d = v - mean;
    rv[t] = d * d;
    __syncthreads();
    for (int off = 128; off; off >>= 1) {
        if (t < off) rv[t] += rv[t + off];
        __syncthreads();
    }
    float var = rv[0] * (1.f / 256.f);
    lnv[t] = d * rsqrtf(var + 1e-5f) * gg[t] + be[t];
    __syncthreads();
    if (t < KIN) {
        int id = idx_in[b * KIN + t];
        sel_acts[row * KIN + t] = f2b(lnv[id] * w_sel[b * KIN + t]);
    }
}

__global__ void gather_sel_cw_b(const float* __restrict__ comb_w, const int* __restrict__ idx_in,
                                unsigned short* __restrict__ sel_cw)
{
    int gidx = blockIdx.x * 256 + threadIdx.x;
    int b = gidx >> 16;
    int rem = gidx & 65535;
    int pb = rem >> 7, j = rem & 127;
    sel_cw[gidx] = f2b(comb_w[pb * NIN + idx_in[b * KIN + j]]);
}

__global__ void gather_sel_proc_b(const float* __restrict__ proc_acts, const int* __restrict__ pidx,
                                  unsigned short* __restrict__ sel_proc)
{
    int s = blockIdx.x, b = blockIdx.y, j = threadIdx.x;
    long row = (long)b * NS + s;
    sel_proc[row * KPROC + j] = f2b(proc_acts[row * NPROC + pidx[b * KPROC + j]]);
}

__global__ void gather_sel_projT(const float* __restrict__ out_proj_w, const int* __restrict__ pidx,
                                 unsigned short* __restrict__ selT)
{
    int gidx = blockIdx.x * 256 + threadIdx.x;
    int b = gidx >> 15;
    int rem = gidx & 32767;
    int d = rem >> 5;
    int kp0 = (rem & 31) * 8;
    unsigned int u[4];
#pragma unroll
    for (int i = 0; i < 4; ++i) {
        unsigned short e0 = f2b(out_proj_w[(long)pidx[b * KPROC + kp0 + 2 * i] * ND + d]);
        unsigned short e1 = f2b(out_proj_w[(long)pidx[b * KPROC + kp0 + 2 * i + 1] * ND + d]);
        u[i] = (unsigned int)e0 | ((unsigned int)e1 << 16);
    }
    uint4 o; o.x = u[0]; o.y = u[1]; o.z = u[2]; o.w = u[3];
    *(uint4*)&selT[((long)b * ND + d) * KPROC + kp0] = o;
}

__global__ __launch_bounds__(512)
void maxpart_kernel(const float* __restrict__ proc, float* __restrict__ part)
{
    int sc = blockIdx.x, b = blockIdx.y, t = threadIdx.x;
    float m = -INFINITY;
    for (int s = sc * 128; s < (sc + 1) * 128; ++s)
        m = fmaxf(m, proc[((long)b * NS + s) * NPROC + t]);
    part[(b * 8 + sc) * NPROC + t] = m;
}

__global__ __launch_bounds__(512)
void relevance_kernel(const float* __restrict__ part, const int* __restrict__ idx_in,
                      const float* __restrict__ a1w, const float* __restrict__ a1b,
                      const float* __restrict__ a2w, const float* __restrict__ a2b,
                      float* __restrict__ finals)
{
    int b = blockIdx.x, t = threadIdx.x;
    float m = part[(b * 8) * NPROC + t];
#pragma unroll
    for (int sc = 1; sc < 8; ++sc) m = fmaxf(m, part[(b * 8 + sc) * NPROC + t]);
    __shared__ float rel1[512];
    __shared__ int sidx[KIN];
    if (t < KIN) sidx[t] = idx_in[b * KIN + t];
    __syncthreads();
    float r1 = a1b[t];
    const float* a1row = a1w + (long)t * NIN;
    for (int j = 0; j < KIN; ++j) r1 += a1row[sidx[j]];
    rel1[t] = gelu_f(r1);
    __syncthreads();
    float r = a2b[t];
    const float* a2row = a2w + (long)t * 512;
    for (int hh = 0; hh < 512; ++hh) r += rel1[hh] * a2row[hh];
    float sig = 1.f / (1.f + expf(-r));
    finals[b * NPROC + t] = m * sig;
}

// ---------------------------------------------------------------------------
extern "C" void kernel_launch(void* const* d_in, const int* in_sizes, int n_in,
                              void* d_out, int out_size, void* d_ws, size_t ws_size,
                              hipStream_t stream)
{
    const float* x       = (const float*)d_in[0];
    const float* r_in_w  = (const float*)d_in[1];
    const float* r_in_b  = (const float*)d_in[2];
    const float* r_out_w = (const float*)d_in[3];
    const float* r_out_b = (const float*)d_in[4];
    const float* aff_w   = (const float*)d_in[5];
    const float* aff_b   = (const float*)d_in[6];
    const float* patterns= (const float*)d_in[7];
    const float* i_in_w  = (const float*)d_in[8];
    const float* i_in_b  = (const float*)d_in[9];
    const float* i_out_w = (const float*)d_in[10];
    const float* i_out_b = (const float*)d_in[11];
    const float* ln_g    = (const float*)d_in[12];
    const float* ln_b    = (const float*)d_in[13];
    const float* comb_w  = (const float*)d_in[14];
    const float* out_proj_w = (const float*)d_in[15];
    const float* a1w     = (const float*)d_in[16];
    const float* a1b     = (const float*)d_in[17];
    const float* a2w     = (const float*)d_in[18];
    const float* a2b     = (const float*)d_in[19];
    float* out = (float*)d_out;

    char* ws = (char*)d_ws;
    unsigned short* qkv1b    = (unsigned short*)(ws + 0);
    unsigned short* contextb = (unsigned short*)(ws + 50331648);
    unsigned short* xb       = (unsigned short*)(ws + 67108864);
    unsigned short* w_rin_b  = (unsigned short*)(ws + 83886080);
    unsigned short* w_rout_b = (unsigned short*)(ws + 90177536);
    unsigned short* w_aff_b  = (unsigned short*)(ws + 92274688);
    unsigned short* patt_b   = (unsigned short*)(ws + 92798976);
    unsigned short* w_iin_b  = (unsigned short*)(ws + 93323264);
    unsigned short* w_iout_b = (unsigned short*)(ws + 93716480);
    float* w_sel   = (float*)(ws + 93855744);
    int*   idx_in  = (int*)(ws + 93859840);
    float* finals  = (float*)(ws + 93863936);
    int*   pidx    = (int*)(ws + 93880320);
    float* maxpart = (float*)(ws + 93888512);
    float* affin   = (float*)(ws + 94019584);
    float* acts0   = (float*)(ws + 102408192);
    unsigned short* acts0b = (unsigned short*)(ws + 110796800);
    unsigned short* qkv2b  = (unsigned short*)(ws + 114991104);
    float* attn2proj = (float*)(ws + 0);
    float* proc_acts = (float*)(ws + 16777216);
    unsigned short* sel_actsb = (unsigned short*)(ws + 33554432);
    unsigned short* sel_cwb   = (unsigned short*)(ws + 35651584);
    unsigned short* sel_procb = (unsigned short*)(ws + 36700160);
    unsigned short* sel_projT = (unsigned short*)(ws + 40894464);
    float* part_aff = (float*)(ws + 45088768);

    cvt_kernel<<<2048, 256, 0, stream>>>(x, xb, (long)NB * NS * ND / 4);
    cvt_kernel<<<1024, 256, 0, stream>>>(r_in_w, w_rin_b, (long)3 * ND * ND / 4);
    cvt_kernel<<<512, 256, 0, stream>>>(r_out_w, w_rout_b, (long)ND * ND / 4);
    cvt_kernel<<<128, 256, 0, stream>>>(aff_w, w_aff_b, (long)NIN * ND / 4);
    cvt_kernel<<<128, 256, 0, stream>>>(patterns, patt_b, (long)NIN * ND / 4);
    cvt_kernel<<<96, 256, 0, stream>>>(i_in_w, w_iin_b, (long)3 * NIN * NIN / 4);
    cvt_kernel<<<32, 256, 0, stream>>>(i_out_w, w_iout_b, (long)NIN * NIN / 4);

    gemm_bf16<<<dim3(24, 64, 1), 256, 0, stream>>>(
        xb, 0, ND, w_rin_b, 0, ND, r_in_b, nullptr, 0, 0,
        nullptr, 0, 0, qkv1b, 0, 3 * ND, NB * NS, 3 * ND, ND, 0);
    attn_mfma<128><<<dim3(8, 8, 8), 512, 0, stream>>>(qkv1b, 3 * ND, ND, 2 * ND, 0.088388347648318447f);
    gemm_bf16<<<dim3(8, 64, 1), 256, 0, stream>>>(
        qkv1b, 0, 3 * ND, w_rout_b, 0, ND, r_out_b, nullptr, 0, 0,
        nullptr, 0, 0, contextb, 0, ND, NB * NS, ND, ND, 0);
    gemm_bf16<<<dim3(2, 64, 1), 256, 0, stream>>>(
        contextb, 0, ND, w_aff_b, 0, ND, aff_b, nullptr, 0, 0,
        affin, 0, NIN, nullptr, 0, 0, NB * NS, NIN, ND, 0);
    maxpart_aff_kernel<<<dim3(8, NB), 256, 0, stream>>>(affin, part_aff);
    rank_input_kernel<<<NB, 256, 0, stream>>>(part_aff, idx_in, w_sel);
    gemm_bf16<<<dim3(2, 64, 1), 256, 0, stream>>>(
        contextb, 0, ND, patt_b, 0, ND, nullptr, nullptr, 0, 0,
        acts0, 0, NIN, acts0b, 0, NIN, NB * NS, NIN, ND, 1);
    gemm_bf16<<<dim3(6, 64, 1), 256, 0, stream>>>(
        acts0b, 0, NIN, w_iin_b, 0, NIN, i_in_b, nullptr, 0, 0,
        nullptr, 0, 0, qkv2b, 0, 3 * NIN, NB * NS, 3 * NIN, NIN, 0);
    attn_mfma<64><<<dim3(8, 4, 8), 512, 0, stream>>>(qkv2b, 3 * NIN, NIN, 2 * NIN, 0.125f);
    gemm_bf16<<<dim3(2, 64, 1), 256, 0, stream>>>(
        qkv2b, 0, 3 * NIN, w_iout_b, 0, NIN, i_out_b, nullptr, 0, 0,
        attn2proj, 0, NIN, nullptr, 0, 0, NB * NS, NIN, NIN, 0);
    ln_gather_kernel<<<NB * NS, 256, 0, stream>>>(acts0, attn2proj, ln_g, ln_b,
                                                  idx_in, w_sel, sel_actsb);
    gather_sel_cw_b<<<2048, 256, 0, stream>>>(comb_w, idx_in, sel_cwb);
    gemm_bf16<<<dim3(4, 8, NB), 256, 0, stream>>>(
        sel_actsb, (long)NS * KIN, KIN, sel_cwb, (long)NPROC * KIN, KIN,
        nullptr, nullptr, 0, 0,
        proc_acts, (long)NS * NPROC, NPROC, nullptr, 0, 0, NS, NPROC, KIN, 1);
    maxpart_kernel<<<dim3(8, NB), 512, 0, stream>>>(proc_acts, maxpart);
    relevance_kernel<<<NB, 512, 0, stream>>>(maxpart, idx_in, a1w, a1b, a2w, a2b, finals);
    rank_proc_kernel<<<NB, 512, 0, stream>>>(finals, pidx);
    gather_sel_proc_b<<<dim3(NS, NB), KPROC, 0, stream>>>(proc_acts, pidx, sel_procb);
    gather_sel_projT<<<1024, 256, 0, stream>>>(out_proj_w, pidx, sel_projT);
    gemm_bf16<<<dim3(8, 8, NB), 256, 0, stream>>>(
        sel_procb, (long)NS * KPROC, KPROC, sel_projT, (long)ND * KPROC, KPROC,
        nullptr, x, (long)NS * ND, ND,
        out, (long)NS * ND, ND, nullptr, 0, 0, NS, ND, KPROC, 0);
    (void)in_sizes; (void)n_in; (void)out_size; (void)ws_size;
}

// Round 6
// 570.565 us; speedup vs baseline: 9.7455x; 1.0580x over previous
//
#include <hip/hip_runtime.h>
#include <hip/hip_bf16.h>
#include <math.h>

constexpr int NB = 8, NS = 1024, ND = 1024, NIN = 256, NPROC = 512, KIN = 128, KPROC = 256;

typedef __attribute__((ext_vector_type(8))) short bf16x8;
typedef __attribute__((ext_vector_type(4))) float f32x4;

__device__ inline float gelu_f(float x) {
    return 0.5f * x * (1.0f + erff(x * 0.7071067811865476f));
}
__device__ inline unsigned short f2b(float f) {
    __hip_bfloat16 h = __float2bfloat16(f);
    return *reinterpret_cast<unsigned short*>(&h);
}
__device__ inline void gload16(const void* g, void* l) {
    __builtin_amdgcn_global_load_lds(
        (const __attribute__((address_space(1))) void*)g,
        (__attribute__((address_space(3))) void*)l, 16, 0, 0);
}

// ---------------------------------------------------------------------------
__global__ void cvt_kernel(const float* __restrict__ in, unsigned short* __restrict__ out, long n4)
{
    long i = (long)blockIdx.x * blockDim.x + threadIdx.x;
    long stride = (long)gridDim.x * blockDim.x;
    for (; i < n4; i += stride) {
        float4 v = ((const float4*)in)[i];
        ushort4 o;
        o.x = f2b(v.x); o.y = f2b(v.y); o.z = f2b(v.z); o.w = f2b(v.w);
        ((ushort4*)out)[i] = o;
    }
}

// ---------------------------------------------------------------------------
// 256x256 bf16 MFMA GEMM, counted-vmcnt pipeline (T2+T4+T5 + XCD swizzle).
// C16 = A @ B^T + bias. A:[M,K] lda, B:[N,K] ldb. Grid = 1D (M/256)*(N/256),
// must be divisible by 8. K%64==0, K>=128. 8 waves (2Mx4N), 128KiB LDS.
// LDS layout: linear [256][64] per buffer (gload_lds), reads XOR-swizzled
// with pre-swizzled global source (both-sides-or-neither rule).
// ---------------------------------------------------------------------------
__global__ __launch_bounds__(512, 2)
void gemm256(const unsigned short* __restrict__ A, int lda,
             const unsigned short* __restrict__ B, int ldb,
             const float* __restrict__ bias,
             unsigned short* __restrict__ C16, int ldc,
             int K, int nbx)
{
    __shared__ __align__(16) unsigned short Abuf[2][256 * 64];
    __shared__ __align__(16) unsigned short Bbuf[2][256 * 64];
    int o = blockIdx.x;
    int cpx = gridDim.x >> 3;
    int swz = (o & 7) * cpx + (o >> 3);
    int by = swz / nbx, bx = swz - by * nbx;
    int row0 = by * 256, col0 = bx * 256;

    int t = threadIdx.x;
    int w = t >> 6, l = t & 63, l15 = l & 15, g = l >> 4;
    int wr = w >> 2, wn = w & 3;
    int srow = l >> 3;              // staging row within 8-row group
    int sgr = (l & 7) ^ srow;       // pre-swizzled source 16B-granule
    int xr = (l15 & 7) << 4;        // read-side XOR (bytes)
    int NT = K >> 6;

    f32x4 acc[8][4];
#pragma unroll
    for (int i = 0; i < 8; ++i)
#pragma unroll
        for (int j = 0; j < 4; ++j) acc[i][j] = (f32x4){0.f, 0.f, 0.f, 0.f};

    const unsigned short* Asrc = A + (long)row0 * lda + sgr * 8;
    const unsigned short* Bsrc = B + (long)col0 * ldb + sgr * 8;

    auto STAGE = [&](int c, int kt) {
        int k0 = kt * 64;
#pragma unroll
        for (int j = 0; j < 4; ++j) {
            int r = j * 64 + w * 8;
            gload16(&Asrc[(long)(r + srow) * lda + k0], &Abuf[c][r * 64]);
        }
#pragma unroll
        for (int j = 0; j < 4; ++j) {
            int r = j * 64 + w * 8;
            gload16(&Bsrc[(long)(r + srow) * ldb + k0], &Bbuf[c][r * 64]);
        }
    };

    STAGE(0, 0);
    STAGE(1, 1);

    for (int T = 0; T < NT; ++T) {
        int c = T & 1;
        if (T + 1 < NT) { asm volatile("s_waitcnt vmcnt(8)" ::: "memory"); }
        else            { asm volatile("s_waitcnt vmcnt(0)" ::: "memory"); }
        __builtin_amdgcn_s_barrier();
        asm volatile("" ::: "memory");

        bf16x8 bfr[4][2];
#pragma unroll
        for (int ni = 0; ni < 4; ++ni)
#pragma unroll
            for (int ks = 0; ks < 2; ++ks) {
                int row = wn * 64 + ni * 16 + l15;
                int cb = (g * 16 + ks * 64) ^ xr;
                bfr[ni][ks] = *(const bf16x8*)((const char*)&Bbuf[c][0] + row * 128 + cb);
            }
#pragma unroll
        for (int q = 0; q < 4; ++q) {
            bf16x8 afr[2][2];
#pragma unroll
            for (int m2 = 0; m2 < 2; ++m2)
#pragma unroll
                for (int ks = 0; ks < 2; ++ks) {
                    int row = wr * 128 + (q * 2 + m2) * 16 + l15;
                    int cb = (g * 16 + ks * 64) ^ xr;
                    afr[m2][ks] = *(const bf16x8*)((const char*)&Abuf[c][0] + row * 128 + cb);
                }
            if (q == 3) {
                // all reads of buf c complete across waves, then refill it
                asm volatile("s_waitcnt lgkmcnt(0)" ::: "memory");
                __builtin_amdgcn_sched_barrier(0);
                __builtin_amdgcn_s_barrier();
                asm volatile("" ::: "memory");
                if (T + 2 < NT) STAGE(c, T + 2);
            }
            __builtin_amdgcn_s_setprio(1);
#pragma unroll
            for (int ks = 0; ks < 2; ++ks)
#pragma unroll
                for (int m2 = 0; m2 < 2; ++m2)
#pragma unroll
                    for (int ni = 0; ni < 4; ++ni)
                        acc[q * 2 + m2][ni] = __builtin_amdgcn_mfma_f32_16x16x32_bf16(
                            afr[m2][ks], bfr[ni][ks], acc[q * 2 + m2][ni], 0, 0, 0);
            __builtin_amdgcn_s_setprio(0);
        }
    }

    // epilogue: pair adjacent cols (lanes) -> dword bf16 stores
#pragma unroll
    for (int mi = 0; mi < 8; ++mi) {
#pragma unroll
        for (int ni = 0; ni < 4; ++ni) {
            int col = col0 + wn * 64 + ni * 16 + l15;
            float bv = bias ? bias[col] : 0.f;
#pragma unroll
            for (int r = 0; r < 4; ++r) {
                int row = row0 + wr * 128 + mi * 16 + g * 4 + r;
                float v = acc[mi][ni][r] + bv;
                float vp = __shfl_xor(v, 1);
                if (!(l15 & 1)) {
                    unsigned int u = (unsigned int)f2b(v) | ((unsigned int)f2b(vp) << 16);
                    *(unsigned int*)&C16[(long)row * ldc + col] = u;
                }
            }
        }
    }
}

// ---------------------------------------------------------------------------
// bf16 MFMA GEMM, m97 structure (128x128, BK=64, 4 waves, gload_lds).
// act: 0 none, 1 gelu, 2 split@256 (col<256 -> C32; col>=256 -> gelu -> C32b+C16)
// ---------------------------------------------------------------------------
__global__ __launch_bounds__(256)
void gemm_bf16(const unsigned short* __restrict__ A, long sA, int lda,
               const unsigned short* __restrict__ B, long sB, int ldb,
               const float* __restrict__ bias,
               const float* __restrict__ resid, long sR, int ldr,
               float* __restrict__ C32, long sC32, int ldc32,
               unsigned short* __restrict__ C16, long sC16, int ldc16,
               float* __restrict__ C32b, int ldc32b,
               int M, int N, int K, int act)
{
    __shared__ __align__(16) unsigned short As[128 * 64];
    __shared__ __align__(16) unsigned short Bs[128 * 64];
    int bz = blockIdx.z;
    const unsigned short* Ab = A + (long)bz * sA;
    const unsigned short* Bb = B + (long)bz * sB;
    int row0 = blockIdx.y * 128, col0 = blockIdx.x * 128;
    int t = threadIdx.x;
    int w = t >> 6, l = t & 63, l15 = l & 15, g = l >> 4;
    int wr = w >> 1, wc = w & 1;
    int srow = l >> 3;
    int scol = (l & 7) * 8;
    f32x4 zero4 = {0.f, 0.f, 0.f, 0.f};
    f32x4 acc[4][4];
#pragma unroll
    for (int i = 0; i < 4; ++i)
#pragma unroll
        for (int j = 0; j < 4; ++j) acc[i][j] = zero4;

    for (int k0 = 0; k0 < K; k0 += 64) {
        __syncthreads();
#pragma unroll
        for (int c = 0; c < 4; ++c) {
            int r = w * 32 + c * 8;
            gload16(&Ab[(long)(row0 + r + srow) * lda + k0 + scol], &As[r * 64]);
            gload16(&Bb[(long)(col0 + r + srow) * ldb + k0 + scol], &Bs[r * 64]);
        }
        __syncthreads();
        bf16x8 af[4][2], bfr[4][2];
#pragma unroll
        for (int mi = 0; mi < 4; ++mi)
#pragma unroll
            for (int ks = 0; ks < 2; ++ks) {
                af[mi][ks] = *(const bf16x8*)&As[(wr * 64 + mi * 16 + l15) * 64 + g * 8 + ks * 32];
                bfr[mi][ks] = *(const bf16x8*)&Bs[(wc * 64 + mi * 16 + l15) * 64 + g * 8 + ks * 32];
            }
#pragma unroll
        for (int ks = 0; ks < 2; ++ks)
#pragma unroll
            for (int mi = 0; mi < 4; ++mi)
#pragma unroll
                for (int ni = 0; ni < 4; ++ni)
                    acc[mi][ni] = __builtin_amdgcn_mfma_f32_16x16x32_bf16(af[mi][ks], bfr[ni][ks], acc[mi][ni], 0, 0, 0);
    }

#pragma unroll
    for (int mi = 0; mi < 4; ++mi) {
#pragma unroll
        for (int ni = 0; ni < 4; ++ni) {
#pragma unroll
            for (int r = 0; r < 4; ++r) {
                int row = row0 + wr * 64 + mi * 16 + g * 4 + r;
                int col = col0 + wc * 64 + ni * 16 + l15;
                float v = acc[mi][ni][r];
                if (bias) v += bias[col];
                if (act == 2) {
                    if (col < 256) {
                        C32[(long)row * ldc32 + col] = v;
                    } else {
                        v = gelu_f(v);
                        C32b[(long)row * ldc32b + (col - 256)] = v;
                        C16[(long)row * ldc16 + (col - 256)] = f2b(v);
                    }
                    continue;
                }
                if (act == 1) v = gelu_f(v);
                if (resid) v += resid[(long)bz * sR + (long)row * ldr + col];
                if (C32) C32[(long)bz * sC32 + (long)row * ldc32 + col] = v;
                if (C16) C16[(long)bz * sC16 + (long)row * ldc16 + col] = f2b(v);
            }
        }
    }
}

// ---------------------------------------------------------------------------
// Flash-style MFMA attention, q-tile 128, 8 waves, kv-tile 64, reg prefetch.
// ---------------------------------------------------------------------------
template <int D>
__global__ __launch_bounds__(512, 4)
void attn_mfma(unsigned short* __restrict__ qkv, int stride, int koff, int voff, float scale)
{
    constexpr int LK = D + 8;
    constexpr int LV = 72;
    constexpr int LP = 72;
    constexpr int NKS = D / 32;
    constexpr int NF = D / 16;
    constexpr int GR = D / 8;
    constexpr int NIT = (64 * GR) / 512;
    constexpr int NT = NS / 64;

    __shared__ __align__(16) unsigned short Ks[64 * LK];
    __shared__ __align__(16) unsigned short Vt[D * LV];
    __shared__ __align__(16) unsigned short Ps[128 * LP];

    int b = blockIdx.z, h = blockIdx.y, qt = blockIdx.x;
    int t = threadIdx.x, w = t >> 6, l = t & 63, l15 = l & 15, g = l >> 4;
    long qbase = ((long)b * NS + qt * 128) * stride + h * D;
    long kvbase = (long)b * NS * stride + h * D;

    bf16x8 qreg[NKS];
#pragma unroll
    for (int ks = 0; ks < NKS; ++ks)
        qreg[ks] = *(const bf16x8*)&qkv[qbase + (long)(w * 16 + l15) * stride + g * 8 + ks * 32];

#pragma unroll
    for (int i = 0; i < NIT; ++i) {
        int gi = t + i * 512;
        int r = gi / GR, sg = gi % GR;
        *(uint4*)&Ks[r * LK + sg * 8] = *(const uint4*)&qkv[kvbase + (long)r * stride + koff + sg * 8];
    }
#pragma unroll
    for (int i = 0; i < NIT; ++i) {
        int gi = t + i * 512;
        int kc = gi & 63, sg = gi >> 6;
        uint4 v = *(const uint4*)&qkv[kvbase + (long)kc * stride + voff + sg * 8];
        Vt[(sg * 8 + 0) * LV + kc] = (unsigned short)(v.x & 0xffff);
        Vt[(sg * 8 + 1) * LV + kc] = (unsigned short)(v.x >> 16);
        Vt[(sg * 8 + 2) * LV + kc] = (unsigned short)(v.y & 0xffff);
        Vt[(sg * 8 + 3) * LV + kc] = (unsigned short)(v.y >> 16);
        Vt[(sg * 8 + 4) * LV + kc] = (unsigned short)(v.z & 0xffff);
        Vt[(sg * 8 + 5) * LV + kc] = (unsigned short)(v.z >> 16);
        Vt[(sg * 8 + 6) * LV + kc] = (unsigned short)(v.w & 0xffff);
        Vt[(sg * 8 + 7) * LV + kc] = (unsigned short)(v.w >> 16);
    }
    __syncthreads();

    float m_run = -INFINITY, l_run = 0.f;
    f32x4 zero4 = {0.f, 0.f, 0.f, 0.f};
    f32x4 oacc[NF];
#pragma unroll
    for (int nf = 0; nf < NF; ++nf) oacc[nf] = zero4;

    for (int kt = 0; kt < NT; ++kt) {
        uint4 kp[NIT], vp[NIT];
        bool pre = (kt + 1 < NT);
        if (pre) {
            long kb = (long)(kt + 1) * 64;
#pragma unroll
            for (int i = 0; i < NIT; ++i) {
                int gi = t + i * 512;
                int r = gi / GR, sg = gi % GR;
                kp[i] = *(const uint4*)&qkv[kvbase + (kb + r) * stride + koff + sg * 8];
            }
#pragma unroll
            for (int i = 0; i < NIT; ++i) {
                int gi = t + i * 512;
                int kc = gi & 63, sg = gi >> 6;
                vp[i] = *(const uint4*)&qkv[kvbase + (kb + kc) * stride + voff + sg * 8];
            }
        }

        f32x4 st[4];
#pragma unroll
        for (int f = 0; f < 4; ++f) st[f] = zero4;
#pragma unroll
        for (int ks = 0; ks < NKS; ++ks) {
#pragma unroll
            for (int f = 0; f < 4; ++f) {
                bf16x8 a = *(const bf16x8*)&Ks[(f * 16 + l15) * LK + g * 8 + ks * 32];
                st[f] = __builtin_amdgcn_mfma_f32_16x16x32_bf16(a, qreg[ks], st[f], 0, 0, 0);
            }
        }
        float pm = -INFINITY;
#pragma unroll
        for (int f = 0; f < 4; ++f) {
            st[f] *= scale;
#pragma unroll
            for (int r = 0; r < 4; ++r) pm = fmaxf(pm, st[f][r]);
        }
        pm = fmaxf(pm, __shfl_xor(pm, 16));
        pm = fmaxf(pm, __shfl_xor(pm, 32));
        float m_new = fmaxf(m_run, pm);
        float corr = __expf(m_run - m_new);
        float rs = 0.f;
#pragma unroll
        for (int f = 0; f < 4; ++f) {
            float p0 = __expf(st[f][0] - m_new);
            float p1 = __expf(st[f][1] - m_new);
            float p2 = __expf(st[f][2] - m_new);
            float p3 = __expf(st[f][3] - m_new);
            rs += (p0 + p1) + (p2 + p3);
            ushort4 pw;
            pw.x = f2b(p0); pw.y = f2b(p1); pw.z = f2b(p2); pw.w = f2b(p3);
            *(ushort4*)&Ps[(w * 16 + l15) * LP + f * 16 + g * 4] = pw;
        }
        rs += __shfl_xor(rs, 16);
        rs += __shfl_xor(rs, 32);
        l_run = l_run * corr + rs;
        m_run = m_new;
        float corrO[4];
#pragma unroll
        for (int r = 0; r < 4; ++r) corrO[r] = __shfl(corr, g * 4 + r);
#pragma unroll
        for (int nf = 0; nf < NF; ++nf)
#pragma unroll
            for (int r = 0; r < 4; ++r) oacc[nf][r] *= corrO[r];
#pragma unroll
        for (int ks2 = 0; ks2 < 2; ++ks2) {
            bf16x8 pa = *(const bf16x8*)&Ps[(w * 16 + l15) * LP + ks2 * 32 + g * 8];
#pragma unroll
            for (int nf = 0; nf < NF; ++nf) {
                bf16x8 vb = *(const bf16x8*)&Vt[(nf * 16 + l15) * LV + ks2 * 32 + g * 8];
                oacc[nf] = __builtin_amdgcn_mfma_f32_16x16x32_bf16(pa, vb, oacc[nf], 0, 0, 0);
            }
        }
        __syncthreads();
        if (pre) {
#pragma unroll
            for (int i = 0; i < NIT; ++i) {
                int gi = t + i * 512;
                int r = gi / GR, sg = gi % GR;
                *(uint4*)&Ks[r * LK + sg * 8] = kp[i];
            }
#pragma unroll
            for (int i = 0; i < NIT; ++i) {
                int gi = t + i * 512;
                int kc = gi & 63, sg = gi >> 6;
                uint4 v = vp[i];
                Vt[(sg * 8 + 0) * LV + kc] = (unsigned short)(v.x & 0xffff);
                Vt[(sg * 8 + 1) * LV + kc] = (unsigned short)(v.x >> 16);
                Vt[(sg * 8 + 2) * LV + kc] = (unsigned short)(v.y & 0xffff);
                Vt[(sg * 8 + 3) * LV + kc] = (unsigned short)(v.y >> 16);
                Vt[(sg * 8 + 4) * LV + kc] = (unsigned short)(v.z & 0xffff);
                Vt[(sg * 8 + 5) * LV + kc] = (unsigned short)(v.z >> 16);
                Vt[(sg * 8 + 6) * LV + kc] = (unsigned short)(v.w & 0xffff);
                Vt[(sg * 8 + 7) * LV + kc] = (unsigned short)(v.w >> 16);
            }
        }
        __syncthreads();
    }
    float lo[4];
#pragma unroll
    for (int r = 0; r < 4; ++r) lo[r] = __shfl(l_run, g * 4 + r);
#pragma unroll
    for (int nf = 0; nf < NF; ++nf)
#pragma unroll
        for (int r = 0; r < 4; ++r) {
            float o = oacc[nf][r] / lo[r];
            qkv[qbase + (long)(w * 16 + g * 4 + r) * stride + nf * 16 + l15] = f2b(o);
        }
}

// ---------------------------------------------------------------------------
__global__ __launch_bounds__(256)
void maxpart_aff_kernel(const float* __restrict__ aff, float* __restrict__ part)
{
    int sc = blockIdx.x, b = blockIdx.y, t = threadIdx.x;
    float m = -INFINITY;
    for (int s = sc * 128; s < (sc + 1) * 128; ++s)
        m = fmaxf(m, aff[((long)b * NS + s) * NIN + t]);
    part[(b * 8 + sc) * NIN + t] = m;
}

__global__ __launch_bounds__(256)
void rank_input_kernel(const float* __restrict__ part, int* __restrict__ idx_out,
                       float* __restrict__ w_out)
{
    int b = blockIdx.x, t = threadIdx.x;
    __shared__ float lg[256], rv[256];
    float m = part[(b * 8) * NIN + t];
#pragma unroll
    for (int sc = 1; sc < 8; ++sc) m = fmaxf(m, part[(b * 8 + sc) * NIN + t]);
    float l = m * 0.5f;
    lg[t] = l;
    rv[t] = l;
    __syncthreads();
    for (int off = 128; off; off >>= 1) {
        if (t < off) rv[t] = fmaxf(rv[t], rv[t + off]);
        __syncthreads();
    }
    float mx = rv[0];
    __syncthreads();
    float e = expf(l - mx);
    rv[t] = e;
    __syncthreads();
    for (int off = 128; off; off >>= 1) {
        if (t < off) rv[t] += rv[t + off];
        __syncthreads();
    }
    float Zs = rv[0];
    float soft = e / Zs;
    __syncthreads();
    int rank = 0;
    for (int j = 0; j < 256; ++j) {
        float vj = lg[j];
        rank += (vj > l) || (vj == l && j < t);
    }
    rv[t] = (rank < KIN) ? soft : 0.f;
    __syncthreads();
    for (int off = 128; off; off >>= 1) {
        if (t < off) rv[t] += rv[t + off];
        __syncthreads();
    }
    float msum = rv[0];
    if (rank < KIN) {
        idx_out[b * KIN + rank] = t;
        w_out[b * KIN + rank] = soft / (msum + 1e-8f);
    }
}

__global__ __launch_bounds__(512)
void rank_proc_kernel(const float* __restrict__ finals, int* __restrict__ pidx)
{
    int b = blockIdx.x, t = threadIdx.x;
    __shared__ float v[512];
    float xv = finals[b * NPROC + t];
    v[t] = xv;
    __syncthreads();
    int rank = 0;
    for (int j = 0; j < 512; ++j) {
        float vj = v[j];
        rank += (vj > xv) || (vj == xv && j < t);
    }
    if (rank < KPROC) pidx[b * KPROC + rank] = t;
}

__global__ __launch_bounds__(256)
void ln_gather_kernel(const float* __restrict__ a, const float* __restrict__ bsrc,
                      const float* __restrict__ gg, const float* __restrict__ be,
                      const int* __restrict__ idx_in, const float* __restrict__ w_sel,
                      unsigned short* __restrict__ sel_acts)
{
    long row = blockIdx.x;
    int b = blockIdx.x >> 10;
    int t = threadIdx.x;
    float v = a[row * 256 + t] + bsrc[row * 256 + t];
    __shared__ float rv[256];
    __shared__ float lnv[256];
    rv[t] = v;
    __syncthreads();
    for (int off = 128; off; off >>= 1) {
        if (t < off) rv[t] += rv[t + off];
        __syncthreads();
    }
    float mean = rv[0] * (1.f / 256.f);
    __syncthreads();
    float d = v - mean;
    rv[t] = d * d;
    __syncthreads();
    for (int off = 128; off; off >>= 1) {
        if (t < off) rv[t] += rv[t + off];
        __syncthreads();
    }
    float var = rv[0] * (1.f / 256.f);
    lnv[t] = d * rsqrtf(var + 1e-5f) * gg[t] + be[t];
    __syncthreads();
    if (t < KIN) {
        int id = idx_in[b * KIN + t];
        sel_acts[row * KIN + t] = f2b(lnv[id] * w_sel[b * KIN + t]);
    }
}

__global__ void gather_sel_cw_b(const float* __restrict__ comb_w, const int* __restrict__ idx_in,
                                unsigned short* __restrict__ sel_cw)
{
    int gidx = blockIdx.x * 256 + threadIdx.x;
    int b = gidx >> 16;
    int rem = gidx & 65535;
    int pb = rem >> 7, j = rem & 127;
    sel_cw[gidx] = f2b(comb_w[pb * NIN + idx_in[b * KIN + j]]);
}

__global__ void gather_sel_proc_b(const float* __restrict__ proc_acts, const int* __restrict__ pidx,
                                  unsigned short* __restrict__ sel_proc)
{
    int s = blockIdx.x, b = blockIdx.y, j = threadIdx.x;
    long row = (long)b * NS + s;
    sel_proc[row * KPROC + j] = f2b(proc_acts[row * NPROC + pidx[b * KPROC + j]]);
}

__global__ void gather_sel_projT(const float* __restrict__ out_proj_w, const int* __restrict__ pidx,
                                 unsigned short* __restrict__ selT)
{
    int gidx = blockIdx.x * 256 + threadIdx.x;
    int b = gidx >> 15;
    int rem = gidx & 32767;
    int d = rem >> 5;
    int kp0 = (rem & 31) * 8;
    unsigned int u[4];
#pragma unroll
    for (int i = 0; i < 4; ++i) {
        unsigned short e0 = f2b(out_proj_w[(long)pidx[b * KPROC + kp0 + 2 * i] * ND + d]);
        unsigned short e1 = f2b(out_proj_w[(long)pidx[b * KPROC + kp0 + 2 * i + 1] * ND + d]);
        u[i] = (unsigned int)e0 | ((unsigned int)e1 << 16);
    }
    uint4 o; o.x = u[0]; o.y = u[1]; o.z = u[2]; o.w = u[3];
    *(uint4*)&selT[((long)b * ND + d) * KPROC + kp0] = o;
}

__global__ __launch_bounds__(512)
void maxpart_kernel(const float* __restrict__ proc, float* __restrict__ part)
{
    int sc = blockIdx.x, b = blockIdx.y, t = threadIdx.x;
    float m = -INFINITY;
    for (int s = sc * 128; s < (sc + 1) * 128; ++s)
        m = fmaxf(m, proc[((long)b * NS + s) * NPROC + t]);
    part[(b * 8 + sc) * NPROC + t] = m;
}

__global__ __launch_bounds__(512)
void relevance_kernel(const float* __restrict__ part, const int* __restrict__ idx_in,
                      const float* __restrict__ a1w, const float* __restrict__ a1b,
                      const float* __restrict__ a2w, const float* __restrict__ a2b,
                      float* __restrict__ finals)
{
    int b = blockIdx.x, t = threadIdx.x;
    float m = part[(b * 8) * NPROC + t];
#pragma unroll
    for (int sc = 1; sc < 8; ++sc) m = fmaxf(m, part[(b * 8 + sc) * NPROC + t]);
    __shared__ float rel1[512];
    __shared__ int sidx[KIN];
    if (t < KIN) sidx[t] = idx_in[b * KIN + t];
    __syncthreads();
    float r1 = a1b[t];
    const float* a1row = a1w + (long)t * NIN;
    for (int j = 0; j < KIN; ++j) r1 += a1row[sidx[j]];
    rel1[t] = gelu_f(r1);
    __syncthreads();
    float r = a2b[t];
    const float* a2row = a2w + (long)t * 512;
    for (int hh = 0; hh < 512; ++hh) r += rel1[hh] * a2row[hh];
    float sig = 1.f / (1.f + expf(-r));
    finals[b * NPROC + t] = m * sig;
}

// ---------------------------------------------------------------------------
extern "C" void kernel_launch(void* const* d_in, const int* in_sizes, int n_in,
                              void* d_out, int out_size, void* d_ws, size_t ws_size,
                              hipStream_t stream)
{
    const float* x       = (const float*)d_in[0];
    const float* r_in_w  = (const float*)d_in[1];
    const float* r_in_b  = (const float*)d_in[2];
    const float* r_out_w = (const float*)d_in[3];
    const float* r_out_b = (const float*)d_in[4];
    const float* aff_w   = (const float*)d_in[5];
    const float* aff_b   = (const float*)d_in[6];
    const float* patterns= (const float*)d_in[7];
    const float* i_in_w  = (const float*)d_in[8];
    const float* i_in_b  = (const float*)d_in[9];
    const float* i_out_w = (const float*)d_in[10];
    const float* i_out_b = (const float*)d_in[11];
    const float* ln_g    = (const float*)d_in[12];
    const float* ln_b    = (const float*)d_in[13];
    const float* comb_w  = (const float*)d_in[14];
    const float* out_proj_w = (const float*)d_in[15];
    const float* a1w     = (const float*)d_in[16];
    const float* a1b     = (const float*)d_in[17];
    const float* a2w     = (const float*)d_in[18];
    const float* a2b     = (const float*)d_in[19];
    float* out = (float*)d_out;

    char* ws = (char*)d_ws;
    unsigned short* qkv1b    = (unsigned short*)(ws + 0);
    unsigned short* contextb = (unsigned short*)(ws + 50331648);
    unsigned short* xb       = (unsigned short*)(ws + 67108864);
    unsigned short* w_rin_b  = (unsigned short*)(ws + 83886080);
    unsigned short* w_rout_b = (unsigned short*)(ws + 90177536);
    unsigned short* w_aff_b  = (unsigned short*)(ws + 92274688);   // [aff_w; patterns] contiguous
    unsigned short* patt_b   = (unsigned short*)(ws + 92798976);
    unsigned short* w_iin_b  = (unsigned short*)(ws + 93323264);
    unsigned short* w_iout_b = (unsigned short*)(ws + 93716480);
    float* w_sel   = (float*)(ws + 93855744);
    int*   idx_in  = (int*)(ws + 93859840);
    float* finals  = (float*)(ws + 93863936);
    int*   pidx    = (int*)(ws + 93880320);
    float* maxpart = (float*)(ws + 93888512);
    float* affin   = (float*)(ws + 94019584);
    float* acts0   = (float*)(ws + 102408192);
    unsigned short* acts0b = (unsigned short*)(ws + 110796800);
    unsigned short* qkv2b  = (unsigned short*)(ws + 114991104);
    float* attn2proj = (float*)(ws + 0);
    float* proc_acts = (float*)(ws + 16777216);
    unsigned short* sel_actsb = (unsigned short*)(ws + 33554432);
    unsigned short* sel_cwb   = (unsigned short*)(ws + 35651584);
    unsigned short* sel_procb = (unsigned short*)(ws + 36700160);
    unsigned short* sel_projT = (unsigned short*)(ws + 40894464);
    float* part_aff = (float*)(ws + 45088768);
    float* biascat  = (float*)(ws + 45154304);  // 512 f32, dead-region overlay

    cvt_kernel<<<2048, 256, 0, stream>>>(x, xb, (long)NB * NS * ND / 4);
    cvt_kernel<<<1024, 256, 0, stream>>>(r_in_w, w_rin_b, (long)3 * ND * ND / 4);
    cvt_kernel<<<512, 256, 0, stream>>>(r_out_w, w_rout_b, (long)ND * ND / 4);
    cvt_kernel<<<128, 256, 0, stream>>>(aff_w, w_aff_b, (long)NIN * ND / 4);
    cvt_kernel<<<128, 256, 0, stream>>>(patterns, patt_b, (long)NIN * ND / 4);
    cvt_kernel<<<96, 256, 0, stream>>>(i_in_w, w_iin_b, (long)3 * NIN * NIN / 4);
    cvt_kernel<<<32, 256, 0, stream>>>(i_out_w, w_iout_b, (long)NIN * NIN / 4);

    // 1. qkv1 = x @ r_in_w^T + b  (256^2 pipelined GEMM; 384 blocks, %8==0)
    gemm256<<<384, 512, 0, stream>>>(xb, ND, w_rin_b, ND, r_in_b, qkv1b, 3 * ND, ND, 12);
    // 2. MHA-1
    attn_mfma<128><<<dim3(8, 8, 8), 512, 0, stream>>>(qkv1b, 3 * ND, ND, 2 * ND, 0.088388347648318447f);
    // 3. context
    gemm_bf16<<<dim3(8, 64, 1), 256, 0, stream>>>(
        qkv1b, 0, 3 * ND, w_rout_b, 0, ND, r_out_b, nullptr, 0, 0,
        nullptr, 0, 0, contextb, 0, ND, nullptr, 0, NB * NS, ND, ND, 0);
    // 4. fused affinity+patterns (N=512 split epilogue); biascat = [aff_b; 0]
    hipMemcpyAsync(biascat, aff_b, 256 * sizeof(float), hipMemcpyDeviceToDevice, stream);
    hipMemsetAsync(biascat + 256, 0, 256 * sizeof(float), stream);
    gemm_bf16<<<dim3(4, 64, 1), 256, 0, stream>>>(
        contextb, 0, ND, w_aff_b, 0, ND, biascat, nullptr, 0, 0,
        affin, 0, NIN, acts0b, 0, NIN, acts0, NIN, NB * NS, 2 * NIN, ND, 2);
    // 5. routing
    maxpart_aff_kernel<<<dim3(8, NB), 256, 0, stream>>>(affin, part_aff);
    rank_input_kernel<<<NB, 256, 0, stream>>>(part_aff, idx_in, w_sel);
    // 6. qkv2
    gemm_bf16<<<dim3(6, 64, 1), 256, 0, stream>>>(
        acts0b, 0, NIN, w_iin_b, 0, NIN, i_in_b, nullptr, 0, 0,
        nullptr, 0, 0, qkv2b, 0, 3 * NIN, nullptr, 0, NB * NS, 3 * NIN, NIN, 0);
    // 7. MHA-2
    attn_mfma<64><<<dim3(8, 4, 8), 512, 0, stream>>>(qkv2b, 3 * NIN, NIN, 2 * NIN, 0.125f);
    // 8. attn2 out-proj
    gemm_bf16<<<dim3(2, 64, 1), 256, 0, stream>>>(
        qkv2b, 0, 3 * NIN, w_iout_b, 0, NIN, i_out_b, nullptr, 0, 0,
        attn2proj, 0, NIN, nullptr, 0, 0, nullptr, 0, NB * NS, NIN, NIN, 0);
    // 9. LN + routed gather (fused)
    ln_gather_kernel<<<NB * NS, 256, 0, stream>>>(acts0, attn2proj, ln_g, ln_b,
                                                  idx_in, w_sel, sel_actsb);
    gather_sel_cw_b<<<2048, 256, 0, stream>>>(comb_w, idx_in, sel_cwb);
    // 10. proc_acts
    gemm_bf16<<<dim3(4, 8, NB), 256, 0, stream>>>(
        sel_actsb, (long)NS * KIN, KIN, sel_cwb, (long)NPROC * KIN, KIN,
        nullptr, nullptr, 0, 0,
        proc_acts, (long)NS * NPROC, NPROC, nullptr, 0, 0, nullptr, 0, NS, NPROC, KIN, 1);
    // 11. final scores + top-256
    maxpart_kernel<<<dim3(8, NB), 512, 0, stream>>>(proc_acts, maxpart);
    relevance_kernel<<<NB, 512, 0, stream>>>(maxpart, idx_in, a1w, a1b, a2w, a2b, finals);
    rank_proc_kernel<<<NB, 512, 0, stream>>>(finals, pidx);
    // 12. output gathers + GEMM + residual
    gather_sel_proc_b<<<dim3(NS, NB), KPROC, 0, stream>>>(proc_acts, pidx, sel_procb);
    gather_sel_projT<<<1024, 256, 0, stream>>>(out_proj_w, pidx, sel_projT);
    gemm_bf16<<<dim3(8, 8, NB), 256, 0, stream>>>(
        sel_procb, (long)NS * KPROC, KPROC, sel_projT, (long)ND * KPROC, KPROC,
        nullptr, x, (long)NS * ND, ND,
        out, (long)NS * ND, ND, nullptr, 0, 0, nullptr, 0, NS, ND, KPROC, 0);
    (void)in_sizes; (void)n_in; (void)out_size; (void)ws_size;
}

// Round 8
// 562.513 us; speedup vs baseline: 9.8850x; 1.0143x over previous
//
#include <hip/hip_runtime.h>
#include <hip/hip_bf16.h>
#include <math.h>

constexpr int NB = 8, NS = 1024, ND = 1024, NIN = 256, NPROC = 512, KIN = 128, KPROC = 256;

typedef __attribute__((ext_vector_type(8))) short bf16x8;
typedef __attribute__((ext_vector_type(4))) float f32x4;

__device__ inline float gelu_f(float x) {
    return 0.5f * x * (1.0f + erff(x * 0.7071067811865476f));
}
__device__ inline unsigned short f2b(float f) {
    __hip_bfloat16 h = __float2bfloat16(f);
    return *reinterpret_cast<unsigned short*>(&h);
}
__device__ inline void gload16(const void* g, void* l) {
    __builtin_amdgcn_global_load_lds(
        (const __attribute__((address_space(1))) void*)g,
        (__attribute__((address_space(3))) void*)l, 16, 0, 0);
}

// ---------------------------------------------------------------------------
__global__ void cvt_kernel(const float* __restrict__ in, unsigned short* __restrict__ out, long n4)
{
    long i = (long)blockIdx.x * blockDim.x + threadIdx.x;
    long stride = (long)gridDim.x * blockDim.x;
    for (; i < n4; i += stride) {
        float4 v = ((const float4*)in)[i];
        ushort4 o;
        o.x = f2b(v.x); o.y = f2b(v.y); o.z = f2b(v.z); o.w = f2b(v.w);
        ((ushort4*)out)[i] = o;
    }
}

// ---------------------------------------------------------------------------
// 256x256 bf16 MFMA GEMM, counted-vmcnt pipeline (T2+T4+T5 + XCD swizzle).
// C16 = A @ B^T + bias. Grid 1D (M/256)*(N/256), %8==0. K%64==0, K>=128.
// ---------------------------------------------------------------------------
__global__ __launch_bounds__(512, 2)
void gemm256(const unsigned short* __restrict__ A, int lda,
             const unsigned short* __restrict__ B, int ldb,
             const float* __restrict__ bias,
             unsigned short* __restrict__ C16, int ldc,
             int K, int nbx)
{
    __shared__ __align__(16) unsigned short Abuf[2][256 * 64];
    __shared__ __align__(16) unsigned short Bbuf[2][256 * 64];
    int o = blockIdx.x;
    int cpx = gridDim.x >> 3;
    int swz = (o & 7) * cpx + (o >> 3);
    int by = swz / nbx, bx = swz - by * nbx;
    int row0 = by * 256, col0 = bx * 256;

    int t = threadIdx.x;
    int w = t >> 6, l = t & 63, l15 = l & 15, g = l >> 4;
    int wr = w >> 2, wn = w & 3;
    int srow = l >> 3;
    int sgr = (l & 7) ^ srow;
    int xr = (l15 & 7) << 4;
    int NT = K >> 6;

    f32x4 acc[8][4];
#pragma unroll
    for (int i = 0; i < 8; ++i)
#pragma unroll
        for (int j = 0; j < 4; ++j) acc[i][j] = (f32x4){0.f, 0.f, 0.f, 0.f};

    const unsigned short* Asrc = A + (long)row0 * lda + sgr * 8;
    const unsigned short* Bsrc = B + (long)col0 * ldb + sgr * 8;

    auto STAGE = [&](int c, int kt) {
        int k0 = kt * 64;
#pragma unroll
        for (int j = 0; j < 4; ++j) {
            int r = j * 64 + w * 8;
            gload16(&Asrc[(long)(r + srow) * lda + k0], &Abuf[c][r * 64]);
        }
#pragma unroll
        for (int j = 0; j < 4; ++j) {
            int r = j * 64 + w * 8;
            gload16(&Bsrc[(long)(r + srow) * ldb + k0], &Bbuf[c][r * 64]);
        }
    };

    STAGE(0, 0);
    STAGE(1, 1);

    for (int T = 0; T < NT; ++T) {
        int c = T & 1;
        if (T + 1 < NT) { asm volatile("s_waitcnt vmcnt(8)" ::: "memory"); }
        else            { asm volatile("s_waitcnt vmcnt(0)" ::: "memory"); }
        __builtin_amdgcn_s_barrier();
        asm volatile("" ::: "memory");

        bf16x8 bfr[4][2];
#pragma unroll
        for (int ni = 0; ni < 4; ++ni)
#pragma unroll
            for (int ks = 0; ks < 2; ++ks) {
                int row = wn * 64 + ni * 16 + l15;
                int cb = (g * 16 + ks * 64) ^ xr;
                bfr[ni][ks] = *(const bf16x8*)((const char*)&Bbuf[c][0] + row * 128 + cb);
            }
#pragma unroll
        for (int q = 0; q < 4; ++q) {
            bf16x8 afr[2][2];
#pragma unroll
            for (int m2 = 0; m2 < 2; ++m2)
#pragma unroll
                for (int ks = 0; ks < 2; ++ks) {
                    int row = wr * 128 + (q * 2 + m2) * 16 + l15;
                    int cb = (g * 16 + ks * 64) ^ xr;
                    afr[m2][ks] = *(const bf16x8*)((const char*)&Abuf[c][0] + row * 128 + cb);
                }
            if (q == 3) {
                asm volatile("s_waitcnt lgkmcnt(0)" ::: "memory");
                __builtin_amdgcn_sched_barrier(0);
                __builtin_amdgcn_s_barrier();
                asm volatile("" ::: "memory");
                if (T + 2 < NT) STAGE(c, T + 2);
            }
            __builtin_amdgcn_s_setprio(1);
#pragma unroll
            for (int ks = 0; ks < 2; ++ks)
#pragma unroll
                for (int m2 = 0; m2 < 2; ++m2)
#pragma unroll
                    for (int ni = 0; ni < 4; ++ni)
                        acc[q * 2 + m2][ni] = __builtin_amdgcn_mfma_f32_16x16x32_bf16(
                            afr[m2][ks], bfr[ni][ks], acc[q * 2 + m2][ni], 0, 0, 0);
            __builtin_amdgcn_s_setprio(0);
        }
    }

#pragma unroll
    for (int mi = 0; mi < 8; ++mi) {
#pragma unroll
        for (int ni = 0; ni < 4; ++ni) {
            int col = col0 + wn * 64 + ni * 16 + l15;
            float bv = bias ? bias[col] : 0.f;
#pragma unroll
            for (int r = 0; r < 4; ++r) {
                int row = row0 + wr * 128 + mi * 16 + g * 4 + r;
                float v = acc[mi][ni][r] + bv;
                float vp = __shfl_xor(v, 1);
                if (!(l15 & 1)) {
                    unsigned int u = (unsigned int)f2b(v) | ((unsigned int)f2b(vp) << 16);
                    *(unsigned int*)&C16[(long)row * ldc + col] = u;
                }
            }
        }
    }
}

// ---------------------------------------------------------------------------
// bf16 MFMA GEMM, m97 structure (128x128, BK=64, 4 waves, gload_lds).
// act: 0 none, 1 gelu, 2 split@256 (col<256 -> C32; col>=256 -> gelu -> C32b+C16)
// ---------------------------------------------------------------------------
__global__ __launch_bounds__(256)
void gemm_bf16(const unsigned short* __restrict__ A, long sA, int lda,
               const unsigned short* __restrict__ B, long sB, int ldb,
               const float* __restrict__ bias,
               const float* __restrict__ resid, long sR, int ldr,
               float* __restrict__ C32, long sC32, int ldc32,
               unsigned short* __restrict__ C16, long sC16, int ldc16,
               float* __restrict__ C32b, int ldc32b,
               int M, int N, int K, int act)
{
    __shared__ __align__(16) unsigned short As[128 * 64];
    __shared__ __align__(16) unsigned short Bs[128 * 64];
    int bz = blockIdx.z;
    const unsigned short* Ab = A + (long)bz * sA;
    const unsigned short* Bb = B + (long)bz * sB;
    int row0 = blockIdx.y * 128, col0 = blockIdx.x * 128;
    int t = threadIdx.x;
    int w = t >> 6, l = t & 63, l15 = l & 15, g = l >> 4;
    int wr = w >> 1, wc = w & 1;
    int srow = l >> 3;
    int scol = (l & 7) * 8;
    f32x4 zero4 = {0.f, 0.f, 0.f, 0.f};
    f32x4 acc[4][4];
#pragma unroll
    for (int i = 0; i < 4; ++i)
#pragma unroll
        for (int j = 0; j < 4; ++j) acc[i][j] = zero4;

    for (int k0 = 0; k0 < K; k0 += 64) {
        __syncthreads();
#pragma unroll
        for (int c = 0; c < 4; ++c) {
            int r = w * 32 + c * 8;
            gload16(&Ab[(long)(row0 + r + srow) * lda + k0 + scol], &As[r * 64]);
            gload16(&Bb[(long)(col0 + r + srow) * ldb + k0 + scol], &Bs[r * 64]);
        }
        __syncthreads();
        bf16x8 af[4][2], bfr[4][2];
#pragma unroll
        for (int mi = 0; mi < 4; ++mi)
#pragma unroll
            for (int ks = 0; ks < 2; ++ks) {
                af[mi][ks] = *(const bf16x8*)&As[(wr * 64 + mi * 16 + l15) * 64 + g * 8 + ks * 32];
                bfr[mi][ks] = *(const bf16x8*)&Bs[(wc * 64 + mi * 16 + l15) * 64 + g * 8 + ks * 32];
            }
#pragma unroll
        for (int ks = 0; ks < 2; ++ks)
#pragma unroll
            for (int mi = 0; mi < 4; ++mi)
#pragma unroll
                for (int ni = 0; ni < 4; ++ni)
                    acc[mi][ni] = __builtin_amdgcn_mfma_f32_16x16x32_bf16(af[mi][ks], bfr[ni][ks], acc[mi][ni], 0, 0, 0);
    }

#pragma unroll
    for (int mi = 0; mi < 4; ++mi) {
#pragma unroll
        for (int ni = 0; ni < 4; ++ni) {
#pragma unroll
            for (int r = 0; r < 4; ++r) {
                int row = row0 + wr * 64 + mi * 16 + g * 4 + r;
                int col = col0 + wc * 64 + ni * 16 + l15;
                float v = acc[mi][ni][r];
                if (bias) v += bias[col];
                if (act == 2) {
                    if (col < 256) {
                        C32[(long)row * ldc32 + col] = v;
                    } else {
                        v = gelu_f(v);
                        C32b[(long)row * ldc32b + (col - 256)] = v;
                        C16[(long)row * ldc16 + (col - 256)] = f2b(v);
                    }
                    continue;
                }
                if (act == 1) v = gelu_f(v);
                if (resid) v += resid[(long)bz * sR + (long)row * ldr + col];
                if (C32) C32[(long)bz * sC32 + (long)row * ldc32 + col] = v;
                if (C16) C16[(long)bz * sC16 + (long)row * ldc16 + col] = f2b(v);
            }
        }
    }
}

// ---------------------------------------------------------------------------
// Flash-style MFMA attention, q-tile 128, 8 waves, kv-tile 64, reg prefetch.
// launch_bounds(512,2): VGPR cap >=128. Vt/Ps pitch 88 -> 2-way bank = free.
// ---------------------------------------------------------------------------
template <int D>
__global__ __launch_bounds__(512, 2)
void attn_mfma(unsigned short* __restrict__ qkv, int stride, int koff, int voff, float scale)
{
    constexpr int LK = D + 8;
    constexpr int LV = 88;
    constexpr int LP = 88;
    constexpr int NKS = D / 32;
    constexpr int NF = D / 16;
    constexpr int GR = D / 8;
    constexpr int NIT = (64 * GR) / 512;
    constexpr int NT = NS / 64;

    __shared__ __align__(16) unsigned short Ks[64 * LK];
    __shared__ __align__(16) unsigned short Vt[D * LV];
    __shared__ __align__(16) unsigned short Ps[128 * LP];

    int b = blockIdx.z, h = blockIdx.y, qt = blockIdx.x;
    int t = threadIdx.x, w = t >> 6, l = t & 63, l15 = l & 15, g = l >> 4;
    long qbase = ((long)b * NS + qt * 128) * stride + h * D;
    long kvbase = (long)b * NS * stride + h * D;

    bf16x8 qreg[NKS];
#pragma unroll
    for (int ks = 0; ks < NKS; ++ks)
        qreg[ks] = *(const bf16x8*)&qkv[qbase + (long)(w * 16 + l15) * stride + g * 8 + ks * 32];

#pragma unroll
    for (int i = 0; i < NIT; ++i) {
        int gi = t + i * 512;
        int r = gi / GR, sg = gi % GR;
        *(uint4*)&Ks[r * LK + sg * 8] = *(const uint4*)&qkv[kvbase + (long)r * stride + koff + sg * 8];
    }
#pragma unroll
    for (int i = 0; i < NIT; ++i) {
        int gi = t + i * 512;
        int kc = gi & 63, sg = gi >> 6;
        uint4 v = *(const uint4*)&qkv[kvbase + (long)kc * stride + voff + sg * 8];
        Vt[(sg * 8 + 0) * LV + kc] = (unsigned short)(v.x & 0xffff);
        Vt[(sg * 8 + 1) * LV + kc] = (unsigned short)(v.x >> 16);
        Vt[(sg * 8 + 2) * LV + kc] = (unsigned short)(v.y & 0xffff);
        Vt[(sg * 8 + 3) * LV + kc] = (unsigned short)(v.y >> 16);
        Vt[(sg * 8 + 4) * LV + kc] = (unsigned short)(v.z & 0xffff);
        Vt[(sg * 8 + 5) * LV + kc] = (unsigned short)(v.z >> 16);
        Vt[(sg * 8 + 6) * LV + kc] = (unsigned short)(v.w & 0xffff);
        Vt[(sg * 8 + 7) * LV + kc] = (unsigned short)(v.w >> 16);
    }
    __syncthreads();

    float m_run = -INFINITY, l_run = 0.f;
    f32x4 zero4 = {0.f, 0.f, 0.f, 0.f};
    f32x4 oacc[NF];
#pragma unroll
    for (int nf = 0; nf < NF; ++nf) oacc[nf] = zero4;

    for (int kt = 0; kt < NT; ++kt) {
        uint4 kp[NIT], vp[NIT];
        bool pre = (kt + 1 < NT);
        if (pre) {
            long kb = (long)(kt + 1) * 64;
#pragma unroll
            for (int i = 0; i < NIT; ++i) {
                int gi = t + i * 512;
                int r = gi / GR, sg = gi % GR;
                kp[i] = *(const uint4*)&qkv[kvbase + (kb + r) * stride + koff + sg * 8];
            }
#pragma unroll
            for (int i = 0; i < NIT; ++i) {
                int gi = t + i * 512;
                int kc = gi & 63, sg = gi >> 6;
                vp[i] = *(const uint4*)&qkv[kvbase + (kb + kc) * stride + voff + sg * 8];
            }
        }

        f32x4 st[4];
#pragma unroll
        for (int f = 0; f < 4; ++f) st[f] = zero4;
#pragma unroll
        for (int ks = 0; ks < NKS; ++ks) {
#pragma unroll
            for (int f = 0; f < 4; ++f) {
                bf16x8 a = *(const bf16x8*)&Ks[(f * 16 + l15) * LK + g * 8 + ks * 32];
                st[f] = __builtin_amdgcn_mfma_f32_16x16x32_bf16(a, qreg[ks], st[f], 0, 0, 0);
            }
        }
        float pm = -INFINITY;
#pragma unroll
        for (int f = 0; f < 4; ++f) {
            st[f] *= scale;
#pragma unroll
            for (int r = 0; r < 4; ++r) pm = fmaxf(pm, st[f][r]);
        }
        pm = fmaxf(pm, __shfl_xor(pm, 16));
        pm = fmaxf(pm, __shfl_xor(pm, 32));
        float m_new = fmaxf(m_run, pm);
        float corr = __expf(m_run - m_new);
        float rs = 0.f;
#pragma unroll
        for (int f = 0; f < 4; ++f) {
            float p0 = __expf(st[f][0] - m_new);
            float p1 = __expf(st[f][1] - m_new);
            float p2 = __expf(st[f][2] - m_new);
            float p3 = __expf(st[f][3] - m_new);
            rs += (p0 + p1) + (p2 + p3);
            ushort4 pw;
            pw.x = f2b(p0); pw.y = f2b(p1); pw.z = f2b(p2); pw.w = f2b(p3);
            *(ushort4*)&Ps[(w * 16 + l15) * LP + f * 16 + g * 4] = pw;
        }
        rs += __shfl_xor(rs, 16);
        rs += __shfl_xor(rs, 32);
        l_run = l_run * corr + rs;
        m_run = m_new;
        float corrO[4];
#pragma unroll
        for (int r = 0; r < 4; ++r) corrO[r] = __shfl(corr, g * 4 + r);
#pragma unroll
        for (int nf = 0; nf < NF; ++nf)
#pragma unroll
            for (int r = 0; r < 4; ++r) oacc[nf][r] *= corrO[r];
#pragma unroll
        for (int ks2 = 0; ks2 < 2; ++ks2) {
            bf16x8 pa = *(const bf16x8*)&Ps[(w * 16 + l15) * LP + ks2 * 32 + g * 8];
#pragma unroll
            for (int nf = 0; nf < NF; ++nf) {
                bf16x8 vb = *(const bf16x8*)&Vt[(nf * 16 + l15) * LV + ks2 * 32 + g * 8];
                oacc[nf] = __builtin_amdgcn_mfma_f32_16x16x32_bf16(pa, vb, oacc[nf], 0, 0, 0);
            }
        }
        __syncthreads();
        if (pre) {
#pragma unroll
            for (int i = 0; i < NIT; ++i) {
                int gi = t + i * 512;
                int r = gi / GR, sg = gi % GR;
                *(uint4*)&Ks[r * LK + sg * 8] = kp[i];
            }
#pragma unroll
            for (int i = 0; i < NIT; ++i) {
                int gi = t + i * 512;
                int kc = gi & 63, sg = gi >> 6;
                uint4 v = vp[i];
                Vt[(sg * 8 + 0) * LV + kc] = (unsigned short)(v.x & 0xffff);
                Vt[(sg * 8 + 1) * LV + kc] = (unsigned short)(v.x >> 16);
                Vt[(sg * 8 + 2) * LV + kc] = (unsigned short)(v.y & 0xffff);
                Vt[(sg * 8 + 3) * LV + kc] = (unsigned short)(v.y >> 16);
                Vt[(sg * 8 + 4) * LV + kc] = (unsigned short)(v.z & 0xffff);
                Vt[(sg * 8 + 5) * LV + kc] = (unsigned short)(v.z >> 16);
                Vt[(sg * 8 + 6) * LV + kc] = (unsigned short)(v.w & 0xffff);
                Vt[(sg * 8 + 7) * LV + kc] = (unsigned short)(v.w >> 16);
            }
        }
        __syncthreads();
    }
    float lo[4];
#pragma unroll
    for (int r = 0; r < 4; ++r) lo[r] = __shfl(l_run, g * 4 + r);
#pragma unroll
    for (int nf = 0; nf < NF; ++nf)
#pragma unroll
        for (int r = 0; r < 4; ++r) {
            float o = oacc[nf][r] / lo[r];
            qkv[qbase + (long)(w * 16 + g * 4 + r) * stride + nf * 16 + l15] = f2b(o);
        }
}

// ---------------------------------------------------------------------------
__global__ __launch_bounds__(256)
void maxpart_aff_kernel(const float* __restrict__ aff, float* __restrict__ part)
{
    int sc = blockIdx.x, b = blockIdx.y, t = threadIdx.x;
    float m = -INFINITY;
    for (int s = sc * 128; s < (sc + 1) * 128; ++s)
        m = fmaxf(m, aff[((long)b * NS + s) * NIN + t]);
    part[(b * 8 + sc) * NIN + t] = m;
}

__global__ __launch_bounds__(256)
void rank_input_kernel(const float* __restrict__ part, int* __restrict__ idx_out,
                       float* __restrict__ w_out)
{
    int b = blockIdx.x, t = threadIdx.x;
    __shared__ float lg[256], rv[256];
    float m = part[(b * 8) * NIN + t];
#pragma unroll
    for (int sc = 1; sc < 8; ++sc) m = fmaxf(m, part[(b * 8 + sc) * NIN + t]);
    float l = m * 0.5f;
    lg[t] = l;
    rv[t] = l;
    __syncthreads();
    for (int off = 128; off; off >>= 1) {
        if (t < off) rv[t] = fmaxf(rv[t], rv[t + off]);
        __syncthreads();
    }
    float mx = rv[0];
    __syncthreads();
    float e = expf(l - mx);
    rv[t] = e;
    __syncthreads();
    for (int off = 128; off; off >>= 1) {
        if (t < off) rv[t] += rv[t + off];
        __syncthreads();
    }
    float Zs = rv[0];
    float soft = e / Zs;
    __syncthreads();
    int rank = 0;
    for (int j = 0; j < 256; ++j) {
        float vj = lg[j];
        rank += (vj > l) || (vj == l && j < t);
    }
    rv[t] = (rank < KIN) ? soft : 0.f;
    __syncthreads();
    for (int off = 128; off; off >>= 1) {
        if (t < off) rv[t] += rv[t + off];
        __syncthreads();
    }
    float msum = rv[0];
    if (rank < KIN) {
        idx_out[b * KIN + rank] = t;
        w_out[b * KIN + rank] = soft / (msum + 1e-8f);
    }
}

__global__ __launch_bounds__(512)
void rank_proc_kernel(const float* __restrict__ finals, int* __restrict__ pidx)
{
    int b = blockIdx.x, t = threadIdx.x;
    __shared__ float v[512];
    float xv = finals[b * NPROC + t];
    v[t] = xv;
    __syncthreads();
    int rank = 0;
    for (int j = 0; j < 512; ++j) {
        float vj = v[j];
        rank += (vj > xv) || (vj == xv && j < t);
    }
    if (rank < KPROC) pidx[b * KPROC + rank] = t;
}

__global__ __launch_bounds__(256)
void ln_gather_kernel(const float* __restrict__ a, const float* __restrict__ bsrc,
                      const float* __restrict__ gg, const float* __restrict__ be,
                      const int* __restrict__ idx_in, const float* __restrict__ w_sel,
                      unsigned short* __restrict__ sel_acts)
{
    long row = blockIdx.x;
    int b = blockIdx.x >> 10;
    int t = threadIdx.x;
    float v = a[row * 256 + t] + bsrc[row * 256 + t];
    __shared__ float rv[256];
    __shared__ float lnv[256];
    rv[t] = v;
    __syncthreads();
    for (int off = 128; off; off >>= 1) {
        if (t < off) rv[t] += rv[t + off];
        __syncthreads();
    }
    float mean = rv[0] * (1.f / 256.f);
    __syncthreads();
    float d = v - mean;
    rv[t] = d * d;
    __syncthreads();
    for (int off = 128; off; off >>= 1) {
        if (t < off) rv[t] += rv[t + off];
        __syncthreads();
    }
    float var = rv[0] * (1.f / 256.f);
    lnv[t] = d * rsqrtf(var + 1e-5f) * gg[t] + be[t];
    __syncthreads();
    if (t < KIN) {
        int id = idx_in[b * KIN + t];
        sel_acts[row * KIN + t] = f2b(lnv[id] * w_sel[b * KIN + t]);
    }
}

__global__ void gather_sel_cw_b(const float* __restrict__ comb_w, const int* __restrict__ idx_in,
                                unsigned short* __restrict__ sel_cw)
{
    int gidx = blockIdx.x * 256 + threadIdx.x;
    int b = gidx >> 16;
    int rem = gidx & 65535;
    int pb = rem >> 7, j = rem & 127;
    sel_cw[gidx] = f2b(comb_w[pb * NIN + idx_in[b * KIN + j]]);
}

__global__ void gather_sel_proc_b(const float* __restrict__ proc_acts, const int* __restrict__ pidx,
                                  unsigned short* __restrict__ sel_proc)
{
    int s = blockIdx.x, b = blockIdx.y, j = threadIdx.x;
    long row = (long)b * NS + s;
    sel_proc[row * KPROC + j] = f2b(proc_acts[row * NPROC + pidx[b * KPROC + j]]);
}

__global__ void gather_sel_projT(const float* __restrict__ out_proj_w, const int* __restrict__ pidx,
                                 unsigned short* __restrict__ selT)
{
    int gidx = blockIdx.x * 256 + threadIdx.x;
    int b = gidx >> 15;
    int rem = gidx & 32767;
    int d = rem >> 5;
    int kp0 = (rem & 31) * 8;
    unsigned int u[4];
#pragma unroll
    for (int i = 0; i < 4; ++i) {
        unsigned short e0 = f2b(out_proj_w[(long)pidx[b * KPROC + kp0 + 2 * i] * ND + d]);
        unsigned short e1 = f2b(out_proj_w[(long)pidx[b * KPROC + kp0 + 2 * i + 1] * ND + d]);
        u[i] = (unsigned int)e0 | ((unsigned int)e1 << 16);
    }
    uint4 o; o.x = u[0]; o.y = u[1]; o.z = u[2]; o.w = u[3];
    *(uint4*)&selT[((long)b * ND + d) * KPROC + kp0] = o;
}

__global__ __launch_bounds__(512)
void maxpart_kernel(const float* __restrict__ proc, float* __restrict__ part)
{
    int sc = blockIdx.x, b = blockIdx.y, t = threadIdx.x;
    float m = -INFINITY;
    for (int s = sc * 128; s < (sc + 1) * 128; ++s)
        m = fmaxf(m, proc[((long)b * NS + s) * NPROC + t]);
    part[(b * 8 + sc) * NPROC + t] = m;
}

__global__ __launch_bounds__(512)
void relevance_kernel(const float* __restrict__ part, const int* __restrict__ idx_in,
                      const float* __restrict__ a1w, const float* __restrict__ a1b,
                      const float* __restrict__ a2w, const float* __restrict__ a2b,
                      float* __restrict__ finals)
{
    int b = blockIdx.x, t = threadIdx.x;
    float m = part[(b * 8) * NPROC + t];
#pragma unroll
    for (int sc = 1; sc < 8; ++sc) m = fmaxf(m, part[(b * 8 + sc) * NPROC + t]);
    __shared__ float rel1[512];
    __shared__ int sidx[KIN];
    if (t < KIN) sidx[t] = idx_in[b * KIN + t];
    __syncthreads();
    float r1 = a1b[t];
    const float* a1row = a1w + (long)t * NIN;
    for (int j = 0; j < KIN; ++j) r1 += a1row[sidx[j]];
    rel1[t] = gelu_f(r1);
    __syncthreads();
    float r = a2b[t];
    const float* a2row = a2w + (long)t * 512;
    for (int hh = 0; hh < 512; ++hh) r += rel1[hh] * a2row[hh];
    float sig = 1.f / (1.f + expf(-r));
    finals[b * NPROC + t] = m * sig;
}

// ---------------------------------------------------------------------------
extern "C" void kernel_launch(void* const* d_in, const int* in_sizes, int n_in,
                              void* d_out, int out_size, void* d_ws, size_t ws_size,
                              hipStream_t stream)
{
    const float* x       = (const float*)d_in[0];
    const float* r_in_w  = (const float*)d_in[1];
    const float* r_in_b  = (const float*)d_in[2];
    const float* r_out_w = (const float*)d_in[3];
    const float* r_out_b = (const float*)d_in[4];
    const float* aff_w   = (const float*)d_in[5];
    const float* aff_b   = (const float*)d_in[6];
    const float* patterns= (const float*)d_in[7];
    const float* i_in_w  = (const float*)d_in[8];
    const float* i_in_b  = (const float*)d_in[9];
    const float* i_out_w = (const float*)d_in[10];
    const float* i_out_b = (const float*)d_in[11];
    const float* ln_g    = (const float*)d_in[12];
    const float* ln_b    = (const float*)d_in[13];
    const float* comb_w  = (const float*)d_in[14];
    const float* out_proj_w = (const float*)d_in[15];
    const float* a1w     = (const float*)d_in[16];
    const float* a1b     = (const float*)d_in[17];
    const float* a2w     = (const float*)d_in[18];
    const float* a2b     = (const float*)d_in[19];
    float* out = (float*)d_out;

    char* ws = (char*)d_ws;
    unsigned short* qkv1b    = (unsigned short*)(ws + 0);
    unsigned short* contextb = (unsigned short*)(ws + 50331648);
    unsigned short* xb       = (unsigned short*)(ws + 67108864);
    unsigned short* w_rin_b  = (unsigned short*)(ws + 83886080);
    unsigned short* w_rout_b = (unsigned short*)(ws + 90177536);
    unsigned short* w_aff_b  = (unsigned short*)(ws + 92274688);   // [aff_w; patterns] contiguous
    unsigned short* patt_b   = (unsigned short*)(ws + 92798976);
    unsigned short* w_iin_b  = (unsigned short*)(ws + 93323264);
    unsigned short* w_iout_b = (unsigned short*)(ws + 93716480);
    float* w_sel   = (float*)(ws + 93855744);
    int*   idx_in  = (int*)(ws + 93859840);
    float* finals  = (float*)(ws + 93863936);
    int*   pidx    = (int*)(ws + 93880320);
    float* maxpart = (float*)(ws + 93888512);
    float* affin   = (float*)(ws + 94019584);
    float* acts0   = (float*)(ws + 102408192);
    unsigned short* acts0b = (unsigned short*)(ws + 110796800);
    unsigned short* qkv2b  = (unsigned short*)(ws + 114991104);
    float* attn2proj = (float*)(ws + 0);
    float* proc_acts = (float*)(ws + 16777216);
    unsigned short* sel_actsb = (unsigned short*)(ws + 33554432);
    unsigned short* sel_cwb   = (unsigned short*)(ws + 35651584);
    unsigned short* sel_procb = (unsigned short*)(ws + 36700160);
    unsigned short* sel_projT = (unsigned short*)(ws + 40894464);
    float* part_aff = (float*)(ws + 45088768);
    float* biascat  = (float*)(ws + 45154304);

    cvt_kernel<<<2048, 256, 0, stream>>>(x, xb, (long)NB * NS * ND / 4);
    cvt_kernel<<<1024, 256, 0, stream>>>(r_in_w, w_rin_b, (long)3 * ND * ND / 4);
    cvt_kernel<<<512, 256, 0, stream>>>(r_out_w, w_rout_b, (long)ND * ND / 4);
    cvt_kernel<<<128, 256, 0, stream>>>(aff_w, w_aff_b, (long)NIN * ND / 4);
    cvt_kernel<<<128, 256, 0, stream>>>(patterns, patt_b, (long)NIN * ND / 4);
    cvt_kernel<<<96, 256, 0, stream>>>(i_in_w, w_iin_b, (long)3 * NIN * NIN / 4);
    cvt_kernel<<<32, 256, 0, stream>>>(i_out_w, w_iout_b, (long)NIN * NIN / 4);

    // 1. qkv1 = x @ r_in_w^T + b (256^2 pipeline, 384 blocks)
    gemm256<<<384, 512, 0, stream>>>(xb, ND, w_rin_b, ND, r_in_b, qkv1b, 3 * ND, ND, 12);
    // 2. MHA-1
    attn_mfma<128><<<dim3(8, 8, 8), 512, 0, stream>>>(qkv1b, 3 * ND, ND, 2 * ND, 0.088388347648318447f);
    // 3. context (256^2 pipeline, 128 blocks)
    gemm256<<<128, 512, 0, stream>>>(qkv1b, 3 * ND, w_rout_b, ND, r_out_b, contextb, ND, ND, 4);
    // 4. fused affinity+patterns (split epilogue)
    hipMemcpyAsync(biascat, aff_b, 256 * sizeof(float), hipMemcpyDeviceToDevice, stream);
    hipMemsetAsync(biascat + 256, 0, 256 * sizeof(float), stream);
    gemm_bf16<<<dim3(4, 64, 1), 256, 0, stream>>>(
        contextb, 0, ND, w_aff_b, 0, ND, biascat, nullptr, 0, 0,
        affin, 0, NIN, acts0b, 0, NIN, acts0, NIN, NB * NS, 2 * NIN, ND, 2);
    // 5. routing
    maxpart_aff_kernel<<<dim3(8, NB), 256, 0, stream>>>(affin, part_aff);
    rank_input_kernel<<<NB, 256, 0, stream>>>(part_aff, idx_in, w_sel);
    // 6. qkv2 (256^2 pipeline, 96 blocks)
    gemm256<<<96, 512, 0, stream>>>(acts0b, NIN, w_iin_b, NIN, i_in_b, qkv2b, 3 * NIN, NIN, 3);
    // 7. MHA-2
    attn_mfma<64><<<dim3(8, 4, 8), 512, 0, stream>>>(qkv2b, 3 * NIN, NIN, 2 * NIN, 0.125f);
    // 8. attn2 out-proj
    gemm_bf16<<<dim3(2, 64, 1), 256, 0, stream>>>(
        qkv2b, 0, 3 * NIN, w_iout_b, 0, NIN, i_out_b, nullptr, 0, 0,
        attn2proj, 0, NIN, nullptr, 0, 0, nullptr, 0, NB * NS, NIN, NIN, 0);
    // 9. LN + routed gather (fused)
    ln_gather_kernel<<<NB * NS, 256, 0, stream>>>(acts0, attn2proj, ln_g, ln_b,
                                                  idx_in, w_sel, sel_actsb);
    gather_sel_cw_b<<<2048, 256, 0, stream>>>(comb_w, idx_in, sel_cwb);
    // 10. proc_acts
    gemm_bf16<<<dim3(4, 8, NB), 256, 0, stream>>>(
        sel_actsb, (long)NS * KIN, KIN, sel_cwb, (long)NPROC * KIN, KIN,
        nullptr, nullptr, 0, 0,
        proc_acts, (long)NS * NPROC, NPROC, nullptr, 0, 0, nullptr, 0, NS, NPROC, KIN, 1);
    // 11. final scores + top-256
    maxpart_kernel<<<dim3(8, NB), 512, 0, stream>>>(proc_acts, maxpart);
    relevance_kernel<<<NB, 512, 0, stream>>>(maxpart, idx_in, a1w, a1b, a2w, a2b, finals);
    rank_proc_kernel<<<NB, 512, 0, stream>>>(finals, pidx);
    // 12. output gathers + GEMM + residual
    gather_sel_proc_b<<<dim3(NS, NB), KPROC, 0, stream>>>(proc_acts, pidx, sel_procb);
    gather_sel_projT<<<1024, 256, 0, stream>>>(out_proj_w, pidx, sel_projT);
    gemm_bf16<<<dim3(8, 8, NB), 256, 0, stream>>>(
        sel_procb, (long)NS * KPROC, KPROC, sel_projT, (long)ND * KPROC, KPROC,
        nullptr, x, (long)NS * ND, ND,
        out, (long)NS * ND, ND, nullptr, 0, 0, nullptr, 0, NS, ND, KPROC, 0);
    (void)in_sizes; (void)n_in; (void)out_size; (void)ws_size;
}

// Round 10
// 528.648 us; speedup vs baseline: 10.5182x; 1.0641x over previous
//
#include <hip/hip_runtime.h>
#include <hip/hip_bf16.h>
#include <math.h>

constexpr int NB = 8, NS = 1024, ND = 1024, NIN = 256, NPROC = 512, KIN = 128, KPROC = 256;

typedef __attribute__((ext_vector_type(8))) short bf16x8;
typedef __attribute__((ext_vector_type(4))) float f32x4;

#define VMCNT(n) asm volatile("s_waitcnt vmcnt(" #n ")" ::: "memory")
#define LGKMCNT0 asm volatile("s_waitcnt lgkmcnt(0)" ::: "memory")

__device__ inline float gelu_f(float x) {
    return 0.5f * x * (1.0f + erff(x * 0.7071067811865476f));
}
__device__ inline unsigned short f2b(float f) {
    __hip_bfloat16 h = __float2bfloat16(f);
    return *reinterpret_cast<unsigned short*>(&h);
}
__device__ inline void gload16(const void* g, void* l) {
    __builtin_amdgcn_global_load_lds(
        (const __attribute__((address_space(1))) void*)g,
        (__attribute__((address_space(3))) void*)l, 16, 0, 0);
}

// ---------------------------------------------------------------------------
__global__ void cvt_kernel(const float* __restrict__ in, unsigned short* __restrict__ out, long n4)
{
    long i = (long)blockIdx.x * blockDim.x + threadIdx.x;
    long stride = (long)gridDim.x * blockDim.x;
    for (; i < n4; i += stride) {
        float4 v = ((const float4*)in)[i];
        ushort4 o;
        o.x = f2b(v.x); o.y = f2b(v.y); o.z = f2b(v.z); o.w = f2b(v.w);
        ((ushort4*)out)[i] = o;
    }
}

// ---------------------------------------------------------------------------
// 256x256 bf16 MFMA GEMM, counted-vmcnt pipeline.
// ---------------------------------------------------------------------------
__global__ __launch_bounds__(512, 2)
void gemm256(const unsigned short* __restrict__ A, int lda,
             const unsigned short* __restrict__ B, int ldb,
             const float* __restrict__ bias,
             unsigned short* __restrict__ C16, int ldc,
             int K, int nbx)
{
    __shared__ __align__(16) unsigned short Abuf[2][256 * 64];
    __shared__ __align__(16) unsigned short Bbuf[2][256 * 64];
    int o = blockIdx.x;
    int cpx = gridDim.x >> 3;
    int swz = (o & 7) * cpx + (o >> 3);
    int by = swz / nbx, bx = swz - by * nbx;
    int row0 = by * 256, col0 = bx * 256;

    int t = threadIdx.x;
    int w = t >> 6, l = t & 63, l15 = l & 15, g = l >> 4;
    int wr = w >> 2, wn = w & 3;
    int srow = l >> 3;
    int sgr = (l & 7) ^ srow;
    int xr = (l15 & 7) << 4;
    int NT = K >> 6;

    f32x4 acc[8][4];
#pragma unroll
    for (int i = 0; i < 8; ++i)
#pragma unroll
        for (int j = 0; j < 4; ++j) acc[i][j] = (f32x4){0.f, 0.f, 0.f, 0.f};

    const unsigned short* Asrc = A + (long)row0 * lda + sgr * 8;
    const unsigned short* Bsrc = B + (long)col0 * ldb + sgr * 8;

    auto STAGE = [&](int c, int kt) {
        int k0 = kt * 64;
#pragma unroll
        for (int j = 0; j < 4; ++j) {
            int r = j * 64 + w * 8;
            gload16(&Asrc[(long)(r + srow) * lda + k0], &Abuf[c][r * 64]);
        }
#pragma unroll
        for (int j = 0; j < 4; ++j) {
            int r = j * 64 + w * 8;
            gload16(&Bsrc[(long)(r + srow) * ldb + k0], &Bbuf[c][r * 64]);
        }
    };

    STAGE(0, 0);
    STAGE(1, 1);

    for (int T = 0; T < NT; ++T) {
        int c = T & 1;
        if (T + 1 < NT) { VMCNT(8); }
        else            { VMCNT(0); }
        __builtin_amdgcn_s_barrier();
        asm volatile("" ::: "memory");

        bf16x8 bfr[4][2];
#pragma unroll
        for (int ni = 0; ni < 4; ++ni)
#pragma unroll
            for (int ks = 0; ks < 2; ++ks) {
                int row = wn * 64 + ni * 16 + l15;
                int cb = (g * 16 + ks * 64) ^ xr;
                bfr[ni][ks] = *(const bf16x8*)((const char*)&Bbuf[c][0] + row * 128 + cb);
            }
#pragma unroll
        for (int q = 0; q < 4; ++q) {
            bf16x8 afr[2][2];
#pragma unroll
            for (int m2 = 0; m2 < 2; ++m2)
#pragma unroll
                for (int ks = 0; ks < 2; ++ks) {
                    int row = wr * 128 + (q * 2 + m2) * 16 + l15;
                    int cb = (g * 16 + ks * 64) ^ xr;
                    afr[m2][ks] = *(const bf16x8*)((const char*)&Abuf[c][0] + row * 128 + cb);
                }
            if (q == 3) {
                LGKMCNT0;
                __builtin_amdgcn_sched_barrier(0);
                __builtin_amdgcn_s_barrier();
                asm volatile("" ::: "memory");
                if (T + 2 < NT) STAGE(c, T + 2);
            }
            __builtin_amdgcn_s_setprio(1);
#pragma unroll
            for (int ks = 0; ks < 2; ++ks)
#pragma unroll
                for (int m2 = 0; m2 < 2; ++m2)
#pragma unroll
                    for (int ni = 0; ni < 4; ++ni)
                        acc[q * 2 + m2][ni] = __builtin_amdgcn_mfma_f32_16x16x32_bf16(
                            afr[m2][ks], bfr[ni][ks], acc[q * 2 + m2][ni], 0, 0, 0);
            __builtin_amdgcn_s_setprio(0);
        }
    }

#pragma unroll
    for (int mi = 0; mi < 8; ++mi) {
#pragma unroll
        for (int ni = 0; ni < 4; ++ni) {
            int col = col0 + wn * 64 + ni * 16 + l15;
            float bv = bias ? bias[col] : 0.f;
#pragma unroll
            for (int r = 0; r < 4; ++r) {
                int row = row0 + wr * 128 + mi * 16 + g * 4 + r;
                float v = acc[mi][ni][r] + bv;
                float vp = __shfl_xor(v, 1);
                if (!(l15 & 1)) {
                    unsigned int u = (unsigned int)f2b(v) | ((unsigned int)f2b(vp) << 16);
                    *(unsigned int*)&C16[(long)row * ldc + col] = u;
                }
            }
        }
    }
}

// ---------------------------------------------------------------------------
// bf16 MFMA GEMM, m97 structure (128x128, BK=64, 4 waves, gload_lds).
// ---------------------------------------------------------------------------
__global__ __launch_bounds__(256)
void gemm_bf16(const unsigned short* __restrict__ A, long sA, int lda,
               const unsigned short* __restrict__ B, long sB, int ldb,
               const float* __restrict__ bias,
               const float* __restrict__ resid, long sR, int ldr,
               float* __restrict__ C32, long sC32, int ldc32,
               unsigned short* __restrict__ C16, long sC16, int ldc16,
               float* __restrict__ C32b, int ldc32b,
               int M, int N, int K, int act)
{
    __shared__ __align__(16) unsigned short As[128 * 64];
    __shared__ __align__(16) unsigned short Bs[128 * 64];
    int bz = blockIdx.z;
    const unsigned short* Ab = A + (long)bz * sA;
    const unsigned short* Bb = B + (long)bz * sB;
    int row0 = blockIdx.y * 128, col0 = blockIdx.x * 128;
    int t = threadIdx.x;
    int w = t >> 6, l = t & 63, l15 = l & 15, g = l >> 4;
    int wr = w >> 1, wc = w & 1;
    int srow = l >> 3;
    int scol = (l & 7) * 8;
    f32x4 zero4 = {0.f, 0.f, 0.f, 0.f};
    f32x4 acc[4][4];
#pragma unroll
    for (int i = 0; i < 4; ++i)
#pragma unroll
        for (int j = 0; j < 4; ++j) acc[i][j] = zero4;

    for (int k0 = 0; k0 < K; k0 += 64) {
        __syncthreads();
#pragma unroll
        for (int c = 0; c < 4; ++c) {
            int r = w * 32 + c * 8;
            gload16(&Ab[(long)(row0 + r + srow) * lda + k0 + scol], &As[r * 64]);
            gload16(&Bb[(long)(col0 + r + srow) * ldb + k0 + scol], &Bs[r * 64]);
        }
        __syncthreads();
        bf16x8 af[4][2], bfr[4][2];
#pragma unroll
        for (int mi = 0; mi < 4; ++mi)
#pragma unroll
            for (int ks = 0; ks < 2; ++ks) {
                af[mi][ks] = *(const bf16x8*)&As[(wr * 64 + mi * 16 + l15) * 64 + g * 8 + ks * 32];
                bfr[mi][ks] = *(const bf16x8*)&Bs[(wc * 64 + mi * 16 + l15) * 64 + g * 8 + ks * 32];
            }
#pragma unroll
        for (int ks = 0; ks < 2; ++ks)
#pragma unroll
            for (int mi = 0; mi < 4; ++mi)
#pragma unroll
                for (int ni = 0; ni < 4; ++ni)
                    acc[mi][ni] = __builtin_amdgcn_mfma_f32_16x16x32_bf16(af[mi][ks], bfr[ni][ks], acc[mi][ni], 0, 0, 0);
    }

#pragma unroll
    for (int mi = 0; mi < 4; ++mi) {
#pragma unroll
        for (int ni = 0; ni < 4; ++ni) {
#pragma unroll
            for (int r = 0; r < 4; ++r) {
                int row = row0 + wr * 64 + mi * 16 + g * 4 + r;
                int col = col0 + wc * 64 + ni * 16 + l15;
                float v = acc[mi][ni][r];
                if (bias) v += bias[col];
                if (act == 2) {
                    if (col < 256) {
                        C32[(long)row * ldc32 + col] = v;
                    } else {
                        v = gelu_f(v);
                        C32b[(long)row * ldc32b + (col - 256)] = v;
                        C16[(long)row * ldc16 + (col - 256)] = f2b(v);
                    }
                    continue;
                }
                if (act == 1) v = gelu_f(v);
                if (resid) v += resid[(long)bz * sR + (long)row * ldr + col];
                if (C32) C32[(long)bz * sC32 + (long)row * ldc32 + col] = v;
                if (C16) C16[(long)bz * sC16 + (long)row * ldc16 + col] = f2b(v);
            }
        }
    }
}

// ---------------------------------------------------------------------------
// Flash attention v2: 4 waves x 32 q-rows (q-tile 128), kv-tile 64.
// K: double-buffered LDS via global_load_lds (linear + XOR-swizzled reads,
// counted vmcnt, never drained mid-loop). V: reg prefetch -> transposed Vt.
// Ps: wave-private LDS (no barrier). Raw s_barrier (no vmcnt drain).
// ---------------------------------------------------------------------------
template <int D>
__global__ __launch_bounds__(256, 2)
void attn_mfma(unsigned short* __restrict__ qkv, int stride, int koff, int voff, float scale)
{
    constexpr int GRL = D / 8;                // 16B granules per K row
    constexpr int NITK = (64 * GRL) / 256;    // K gload rounds (4 / 2)
    constexpr int NITV = NITK;                // V uint4 rounds
    constexpr int NKS = D / 32;
    constexpr int NF = D / 16;
    constexpr int LV = 72;
    constexpr int LP = 72;
    constexpr int NT = NS / 64;

    __shared__ __align__(16) unsigned short Ks[2][64 * D];
    __shared__ __align__(16) unsigned short Vt[D * LV];
    __shared__ __align__(16) unsigned short Ps[128 * LP];

    int b = blockIdx.z, h = blockIdx.y, qt = blockIdx.x;
    int t = threadIdx.x, w = t >> 6, l = t & 63, l15 = l & 15, g = l >> 4;
    int wq = w * 32;
    long qbase = ((long)b * NS + qt * 128) * stride + h * D;
    long kvbase = (long)b * NS * stride + h * D;

    // Q fragments: 32 q-rows per wave (2 x 16-row fragments)
    bf16x8 qreg[2][NKS];
#pragma unroll
    for (int qh = 0; qh < 2; ++qh)
#pragma unroll
        for (int ks = 0; ks < NKS; ++ks)
            qreg[qh][ks] = *(const bf16x8*)&qkv[qbase + (long)(wq + qh * 16 + l15) * stride + g * 8 + ks * 32];

    auto KSTAGE = [&](int c, int kt) {
#pragma unroll
        for (int i = 0; i < NITK; ++i) {
            int gi = t + i * 256;
            int row = gi / GRL, cg = gi % GRL;
            int cgs = cg ^ (row & 7);           // pre-swizzled source granule
            gload16(&qkv[kvbase + (long)(kt * 64 + row) * stride + koff + cgs * 8],
                    &Ks[c][gi * 8]);
        }
    };
    uint4 vp[NITV];
    auto VLOAD = [&](int kt) {
#pragma unroll
        for (int i = 0; i < NITV; ++i) {
            int vgi = t + i * 256;
            int kc = vgi & 63, db = vgi >> 6;
            vp[i] = *(const uint4*)&qkv[kvbase + (long)(kt * 64 + kc) * stride + voff + db * 8];
        }
    };
    auto VWRITE = [&]() {
#pragma unroll
        for (int i = 0; i < NITV; ++i) {
            int vgi = t + i * 256;
            int kc = vgi & 63, db = vgi >> 6;
            uint4 v = vp[i];
            Vt[(db * 8 + 0) * LV + kc] = (unsigned short)(v.x & 0xffff);
            Vt[(db * 8 + 1) * LV + kc] = (unsigned short)(v.x >> 16);
            Vt[(db * 8 + 2) * LV + kc] = (unsigned short)(v.y & 0xffff);
            Vt[(db * 8 + 3) * LV + kc] = (unsigned short)(v.y >> 16);
            Vt[(db * 8 + 4) * LV + kc] = (unsigned short)(v.z & 0xffff);
            Vt[(db * 8 + 5) * LV + kc] = (unsigned short)(v.z >> 16);
            Vt[(db * 8 + 6) * LV + kc] = (unsigned short)(v.w & 0xffff);
            Vt[(db * 8 + 7) * LV + kc] = (unsigned short)(v.w >> 16);
        }
    };

    // prologue: Ks0, V0, Ks1 in flight; drain Ks0+V0; fill Vt; barrier
    KSTAGE(0, 0);
    VLOAD(0);
    KSTAGE(1, 1);
    if constexpr (NITK == 4) { VMCNT(4); } else { VMCNT(2); }
    VWRITE();
    LGKMCNT0;
    __builtin_amdgcn_sched_barrier(0);
    __builtin_amdgcn_s_barrier();

    float m_run[2] = {-INFINITY, -INFINITY};
    float l_run[2] = {0.f, 0.f};
    f32x4 zero4 = {0.f, 0.f, 0.f, 0.f};
    f32x4 oacc[2][NF];
#pragma unroll
    for (int qh = 0; qh < 2; ++qh)
#pragma unroll
        for (int nf = 0; nf < NF; ++nf) oacc[qh][nf] = zero4;

    int xr = (l15 & 7) << 4;
    for (int kt = 0; kt < NT; ++kt) {
        if (kt + 1 < NT) VLOAD(kt + 1);

        // QK^T: St[kc][q] = K . Q^T
        const char* ksb = (const char*)&Ks[kt & 1][0];
        f32x4 st[4][2];
#pragma unroll
        for (int f = 0; f < 4; ++f)
#pragma unroll
            for (int qh = 0; qh < 2; ++qh) st[f][qh] = zero4;
#pragma unroll
        for (int ks = 0; ks < NKS; ++ks) {
#pragma unroll
            for (int f = 0; f < 4; ++f) {
                int cb = (g * 16 + ks * 64) ^ xr;
                bf16x8 a = *(const bf16x8*)(ksb + (f * 16 + l15) * (D * 2) + cb);
#pragma unroll
                for (int qh = 0; qh < 2; ++qh)
                    st[f][qh] = __builtin_amdgcn_mfma_f32_16x16x32_bf16(a, qreg[qh][ks], st[f][qh], 0, 0, 0);
            }
        }
        // online softmax per qh (q = wq + qh*16 + l15)
#pragma unroll
        for (int qh = 0; qh < 2; ++qh) {
            float pm = -INFINITY;
#pragma unroll
            for (int f = 0; f < 4; ++f) {
                st[f][qh] *= scale;
#pragma unroll
                for (int r = 0; r < 4; ++r) pm = fmaxf(pm, st[f][qh][r]);
            }
            pm = fmaxf(pm, __shfl_xor(pm, 16));
            pm = fmaxf(pm, __shfl_xor(pm, 32));
            float mn = fmaxf(m_run[qh], pm);
            float corr = __expf(m_run[qh] - mn);
            float rs = 0.f;
#pragma unroll
            for (int f = 0; f < 4; ++f) {
                float p0 = __expf(st[f][qh][0] - mn);
                float p1 = __expf(st[f][qh][1] - mn);
                float p2 = __expf(st[f][qh][2] - mn);
                float p3 = __expf(st[f][qh][3] - mn);
                rs += (p0 + p1) + (p2 + p3);
                ushort4 pw;
                pw.x = f2b(p0); pw.y = f2b(p1); pw.z = f2b(p2); pw.w = f2b(p3);
                *(ushort4*)&Ps[(wq + qh * 16 + l15) * LP + f * 16 + g * 4] = pw;
            }
            rs += __shfl_xor(rs, 16);
            rs += __shfl_xor(rs, 32);
            l_run[qh] = l_run[qh] * corr + rs;
            m_run[qh] = mn;
            float corrO[4];
#pragma unroll
            for (int r = 0; r < 4; ++r) corrO[r] = __shfl(corr, g * 4 + r);
#pragma unroll
            for (int nf = 0; nf < NF; ++nf)
#pragma unroll
                for (int r = 0; r < 4; ++r) oacc[qh][nf][r] *= corrO[r];
        }
        // PV
#pragma unroll
        for (int ks2 = 0; ks2 < 2; ++ks2) {
            bf16x8 vb[NF];
#pragma unroll
            for (int nf = 0; nf < NF; ++nf)
                vb[nf] = *(const bf16x8*)&Vt[(nf * 16 + l15) * LV + ks2 * 32 + g * 8];
#pragma unroll
            for (int qh = 0; qh < 2; ++qh) {
                bf16x8 pa = *(const bf16x8*)&Ps[(wq + qh * 16 + l15) * LP + ks2 * 32 + g * 8];
#pragma unroll
                for (int nf = 0; nf < NF; ++nf)
                    oacc[qh][nf] = __builtin_amdgcn_mfma_f32_16x16x32_bf16(pa, vb[nf], oacc[qh][nf], 0, 0, 0);
            }
        }

        if (kt + 1 < NT) {
            LGKMCNT0;
            __builtin_amdgcn_sched_barrier(0);
            __builtin_amdgcn_s_barrier();            // A: all Vt/Ks reads done
            if (kt + 2 < NT) {
                KSTAGE(kt & 1, kt + 2);
                if constexpr (NITK == 4) { VMCNT(4); } else { VMCNT(2); }
            } else {
                VMCNT(0);
            }
            VWRITE();                                 // Vt <- V(kt+1)
            LGKMCNT0;
            __builtin_amdgcn_sched_barrier(0);
            __builtin_amdgcn_s_barrier();            // B: Vt(kt+1)+Ks visible
        }
    }

    // epilogue
#pragma unroll
    for (int qh = 0; qh < 2; ++qh) {
        float lo[4];
#pragma unroll
        for (int r = 0; r < 4; ++r) lo[r] = __shfl(l_run[qh], g * 4 + r);
#pragma unroll
        for (int nf = 0; nf < NF; ++nf)
#pragma unroll
            for (int r = 0; r < 4; ++r) {
                float o = oacc[qh][nf][r] / lo[r];
                qkv[qbase + (long)(wq + qh * 16 + g * 4 + r) * stride + nf * 16 + l15] = f2b(o);
            }
    }
}

// ---------------------------------------------------------------------------
__global__ __launch_bounds__(256)
void maxpart_aff_kernel(const float* __restrict__ aff, float* __restrict__ part)
{
    int sc = blockIdx.x, b = blockIdx.y, t = threadIdx.x;  // 32 chunks x 32 s
    float m = -INFINITY;
    for (int s = sc * 32; s < (sc + 1) * 32; ++s)
        m = fmaxf(m, aff[((long)b * NS + s) * NIN + t]);
    part[(b * 32 + sc) * NIN + t] = m;
}

__global__ __launch_bounds__(256)
void rank_input_kernel(const float* __restrict__ part, int* __restrict__ idx_out,
                       float* __restrict__ w_out)
{
    int b = blockIdx.x, t = threadIdx.x;
    __shared__ float lg[256], rv[256];
    float m = part[(b * 32) * NIN + t];
#pragma unroll
    for (int sc = 1; sc < 32; ++sc) m = fmaxf(m, part[(b * 32 + sc) * NIN + t]);
    float l = m * 0.5f;
    lg[t] = l;
    rv[t] = l;
    __syncthreads();
    for (int off = 128; off; off >>= 1) {
        if (t < off) rv[t] = fmaxf(rv[t], rv[t + off]);
        __syncthreads();
    }
    float mx = rv[0];
    __syncthreads();
    float e = expf(l - mx);
    rv[t] = e;
    __syncthreads();
    for (int off = 128; off; off >>= 1) {
        if (t < off) rv[t] += rv[t + off];
        __syncthreads();
    }
    float Zs = rv[0];
    float soft = e / Zs;
    __syncthreads();
    int rank = 0;
    for (int j = 0; j < 256; ++j) {
        float vj = lg[j];
        rank += (vj > l) || (vj == l && j < t);
    }
    rv[t] = (rank < KIN) ? soft : 0.f;
    __syncthreads();
    for (int off = 128; off; off >>= 1) {
        if (t < off) rv[t] += rv[t + off];
        __syncthreads();
    }
    float msum = rv[0];
    if (rank < KIN) {
        idx_out[b * KIN + rank] = t;
        w_out[b * KIN + rank] = soft / (msum + 1e-8f);
    }
}

__global__ __launch_bounds__(512)
void rank_proc_kernel(const float* __restrict__ finals, int* __restrict__ pidx)
{
    int b = blockIdx.x, t = threadIdx.x;
    __shared__ float v[512];
    float xv = finals[b * NPROC + t];
    v[t] = xv;
    __syncthreads();
    int rank = 0;
    for (int j = 0; j < 512; ++j) {
        float vj = v[j];
        rank += (vj > xv) || (vj == xv && j < t);
    }
    if (rank < KPROC) pidx[b * KPROC + rank] = t;
}

__global__ __launch_bounds__(256)
void ln_gather_kernel(const float* __restrict__ a, const float* __restrict__ bsrc,
                      const float* __restrict__ gg, const float* __restrict__ be,
                      const int* __restrict__ idx_in, const float* __restrict__ w_sel,
                      unsigned short* __restrict__ sel_acts)
{
    long row = blockIdx.x;
    int b = blockIdx.x >> 10;
    int t = threadIdx.x;
    float v = a[row * 256 + t] + bsrc[row * 256 + t];
    __shared__ float rv[256];
    __shared__ float lnv[256];
    rv[t] = v;
    __syncthreads();
    for (int off = 128; off; off >>= 1) {
        if (t < off) rv[t] += rv[t + off];
        __syncthreads();
    }
    float mean = rv[0] * (1.f / 256.f);
    __syncthreads();
    float d = v - mean;
    rv[t] = d * d;
    __syncthreads();
    for (int off = 128; off; off >>= 1) {
        if (t < off) rv[t] += rv[t + off];
        __syncthreads();
    }
    float var = rv[0] * (1.f / 256.f);
    lnv[t] = d * rsqrtf(var + 1e-5f) * gg[t] + be[t];
    __syncthreads();
    if (t < KIN) {
        int id = idx_in[b * KIN + t];
        sel_acts[row * KIN + t] = f2b(lnv[id] * w_sel[b * KIN + t]);
    }
}

__global__ void gather_sel_cw_b(const float* __restrict__ comb_w, const int* __restrict__ idx_in,
                                unsigned short* __restrict__ sel_cw)
{
    int gidx = blockIdx.x * 256 + threadIdx.x;
    int b = gidx >> 16;
    int rem = gidx & 65535;
    int pb = rem >> 7, j = rem & 127;
    sel_cw[gidx] = f2b(comb_w[pb * NIN + idx_in[b * KIN + j]]);
}

__global__ void gather_sel_proc_b(const float* __restrict__ proc_acts, const int* __restrict__ pidx,
                                  unsigned short* __restrict__ sel_proc)
{
    int s = blockIdx.x, b = blockIdx.y, j = threadIdx.x;
    long row = (long)b * NS + s;
    sel_proc[row * KPROC + j] = f2b(proc_acts[row * NPROC + pidx[b * KPROC + j]]);
}

__global__ void gather_sel_projT(const float* __restrict__ out_proj_w, const int* __restrict__ pidx,
                                 unsigned short* __restrict__ selT)
{
    int gidx = blockIdx.x * 256 + threadIdx.x;
    int b = gidx >> 15;
    int rem = gidx & 32767;
    int d = rem >> 5;
    int kp0 = (rem & 31) * 8;
    unsigned int u[4];
#pragma unroll
    for (int i = 0; i < 4; ++i) {
        unsigned short e0 = f2b(out_proj_w[(long)pidx[b * KPROC + kp0 + 2 * i] * ND + d]);
        unsigned short e1 = f2b(out_proj_w[(long)pidx[b * KPROC + kp0 + 2 * i + 1] * ND + d]);
        u[i] = (unsigned int)e0 | ((unsigned int)e1 << 16);
    }
    uint4 o; o.x = u[0]; o.y = u[1]; o.z = u[2]; o.w = u[3];
    *(uint4*)&selT[((long)b * ND + d) * KPROC + kp0] = o;
}

__global__ __launch_bounds__(512)
void maxpart_kernel(const float* __restrict__ proc, float* __restrict__ part)
{
    int sc = blockIdx.x, b = blockIdx.y, t = threadIdx.x;  // 32 chunks x 32 s
    float m = -INFINITY;
    for (int s = sc * 32; s < (sc + 1) * 32; ++s)
        m = fmaxf(m, proc[((long)b * NS + s) * NPROC + t]);
    part[(b * 32 + sc) * NPROC + t] = m;
}

__global__ __launch_bounds__(512)
void relevance_kernel(const float* __restrict__ part, const int* __restrict__ idx_in,
                      const float* __restrict__ a1w, const float* __restrict__ a1b,
                      const float* __restrict__ a2w, const float* __restrict__ a2b,
                      float* __restrict__ finals)
{
    int b = blockIdx.x, t = threadIdx.x;
    float m = part[(b * 32) * NPROC + t];
#pragma unroll
    for (int sc = 1; sc < 32; ++sc) m = fmaxf(m, part[(b * 32 + sc) * NPROC + t]);
    __shared__ float rel1[512];
    __shared__ int sidx[KIN];
    if (t < KIN) sidx[t] = idx_in[b * KIN + t];
    __syncthreads();
    float r1 = a1b[t];
    const float* a1row = a1w + (long)t * NIN;
    for (int j = 0; j < KIN; ++j) r1 += a1row[sidx[j]];
    rel1[t] = gelu_f(r1);
    __syncthreads();
    float r = a2b[t];
    const float* a2row = a2w + (long)t * 512;
    for (int hh = 0; hh < 512; ++hh) r += rel1[hh] * a2row[hh];
    float sig = 1.f / (1.f + expf(-r));
    finals[b * NPROC + t] = m * sig;
}

// ---------------------------------------------------------------------------
extern "C" void kernel_launch(void* const* d_in, const int* in_sizes, int n_in,
                              void* d_out, int out_size, void* d_ws, size_t ws_size,
                              hipStream_t stream)
{
    const float* x       = (const float*)d_in[0];
    const float* r_in_w  = (const float*)d_in[1];
    const float* r_in_b  = (const float*)d_in[2];
    const float* r_out_w = (const float*)d_in[3];
    const float* r_out_b = (const float*)d_in[4];
    const float* aff_w   = (const float*)d_in[5];
    const float* aff_b   = (const float*)d_in[6];
    const float* patterns= (const float*)d_in[7];
    const float* i_in_w  = (const float*)d_in[8];
    const float* i_in_b  = (const float*)d_in[9];
    const float* i_out_w = (const float*)d_in[10];
    const float* i_out_b = (const float*)d_in[11];
    const float* ln_g    = (const float*)d_in[12];
    const float* ln_b    = (const float*)d_in[13];
    const float* comb_w  = (const float*)d_in[14];
    const float* out_proj_w = (const float*)d_in[15];
    const float* a1w     = (const float*)d_in[16];
    const float* a1b     = (const float*)d_in[17];
    const float* a2w     = (const float*)d_in[18];
    const float* a2b     = (const float*)d_in[19];
    float* out = (float*)d_out;

    char* ws = (char*)d_ws;
    unsigned short* qkv1b    = (unsigned short*)(ws + 0);
    unsigned short* contextb = (unsigned short*)(ws + 50331648);
    unsigned short* xb       = (unsigned short*)(ws + 67108864);
    unsigned short* w_rin_b  = (unsigned short*)(ws + 83886080);
    unsigned short* w_rout_b = (unsigned short*)(ws + 90177536);
    unsigned short* w_aff_b  = (unsigned short*)(ws + 92274688);   // [aff_w; patterns] contiguous
    unsigned short* patt_b   = (unsigned short*)(ws + 92798976);
    unsigned short* w_iin_b  = (unsigned short*)(ws + 93323264);
    unsigned short* w_iout_b = (unsigned short*)(ws + 93716480);
    float* w_sel   = (float*)(ws + 93855744);
    int*   idx_in  = (int*)(ws + 93859840);
    float* finals  = (float*)(ws + 93863936);
    int*   pidx    = (int*)(ws + 93880320);
    float* affin   = (float*)(ws + 94019584);
    float* acts0   = (float*)(ws + 102408192);
    unsigned short* acts0b = (unsigned short*)(ws + 110796800);
    unsigned short* qkv2b  = (unsigned short*)(ws + 114991104);
    float* attn2proj = (float*)(ws + 0);
    float* proc_acts = (float*)(ws + 16777216);
    unsigned short* sel_actsb = (unsigned short*)(ws + 33554432);
    unsigned short* sel_cwb   = (unsigned short*)(ws + 35651584);
    unsigned short* sel_procb = (unsigned short*)(ws + 36700160);
    unsigned short* sel_projT = (unsigned short*)(ws + 40894464);
    float* biascat  = (float*)(ws + 45088768);   // 2 KB
    float* part_aff = (float*)(ws + 45091840);   // 256 KB
    float* maxpart  = (float*)(ws + 45353984);   // 512 KB (dead region)

    cvt_kernel<<<2048, 256, 0, stream>>>(x, xb, (long)NB * NS * ND / 4);
    cvt_kernel<<<1024, 256, 0, stream>>>(r_in_w, w_rin_b, (long)3 * ND * ND / 4);
    cvt_kernel<<<512, 256, 0, stream>>>(r_out_w, w_rout_b, (long)ND * ND / 4);
    cvt_kernel<<<128, 256, 0, stream>>>(aff_w, w_aff_b, (long)NIN * ND / 4);
    cvt_kernel<<<128, 256, 0, stream>>>(patterns, patt_b, (long)NIN * ND / 4);
    cvt_kernel<<<96, 256, 0, stream>>>(i_in_w, w_iin_b, (long)3 * NIN * NIN / 4);
    cvt_kernel<<<32, 256, 0, stream>>>(i_out_w, w_iout_b, (long)NIN * NIN / 4);

    // 1. qkv1 = x @ r_in_w^T + b (256^2 pipeline, 384 blocks)
    gemm256<<<384, 512, 0, stream>>>(xb, ND, w_rin_b, ND, r_in_b, qkv1b, 3 * ND, ND, 12);
    // 2. MHA-1 (4-wave blocks)
    attn_mfma<128><<<dim3(8, 8, 8), 256, 0, stream>>>(qkv1b, 3 * ND, ND, 2 * ND, 0.088388347648318447f);
    // 3. context (256^2 pipeline, 128 blocks)
    gemm256<<<128, 512, 0, stream>>>(qkv1b, 3 * ND, w_rout_b, ND, r_out_b, contextb, ND, ND, 4);
    // 4. fused affinity+patterns (split epilogue)
    hipMemcpyAsync(biascat, aff_b, 256 * sizeof(float), hipMemcpyDeviceToDevice, stream);
    hipMemsetAsync(biascat + 256, 0, 256 * sizeof(float), stream);
    gemm_bf16<<<dim3(4, 64, 1), 256, 0, stream>>>(
        contextb, 0, ND, w_aff_b, 0, ND, biascat, nullptr, 0, 0,
        affin, 0, NIN, acts0b, 0, NIN, acts0, NIN, NB * NS, 2 * NIN, ND, 2);
    // 5. routing
    maxpart_aff_kernel<<<dim3(32, NB), 256, 0, stream>>>(affin, part_aff);
    rank_input_kernel<<<NB, 256, 0, stream>>>(part_aff, idx_in, w_sel);
    // 6. qkv2 (256^2 pipeline, 96 blocks)
    gemm256<<<96, 512, 0, stream>>>(acts0b, NIN, w_iin_b, NIN, i_in_b, qkv2b, 3 * NIN, NIN, 3);
    // 7. MHA-2
    attn_mfma<64><<<dim3(8, 4, 8), 256, 0, stream>>>(qkv2b, 3 * NIN, NIN, 2 * NIN, 0.125f);
    // 8. attn2 out-proj
    gemm_bf16<<<dim3(2, 64, 1), 256, 0, stream>>>(
        qkv2b, 0, 3 * NIN, w_iout_b, 0, NIN, i_out_b, nullptr, 0, 0,
        attn2proj, 0, NIN, nullptr, 0, 0, nullptr, 0, NB * NS, NIN, NIN, 0);
    // 9. LN + routed gather (fused)
    ln_gather_kernel<<<NB * NS, 256, 0, stream>>>(acts0, attn2proj, ln_g, ln_b,
                                                  idx_in, w_sel, sel_actsb);
    gather_sel_cw_b<<<2048, 256, 0, stream>>>(comb_w, idx_in, sel_cwb);
    // 10. proc_acts
    gemm_bf16<<<dim3(4, 8, NB), 256, 0, stream>>>(
        sel_actsb, (long)NS * KIN, KIN, sel_cwb, (long)NPROC * KIN, KIN,
        nullptr, nullptr, 0, 0,
        proc_acts, (long)NS * NPROC, NPROC, nullptr, 0, 0, nullptr, 0, NS, NPROC, KIN, 1);
    // 11. final scores + top-256
    maxpart_kernel<<<dim3(32, NB), 512, 0, stream>>>(proc_acts, maxpart);
    relevance_kernel<<<NB, 512, 0, stream>>>(maxpart, idx_in, a1w, a1b, a2w, a2b, finals);
    rank_proc_kernel<<<NB, 512, 0, stream>>>(finals, pidx);
    // 12. output gathers + GEMM + residual
    gather_sel_proc_b<<<dim3(NS, NB), KPROC, 0, stream>>>(proc_acts, pidx, sel_procb);
    gather_sel_projT<<<1024, 256, 0, stream>>>(out_proj_w, pidx, sel_projT);
    gemm_bf16<<<dim3(8, 8, NB), 256, 0, stream>>>(
        sel_procb, (long)NS * KPROC, KPROC, sel_projT, (long)ND * KPROC, KPROC,
        nullptr, x, (long)NS * ND, ND,
        out, (long)NS * ND, ND, nullptr, 0, 0, nullptr, 0, NS, ND, KPROC, 0);
    (void)in_sizes; (void)n_in; (void)out_size; (void)ws_size;
}

// Round 12
// 520.275 us; speedup vs baseline: 10.6875x; 1.0161x over previous
//
#include <hip/hip_runtime.h>
#include <hip/hip_bf16.h>
#include <math.h>

constexpr int NB = 8, NS = 1024, ND = 1024, NIN = 256, NPROC = 512, KIN = 128, KPROC = 256;

typedef __attribute__((ext_vector_type(8))) short bf16x8;
typedef __attribute__((ext_vector_type(4))) float f32x4;

#define VMCNT(n) asm volatile("s_waitcnt vmcnt(" #n ")" ::: "memory")
#define LGKMCNT0 asm volatile("s_waitcnt lgkmcnt(0)" ::: "memory")

__device__ inline float gelu_f(float x) {
    return 0.5f * x * (1.0f + erff(x * 0.7071067811865476f));
}
__device__ inline unsigned short f2b(float f) {
    __hip_bfloat16 h = __float2bfloat16(f);
    return *reinterpret_cast<unsigned short*>(&h);
}
__device__ inline void gload16(const void* g, void* l) {
    __builtin_amdgcn_global_load_lds(
        (const __attribute__((address_space(1))) void*)g,
        (__attribute__((address_space(3))) void*)l, 16, 0, 0);
}

// ---------------------------------------------------------------------------
__global__ void cvt_kernel(const float* __restrict__ in, unsigned short* __restrict__ out, long n4)
{
    long i = (long)blockIdx.x * blockDim.x + threadIdx.x;
    long stride = (long)gridDim.x * blockDim.x;
    for (; i < n4; i += stride) {
        float4 v = ((const float4*)in)[i];
        ushort4 o;
        o.x = f2b(v.x); o.y = f2b(v.y); o.z = f2b(v.z); o.w = f2b(v.w);
        ((ushort4*)out)[i] = o;
    }
}

// ---------------------------------------------------------------------------
// 256x256 bf16 MFMA GEMM — 4-phase/tile counted-vmcnt schedule (T2+T3+T4+T5
// + XCD swizzle). C16 = A @ B^T + bias. Grid 1D (M/256)*(N/256), %8==0.
// Staging order per tile: part0=B(j0,j1) part1=B(j2,j3) part2=A(j0,j2)
// part3=A(j1,j3); phase p computes C-quadrant p (A rows p*32 strip).
// Gates: vmcnt(2)@p0 (B+A02 of this tile done), vmcnt(4)@p2 (A13 done),
// vmcnt(0)@p2 of last tile only.
// ---------------------------------------------------------------------------
__global__ __launch_bounds__(512, 2)
void gemm256(const unsigned short* __restrict__ A, int lda,
             const unsigned short* __restrict__ B, int ldb,
             const float* __restrict__ bias,
             unsigned short* __restrict__ C16, int ldc,
             int K, int nbx)
{
    __shared__ __align__(16) unsigned short Abuf[2][256 * 64];
    __shared__ __align__(16) unsigned short Bbuf[2][256 * 64];
    int o = blockIdx.x;
    int cpx = gridDim.x >> 3;
    int swz = (o & 7) * cpx + (o >> 3);
    int by = swz / nbx, bx = swz - by * nbx;
    int row0 = by * 256, col0 = bx * 256;

    int t = threadIdx.x;
    int w = t >> 6, l = t & 63, l15 = l & 15, g = l >> 4;
    int wr = w >> 2, wn = w & 3;
    int srow = l >> 3;
    int sgr = (l & 7) ^ srow;
    int xr = (l15 & 7) << 4;
    int NT = K >> 6;

    f32x4 acc[8][4];
#pragma unroll
    for (int i = 0; i < 8; ++i)
#pragma unroll
        for (int j = 0; j < 4; ++j) acc[i][j] = (f32x4){0.f, 0.f, 0.f, 0.f};

    const unsigned short* Asrc = A + (long)row0 * lda + sgr * 8;
    const unsigned short* Bsrc = B + (long)col0 * ldb + sgr * 8;

    auto PART = [&](int c, int kt, int part) {
        int k0 = kt * 64;
        if (part == 0) {
            int r0 = 0 * 64 + w * 8, r1 = 1 * 64 + w * 8;
            gload16(&Bsrc[(long)(r0 + srow) * ldb + k0], &Bbuf[c][r0 * 64]);
            gload16(&Bsrc[(long)(r1 + srow) * ldb + k0], &Bbuf[c][r1 * 64]);
        } else if (part == 1) {
            int r0 = 2 * 64 + w * 8, r1 = 3 * 64 + w * 8;
            gload16(&Bsrc[(long)(r0 + srow) * ldb + k0], &Bbuf[c][r0 * 64]);
            gload16(&Bsrc[(long)(r1 + srow) * ldb + k0], &Bbuf[c][r1 * 64]);
        } else if (part == 2) {
            int r0 = 0 * 64 + w * 8, r1 = 2 * 64 + w * 8;
            gload16(&Asrc[(long)(r0 + srow) * lda + k0], &Abuf[c][r0 * 64]);
            gload16(&Asrc[(long)(r1 + srow) * lda + k0], &Abuf[c][r1 * 64]);
        } else {
            int r0 = 1 * 64 + w * 8, r1 = 3 * 64 + w * 8;
            gload16(&Asrc[(long)(r0 + srow) * lda + k0], &Abuf[c][r0 * 64]);
            gload16(&Asrc[(long)(r1 + srow) * lda + k0], &Abuf[c][r1 * 64]);
        }
    };

    PART(0, 0, 0); PART(0, 0, 1); PART(0, 0, 2); PART(0, 0, 3);

    for (int T = 0; T < NT; ++T) {
        int c = T & 1;
        const char* Ab_ = (const char*)&Abuf[c][0];
        const char* Bb_ = (const char*)&Bbuf[c][0];
        bool haveNext = (T + 1 < NT);
        bf16x8 bfr[4][2];
#pragma unroll
        for (int q = 0; q < 4; ++q) {
            if (q == 0) { VMCNT(2); }
            if (q == 2) { if (haveNext) { VMCNT(4); } else { VMCNT(0); } }
            __builtin_amdgcn_s_barrier();
            asm volatile("" ::: "memory");

            if (q == 0) {
#pragma unroll
                for (int ni = 0; ni < 4; ++ni)
#pragma unroll
                    for (int ks = 0; ks < 2; ++ks) {
                        int row = wn * 64 + ni * 16 + l15;
                        int cb = (g * 16 + ks * 64) ^ xr;
                        bfr[ni][ks] = *(const bf16x8*)(Bb_ + row * 128 + cb);
                    }
            }
            bf16x8 afr[2][2];
#pragma unroll
            for (int m2 = 0; m2 < 2; ++m2)
#pragma unroll
                for (int ks = 0; ks < 2; ++ks) {
                    int row = wr * 128 + (q * 2 + m2) * 16 + l15;
                    int cb = (g * 16 + ks * 64) ^ xr;
                    afr[m2][ks] = *(const bf16x8*)(Ab_ + row * 128 + cb);
                }
            if (haveNext) PART(c ^ 1, T + 1, q);

            LGKMCNT0;
            __builtin_amdgcn_sched_barrier(0);
            __builtin_amdgcn_s_setprio(1);
#pragma unroll
            for (int ks = 0; ks < 2; ++ks)
#pragma unroll
                for (int m2 = 0; m2 < 2; ++m2)
#pragma unroll
                    for (int ni = 0; ni < 4; ++ni)
                        acc[q * 2 + m2][ni] = __builtin_amdgcn_mfma_f32_16x16x32_bf16(
                            afr[m2][ks], bfr[ni][ks], acc[q * 2 + m2][ni], 0, 0, 0);
            __builtin_amdgcn_s_setprio(0);
        }
    }

#pragma unroll
    for (int mi = 0; mi < 8; ++mi) {
#pragma unroll
        for (int ni = 0; ni < 4; ++ni) {
            int col = col0 + wn * 64 + ni * 16 + l15;
            float bv = bias ? bias[col] : 0.f;
#pragma unroll
            for (int r = 0; r < 4; ++r) {
                int row = row0 + wr * 128 + mi * 16 + g * 4 + r;
                float v = acc[mi][ni][r] + bv;
                float vp = __shfl_xor(v, 1);
                if (!(l15 & 1)) {
                    unsigned int u = (unsigned int)f2b(v) | ((unsigned int)f2b(vp) << 16);
                    *(unsigned int*)&C16[(long)row * ldc + col] = u;
                }
            }
        }
    }
}

// ---------------------------------------------------------------------------
// bf16 MFMA GEMM, m97 structure (128x128, BK=64, 4 waves, gload_lds).
// ---------------------------------------------------------------------------
__global__ __launch_bounds__(256)
void gemm_bf16(const unsigned short* __restrict__ A, long sA, int lda,
               const unsigned short* __restrict__ B, long sB, int ldb,
               const float* __restrict__ bias,
               const float* __restrict__ resid, long sR, int ldr,
               float* __restrict__ C32, long sC32, int ldc32,
               unsigned short* __restrict__ C16, long sC16, int ldc16,
               float* __restrict__ C32b, int ldc32b,
               int M, int N, int K, int act)
{
    __shared__ __align__(16) unsigned short As[128 * 64];
    __shared__ __align__(16) unsigned short Bs[128 * 64];
    int bz = blockIdx.z;
    const unsigned short* Ab = A + (long)bz * sA;
    const unsigned short* Bb = B + (long)bz * sB;
    int row0 = blockIdx.y * 128, col0 = blockIdx.x * 128;
    int t = threadIdx.x;
    int w = t >> 6, l = t & 63, l15 = l & 15, g = l >> 4;
    int wr = w >> 1, wc = w & 1;
    int srow = l >> 3;
    int scol = (l & 7) * 8;
    f32x4 zero4 = {0.f, 0.f, 0.f, 0.f};
    f32x4 acc[4][4];
#pragma unroll
    for (int i = 0; i < 4; ++i)
#pragma unroll
        for (int j = 0; j < 4; ++j) acc[i][j] = zero4;

    for (int k0 = 0; k0 < K; k0 += 64) {
        __syncthreads();
#pragma unroll
        for (int c = 0; c < 4; ++c) {
            int r = w * 32 + c * 8;
            gload16(&Ab[(long)(row0 + r + srow) * lda + k0 + scol], &As[r * 64]);
            gload16(&Bb[(long)(col0 + r + srow) * ldb + k0 + scol], &Bs[r * 64]);
        }
        __syncthreads();
        bf16x8 af[4][2], bfr[4][2];
#pragma unroll
        for (int mi = 0; mi < 4; ++mi)
#pragma unroll
            for (int ks = 0; ks < 2; ++ks) {
                af[mi][ks] = *(const bf16x8*)&As[(wr * 64 + mi * 16 + l15) * 64 + g * 8 + ks * 32];
                bfr[mi][ks] = *(const bf16x8*)&Bs[(wc * 64 + mi * 16 + l15) * 64 + g * 8 + ks * 32];
            }
#pragma unroll
        for (int ks = 0; ks < 2; ++ks)
#pragma unroll
            for (int mi = 0; mi < 4; ++mi)
#pragma unroll
                for (int ni = 0; ni < 4; ++ni)
                    acc[mi][ni] = __builtin_amdgcn_mfma_f32_16x16x32_bf16(af[mi][ks], bfr[ni][ks], acc[mi][ni], 0, 0, 0);
    }

#pragma unroll
    for (int mi = 0; mi < 4; ++mi) {
#pragma unroll
        for (int ni = 0; ni < 4; ++ni) {
#pragma unroll
            for (int r = 0; r < 4; ++r) {
                int row = row0 + wr * 64 + mi * 16 + g * 4 + r;
                int col = col0 + wc * 64 + ni * 16 + l15;
                float v = acc[mi][ni][r];
                if (bias) v += bias[col];
                if (act == 2) {
                    if (col < 256) {
                        C32[(long)row * ldc32 + col] = v;
                    } else {
                        v = gelu_f(v);
                        C32b[(long)row * ldc32b + (col - 256)] = v;
                        C16[(long)row * ldc16 + (col - 256)] = f2b(v);
                    }
                    continue;
                }
                if (act == 1) v = gelu_f(v);
                if (resid) v += resid[(long)bz * sR + (long)row * ldr + col];
                if (C32) C32[(long)bz * sC32 + (long)row * ldc32 + col] = v;
                if (C16) C16[(long)bz * sC16 + (long)row * ldc16 + col] = f2b(v);
            }
        }
    }
}

// ---------------------------------------------------------------------------
// Flash attention v2: 4 waves x 32 q-rows (q-tile 128), kv-tile 64.
// ---------------------------------------------------------------------------
template <int D>
__global__ __launch_bounds__(256, 2)
void attn_mfma(unsigned short* __restrict__ qkv, int stride, int koff, int voff, float scale)
{
    constexpr int GRL = D / 8;
    constexpr int NITK = (64 * GRL) / 256;
    constexpr int NITV = NITK;
    constexpr int NKS = D / 32;
    constexpr int NF = D / 16;
    constexpr int LV = 72;
    constexpr int LP = 72;
    constexpr int NT = NS / 64;

    __shared__ __align__(16) unsigned short Ks[2][64 * D];
    __shared__ __align__(16) unsigned short Vt[D * LV];
    __shared__ __align__(16) unsigned short Ps[128 * LP];

    int b = blockIdx.z, h = blockIdx.y, qt = blockIdx.x;
    int t = threadIdx.x, w = t >> 6, l = t & 63, l15 = l & 15, g = l >> 4;
    int wq = w * 32;
    long qbase = ((long)b * NS + qt * 128) * stride + h * D;
    long kvbase = (long)b * NS * stride + h * D;

    bf16x8 qreg[2][NKS];
#pragma unroll
    for (int qh = 0; qh < 2; ++qh)
#pragma unroll
        for (int ks = 0; ks < NKS; ++ks)
            qreg[qh][ks] = *(const bf16x8*)&qkv[qbase + (long)(wq + qh * 16 + l15) * stride + g * 8 + ks * 32];

    auto KSTAGE = [&](int c, int kt) {
#pragma unroll
        for (int i = 0; i < NITK; ++i) {
            int gi = t + i * 256;
            int row = gi / GRL, cg = gi % GRL;
            int cgs = cg ^ (row & 7);
            gload16(&qkv[kvbase + (long)(kt * 64 + row) * stride + koff + cgs * 8],
                    &Ks[c][gi * 8]);
        }
    };
    uint4 vp[NITV];
    auto VLOAD = [&](int kt) {
#pragma unroll
        for (int i = 0; i < NITV; ++i) {
            int vgi = t + i * 256;
            int kc = vgi & 63, db = vgi >> 6;
            vp[i] = *(const uint4*)&qkv[kvbase + (long)(kt * 64 + kc) * stride + voff + db * 8];
        }
    };
    auto VWRITE = [&]() {
#pragma unroll
        for (int i = 0; i < NITV; ++i) {
            int vgi = t + i * 256;
            int kc = vgi & 63, db = vgi >> 6;
            uint4 v = vp[i];
            Vt[(db * 8 + 0) * LV + kc] = (unsigned short)(v.x & 0xffff);
            Vt[(db * 8 + 1) * LV + kc] = (unsigned short)(v.x >> 16);
            Vt[(db * 8 + 2) * LV + kc] = (unsigned short)(v.y & 0xffff);
            Vt[(db * 8 + 3) * LV + kc] = (unsigned short)(v.y >> 16);
            Vt[(db * 8 + 4) * LV + kc] = (unsigned short)(v.z & 0xffff);
            Vt[(db * 8 + 5) * LV + kc] = (unsigned short)(v.z >> 16);
            Vt[(db * 8 + 6) * LV + kc] = (unsigned short)(v.w & 0xffff);
            Vt[(db * 8 + 7) * LV + kc] = (unsigned short)(v.w >> 16);
        }
    };

    KSTAGE(0, 0);
    VLOAD(0);
    KSTAGE(1, 1);
    if constexpr (NITK == 4) { VMCNT(4); } else { VMCNT(2); }
    VWRITE();
    LGKMCNT0;
    __builtin_amdgcn_sched_barrier(0);
    __builtin_amdgcn_s_barrier();

    float m_run[2] = {-INFINITY, -INFINITY};
    float l_run[2] = {0.f, 0.f};
    f32x4 zero4 = {0.f, 0.f, 0.f, 0.f};
    f32x4 oacc[2][NF];
#pragma unroll
    for (int qh = 0; qh < 2; ++qh)
#pragma unroll
        for (int nf = 0; nf < NF; ++nf) oacc[qh][nf] = zero4;

    int xr = (l15 & 7) << 4;
    for (int kt = 0; kt < NT; ++kt) {
        if (kt + 1 < NT) VLOAD(kt + 1);

        const char* ksb = (const char*)&Ks[kt & 1][0];
        f32x4 st[4][2];
#pragma unroll
        for (int f = 0; f < 4; ++f)
#pragma unroll
            for (int qh = 0; qh < 2; ++qh) st[f][qh] = zero4;
#pragma unroll
        for (int ks = 0; ks < NKS; ++ks) {
#pragma unroll
            for (int f = 0; f < 4; ++f) {
                int cb = (g * 16 + ks * 64) ^ xr;
                bf16x8 a = *(const bf16x8*)(ksb + (f * 16 + l15) * (D * 2) + cb);
#pragma unroll
                for (int qh = 0; qh < 2; ++qh)
                    st[f][qh] = __builtin_amdgcn_mfma_f32_16x16x32_bf16(a, qreg[qh][ks], st[f][qh], 0, 0, 0);
            }
        }
#pragma unroll
        for (int qh = 0; qh < 2; ++qh) {
            float pm = -INFINITY;
#pragma unroll
            for (int f = 0; f < 4; ++f) {
                st[f][qh] *= scale;
#pragma unroll
                for (int r = 0; r < 4; ++r) pm = fmaxf(pm, st[f][qh][r]);
            }
            pm = fmaxf(pm, __shfl_xor(pm, 16));
            pm = fmaxf(pm, __shfl_xor(pm, 32));
            float mn = fmaxf(m_run[qh], pm);
            float corr = __expf(m_run[qh] - mn);
            float rs = 0.f;
#pragma unroll
            for (int f = 0; f < 4; ++f) {
                float p0 = __expf(st[f][qh][0] - mn);
                float p1 = __expf(st[f][qh][1] - mn);
                float p2 = __expf(st[f][qh][2] - mn);
                float p3 = __expf(st[f][qh][3] - mn);
                rs += (p0 + p1) + (p2 + p3);
                ushort4 pw;
                pw.x = f2b(p0); pw.y = f2b(p1); pw.z = f2b(p2); pw.w = f2b(p3);
                *(ushort4*)&Ps[(wq + qh * 16 + l15) * LP + f * 16 + g * 4] = pw;
            }
            rs += __shfl_xor(rs, 16);
            rs += __shfl_xor(rs, 32);
            l_run[qh] = l_run[qh] * corr + rs;
            m_run[qh] = mn;
            float corrO[4];
#pragma unroll
            for (int r = 0; r < 4; ++r) corrO[r] = __shfl(corr, g * 4 + r);
#pragma unroll
            for (int nf = 0; nf < NF; ++nf)
#pragma unroll
                for (int r = 0; r < 4; ++r) oacc[qh][nf][r] *= corrO[r];
        }
#pragma unroll
        for (int ks2 = 0; ks2 < 2; ++ks2) {
            bf16x8 vb[NF];
#pragma unroll
            for (int nf = 0; nf < NF; ++nf)
                vb[nf] = *(const bf16x8*)&Vt[(nf * 16 + l15) * LV + ks2 * 32 + g * 8];
#pragma unroll
            for (int qh = 0; qh < 2; ++qh) {
                bf16x8 pa = *(const bf16x8*)&Ps[(wq + qh * 16 + l15) * LP + ks2 * 32 + g * 8];
#pragma unroll
                for (int nf = 0; nf < NF; ++nf)
                    oacc[qh][nf] = __builtin_amdgcn_mfma_f32_16x16x32_bf16(pa, vb[nf], oacc[qh][nf], 0, 0, 0);
            }
        }

        if (kt + 1 < NT) {
            LGKMCNT0;
            __builtin_amdgcn_sched_barrier(0);
            __builtin_amdgcn_s_barrier();
            if (kt + 2 < NT) {
                KSTAGE(kt & 1, kt + 2);
                if constexpr (NITK == 4) { VMCNT(4); } else { VMCNT(2); }
            } else {
                VMCNT(0);
            }
            VWRITE();
            LGKMCNT0;
            __builtin_amdgcn_sched_barrier(0);
            __builtin_amdgcn_s_barrier();
        }
    }

#pragma unroll
    for (int qh = 0; qh < 2; ++qh) {
        float lo[4];
#pragma unroll
        for (int r = 0; r < 4; ++r) lo[r] = __shfl(l_run[qh], g * 4 + r);
#pragma unroll
        for (int nf = 0; nf < NF; ++nf)
#pragma unroll
            for (int r = 0; r < 4; ++r) {
                float o = oacc[qh][nf][r] / lo[r];
                qkv[qbase + (long)(wq + qh * 16 + g * 4 + r) * stride + nf * 16 + l15] = f2b(o);
            }
    }
}

// ---------------------------------------------------------------------------
__global__ __launch_bounds__(256)
void maxpart_aff_kernel(const float* __restrict__ aff, float* __restrict__ part)
{
    int sc = blockIdx.x, b = blockIdx.y, t = threadIdx.x;
    float m = -INFINITY;
    for (int s = sc * 32; s < (sc + 1) * 32; ++s)
        m = fmaxf(m, aff[((long)b * NS + s) * NIN + t]);
    part[(b * 32 + sc) * NIN + t] = m;
}

__global__ __launch_bounds__(256)
void rank_input_kernel(const float* __restrict__ part, int* __restrict__ idx_out,
                       float* __restrict__ w_out)
{
    int b = blockIdx.x, t = threadIdx.x;
    __shared__ float lg[256], rv[256];
    float m = part[(b * 32) * NIN + t];
#pragma unroll
    for (int sc = 1; sc < 32; ++sc) m = fmaxf(m, part[(b * 32 + sc) * NIN + t]);
    float l = m * 0.5f;
    lg[t] = l;
    rv[t] = l;
    __syncthreads();
    for (int off = 128; off; off >>= 1) {
        if (t < off) rv[t] = fmaxf(rv[t], rv[t + off]);
        __syncthreads();
    }
    float mx = rv[0];
    __syncthreads();
    float e = expf(l - mx);
    rv[t] = e;
    __syncthreads();
    for (int off = 128; off; off >>= 1) {
        if (t < off) rv[t] += rv[t + off];
        __syncthreads();
    }
    float Zs = rv[0];
    float soft = e / Zs;
    __syncthreads();
    int rank = 0;
    for (int j = 0; j < 256; ++j) {
        float vj = lg[j];
        rank += (vj > l) || (vj == l && j < t);
    }
    rv[t] = (rank < KIN) ? soft : 0.f;
    __syncthreads();
    for (int off = 128; off; off >>= 1) {
        if (t < off) rv[t] += rv[t + off];
        __syncthreads();
    }
    float msum = rv[0];
    if (rank < KIN) {
        idx_out[b * KIN + rank] = t;
        w_out[b * KIN + rank] = soft / (msum + 1e-8f);
    }
}

__global__ __launch_bounds__(512)
void rank_proc_kernel(const float* __restrict__ finals, int* __restrict__ pidx)
{
    int b = blockIdx.x, t = threadIdx.x;
    __shared__ float v[512];
    float xv = finals[b * NPROC + t];
    v[t] = xv;
    __syncthreads();
    int rank = 0;
    for (int j = 0; j < 512; ++j) {
        float vj = v[j];
        rank += (vj > xv) || (vj == xv && j < t);
    }
    if (rank < KPROC) pidx[b * KPROC + rank] = t;
}

__global__ __launch_bounds__(256)
void ln_gather_kernel(const float* __restrict__ a, const float* __restrict__ bsrc,
                      const float* __restrict__ gg, const float* __restrict__ be,
                      const int* __restrict__ idx_in, const float* __restrict__ w_sel,
                      unsigned short* __restrict__ sel_acts)
{
    long row = blockIdx.x;
    int b = blockIdx.x >> 10;
    int t = threadIdx.x;
    float v = a[row * 256 + t] + bsrc[row * 256 + t];
    __shared__ float rv[256];
    __shared__ float lnv[256];
    rv[t] = v;
    __syncthreads();
    for (int off = 128; off; off >>= 1) {
        if (t < off) rv[t] += rv[t + off];
        __syncthreads();
    }
    float mean = rv[0] * (1.f / 256.f);
    __syncthreads();
    float d = v - mean;
    rv[t] = d * d;
    __syncthreads();
    for (int off = 128; off; off >>= 1) {
        if (t < off) rv[t] += rv[t + off];
        __syncthreads();
    }
    float var = rv[0] * (1.f / 256.f);
    lnv[t] = d * rsqrtf(var + 1e-5f) * gg[t] + be[t];
    __syncthreads();
    if (t < KIN) {
        int id = idx_in[b * KIN + t];
        sel_acts[row * KIN + t] = f2b(lnv[id] * w_sel[b * KIN + t]);
    }
}

__global__ void gather_sel_cw_b(const float* __restrict__ comb_w, const int* __restrict__ idx_in,
                                unsigned short* __restrict__ sel_cw)
{
    int gidx = blockIdx.x * 256 + threadIdx.x;
    int b = gidx >> 16;
    int rem = gidx & 65535;
    int pb = rem >> 7, j = rem & 127;
    sel_cw[gidx] = f2b(comb_w[pb * NIN + idx_in[b * KIN + j]]);
}

__global__ void gather_sel_proc_b(const float* __restrict__ proc_acts, const int* __restrict__ pidx,
                                  unsigned short* __restrict__ sel_proc)
{
    int s = blockIdx.x, b = blockIdx.y, j = threadIdx.x;
    long row = (long)b * NS + s;
    sel_proc[row * KPROC + j] = f2b(proc_acts[row * NPROC + pidx[b * KPROC + j]]);
}

__global__ void gather_sel_projT(const float* __restrict__ out_proj_w, const int* __restrict__ pidx,
                                 unsigned short* __restrict__ selT)
{
    int gidx = blockIdx.x * 256 + threadIdx.x;
    int b = gidx >> 15;
    int rem = gidx & 32767;
    int d = rem >> 5;
    int kp0 = (rem & 31) * 8;
    unsigned int u[4];
#pragma unroll
    for (int i = 0; i < 4; ++i) {
        unsigned short e0 = f2b(out_proj_w[(long)pidx[b * KPROC + kp0 + 2 * i] * ND + d]);
        unsigned short e1 = f2b(out_proj_w[(long)pidx[b * KPROC + kp0 + 2 * i + 1] * ND + d]);
        u[i] = (unsigned int)e0 | ((unsigned int)e1 << 16);
    }
    uint4 o; o.x = u[0]; o.y = u[1]; o.z = u[2]; o.w = u[3];
    *(uint4*)&selT[((long)b * ND + d) * KPROC + kp0] = o;
}

__global__ __launch_bounds__(512)
void maxpart_kernel(const float* __restrict__ proc, float* __restrict__ part)
{
    int sc = blockIdx.x, b = blockIdx.y, t = threadIdx.x;
    float m = -INFINITY;
    for (int s = sc * 32; s < (sc + 1) * 32; ++s)
        m = fmaxf(m, proc[((long)b * NS + s) * NPROC + t]);
    part[(b * 32 + sc) * NPROC + t] = m;
}

__global__ __launch_bounds__(512)
void relevance_kernel(const float* __restrict__ part, const int* __restrict__ idx_in,
                      const float* __restrict__ a1w, const float* __restrict__ a1b,
                      const float* __restrict__ a2w, const float* __restrict__ a2b,
                      float* __restrict__ finals)
{
    int b = blockIdx.x, t = threadIdx.x;
    float m = part[(b * 32) * NPROC + t];
#pragma unroll
    for (int sc = 1; sc < 32; ++sc) m = fmaxf(m, part[(b * 32 + sc) * NPROC + t]);
    __shared__ float rel1[512];
    __shared__ int sidx[KIN];
    if (t < KIN) sidx[t] = idx_in[b * KIN + t];
    __syncthreads();
    float r1 = a1b[t];
    const float* a1row = a1w + (long)t * NIN;
    for (int j = 0; j < KIN; ++j) r1 += a1row[sidx[j]];
    rel1[t] = gelu_f(r1);
    __syncthreads();
    float r = a2b[t];
    const float* a2row = a2w + (long)t * 512;
    for (int hh = 0; hh < 512; ++hh) r += rel1[hh] * a2row[hh];
    float sig = 1.f / (1.f + expf(-r));
    finals[b * NPROC + t] = m * sig;
}

// ---------------------------------------------------------------------------
extern "C" void kernel_launch(void* const* d_in, const int* in_sizes, int n_in,
                              void* d_out, int out_size, void* d_ws, size_t ws_size,
                              hipStream_t stream)
{
    const float* x       = (const float*)d_in[0];
    const float* r_in_w  = (const float*)d_in[1];
    const float* r_in_b  = (const float*)d_in[2];
    const float* r_out_w = (const float*)d_in[3];
    const float* r_out_b = (const float*)d_in[4];
    const float* aff_w   = (const float*)d_in[5];
    const float* aff_b   = (const float*)d_in[6];
    const float* patterns= (const float*)d_in[7];
    const float* i_in_w  = (const float*)d_in[8];
    const float* i_in_b  = (const float*)d_in[9];
    const float* i_out_w = (const float*)d_in[10];
    const float* i_out_b = (const float*)d_in[11];
    const float* ln_g    = (const float*)d_in[12];
    const float* ln_b    = (const float*)d_in[13];
    const float* comb_w  = (const float*)d_in[14];
    const float* out_proj_w = (const float*)d_in[15];
    const float* a1w     = (const float*)d_in[16];
    const float* a1b     = (const float*)d_in[17];
    const float* a2w     = (const float*)d_in[18];
    const float* a2b     = (const float*)d_in[19];
    float* out = (float*)d_out;

    char* ws = (char*)d_ws;
    unsigned short* qkv1b    = (unsigned short*)(ws + 0);
    unsigned short* contextb = (unsigned short*)(ws + 50331648);
    unsigned short* xb       = (unsigned short*)(ws + 67108864);
    unsigned short* w_rin_b  = (unsigned short*)(ws + 83886080);
    unsigned short* w_rout_b = (unsigned short*)(ws + 90177536);
    unsigned short* w_aff_b  = (unsigned short*)(ws + 92274688);
    unsigned short* patt_b   = (unsigned short*)(ws + 92798976);
    unsigned short* w_iin_b  = (unsigned short*)(ws + 93323264);
    unsigned short* w_iout_b = (unsigned short*)(ws + 93716480);
    float* w_sel   = (float*)(ws + 93855744);
    int*   idx_in  = (int*)(ws + 93859840);
    float* finals  = (float*)(ws + 93863936);
    int*   pidx    = (int*)(ws + 93880320);
    float* affin   = (float*)(ws + 94019584);
    float* acts0   = (float*)(ws + 102408192);
    unsigned short* acts0b = (unsigned short*)(ws + 110796800);
    unsigned short* qkv2b  = (unsigned short*)(ws + 114991104);
    float* attn2proj = (float*)(ws + 0);
    float* proc_acts = (float*)(ws + 16777216);
    unsigned short* sel_actsb = (unsigned short*)(ws + 33554432);
    unsigned short* sel_cwb   = (unsigned short*)(ws + 35651584);
    unsigned short* sel_procb = (unsigned short*)(ws + 36700160);
    unsigned short* sel_projT = (unsigned short*)(ws + 40894464);
    float* biascat  = (float*)(ws + 45088768);
    float* part_aff = (float*)(ws + 45091840);
    float* maxpart  = (float*)(ws + 45353984);

    cvt_kernel<<<2048, 256, 0, stream>>>(x, xb, (long)NB * NS * ND / 4);
    cvt_kernel<<<1024, 256, 0, stream>>>(r_in_w, w_rin_b, (long)3 * ND * ND / 4);
    cvt_kernel<<<512, 256, 0, stream>>>(r_out_w, w_rout_b, (long)ND * ND / 4);
    cvt_kernel<<<128, 256, 0, stream>>>(aff_w, w_aff_b, (long)NIN * ND / 4);
    cvt_kernel<<<128, 256, 0, stream>>>(patterns, patt_b, (long)NIN * ND / 4);
    cvt_kernel<<<96, 256, 0, stream>>>(i_in_w, w_iin_b, (long)3 * NIN * NIN / 4);
    cvt_kernel<<<32, 256, 0, stream>>>(i_out_w, w_iout_b, (long)NIN * NIN / 4);

    // 1. qkv1 = x @ r_in_w^T + b (4-phase 256^2 pipeline, 384 blocks)
    gemm256<<<384, 512, 0, stream>>>(xb, ND, w_rin_b, ND, r_in_b, qkv1b, 3 * ND, ND, 12);
    // 2. MHA-1
    attn_mfma<128><<<dim3(8, 8, 8), 256, 0, stream>>>(qkv1b, 3 * ND, ND, 2 * ND, 0.088388347648318447f);
    // 3. context (4-phase 256^2 pipeline, 128 blocks)
    gemm256<<<128, 512, 0, stream>>>(qkv1b, 3 * ND, w_rout_b, ND, r_out_b, contextb, ND, ND, 4);
    // 4. fused affinity+patterns (split epilogue)
    hipMemcpyAsync(biascat, aff_b, 256 * sizeof(float), hipMemcpyDeviceToDevice, stream);
    hipMemsetAsync(biascat + 256, 0, 256 * sizeof(float), stream);
    gemm_bf16<<<dim3(4, 64, 1), 256, 0, stream>>>(
        contextb, 0, ND, w_aff_b, 0, ND, biascat, nullptr, 0, 0,
        affin, 0, NIN, acts0b, 0, NIN, acts0, NIN, NB * NS, 2 * NIN, ND, 2);
    // 5. routing
    maxpart_aff_kernel<<<dim3(32, NB), 256, 0, stream>>>(affin, part_aff);
    rank_input_kernel<<<NB, 256, 0, stream>>>(part_aff, idx_in, w_sel);
    // 6. qkv2 (4-phase 256^2 pipeline, 96 blocks)
    gemm256<<<96, 512, 0, stream>>>(acts0b, NIN, w_iin_b, NIN, i_in_b, qkv2b, 3 * NIN, NIN, 3);
    // 7. MHA-2
    attn_mfma<64><<<dim3(8, 4, 8), 256, 0, stream>>>(qkv2b, 3 * NIN, NIN, 2 * NIN, 0.125f);
    // 8. attn2 out-proj
    gemm_bf16<<<dim3(2, 64, 1), 256, 0, stream>>>(
        qkv2b, 0, 3 * NIN, w_iout_b, 0, NIN, i_out_b, nullptr, 0, 0,
        attn2proj, 0, NIN, nullptr, 0, 0, nullptr, 0, NB * NS, NIN, NIN, 0);
    // 9. LN + routed gather (fused)
    ln_gather_kernel<<<NB * NS, 256, 0, stream>>>(acts0, attn2proj, ln_g, ln_b,
                                                  idx_in, w_sel, sel_actsb);
    gather_sel_cw_b<<<2048, 256, 0, stream>>>(comb_w, idx_in, sel_cwb);
    // 10. proc_acts
    gemm_bf16<<<dim3(4, 8, NB), 256, 0, stream>>>(
        sel_actsb, (long)NS * KIN, KIN, sel_cwb, (long)NPROC * KIN, KIN,
        nullptr, nullptr, 0, 0,
        proc_acts, (long)NS * NPROC, NPROC, nullptr, 0, 0, nullptr, 0, NS, NPROC, KIN, 1);
    // 11. final scores + top-256
    maxpart_kernel<<<dim3(32, NB), 512, 0, stream>>>(proc_acts, maxpart);
    relevance_kernel<<<NB, 512, 0, stream>>>(maxpart, idx_in, a1w, a1b, a2w, a2b, finals);
    rank_proc_kernel<<<NB, 512, 0, stream>>>(finals, pidx);
    // 12. output gathers + GEMM + residual
    gather_sel_proc_b<<<dim3(NS, NB), KPROC, 0, stream>>>(proc_acts, pidx, sel_procb);
    gather_sel_projT<<<1024, 256, 0, stream>>>(out_proj_w, pidx, sel_projT);
    gemm_bf16<<<dim3(8, 8, NB), 256, 0, stream>>>(
        sel_procb, (long)NS * KPROC, KPROC, sel_projT, (long)ND * KPROC, KPROC,
        nullptr, x, (long)NS * ND, ND,
        out, (long)NS * ND, ND, nullptr, 0, 0, nullptr, 0, NS, ND, KPROC, 0);
    (void)in_sizes; (void)n_in; (void)out_size; (void)ws_size;
}

// Round 13
// 508.127 us; speedup vs baseline: 10.9430x; 1.0239x over previous
//
#include <hip/hip_runtime.h>
#include <hip/hip_bf16.h>
#include <math.h>

constexpr int NB = 8, NS = 1024, ND = 1024, NIN = 256, NPROC = 512, KIN = 128, KPROC = 256;

typedef __attribute__((ext_vector_type(8))) short bf16x8;
typedef __attribute__((ext_vector_type(4))) float f32x4;

#define VMCNT(n) asm volatile("s_waitcnt vmcnt(" #n ")" ::: "memory")
#define LGKMCNT(n) asm volatile("s_waitcnt lgkmcnt(" #n ")" ::: "memory")

__device__ inline float gelu_f(float x) {
    return 0.5f * x * (1.0f + erff(x * 0.7071067811865476f));
}
__device__ inline unsigned short f2b(float f) {
    __hip_bfloat16 h = __float2bfloat16(f);
    return *reinterpret_cast<unsigned short*>(&h);
}
__device__ inline void gload16(const void* g, void* l) {
    __builtin_amdgcn_global_load_lds(
        (const __attribute__((address_space(1))) void*)g,
        (__attribute__((address_space(3))) void*)l, 16, 0, 0);
}

// ---------------------------------------------------------------------------
// Fused f32->bf16 conversions for all weights/inputs + biascat init.
// Segment boundaries in float4 units (compile-time constants).
// ---------------------------------------------------------------------------
__global__ __launch_bounds__(256)
void cvt_all_kernel(const float* __restrict__ x, const float* __restrict__ rin,
                    const float* __restrict__ rout, const float* __restrict__ affw,
                    const float* __restrict__ patt, const float* __restrict__ iin,
                    const float* __restrict__ iout, const float* __restrict__ aff_b,
                    unsigned short* __restrict__ xb, unsigned short* __restrict__ rinb,
                    unsigned short* __restrict__ routb, unsigned short* __restrict__ affbw,
                    unsigned short* __restrict__ pattb, unsigned short* __restrict__ iinb,
                    unsigned short* __restrict__ ioutb, float* __restrict__ biascat)
{
    if (blockIdx.x == 0) {
        int t = threadIdx.x;
        biascat[t] = aff_b[t];
        biascat[256 + t] = 0.f;
    }
    long gi = (long)blockIdx.x * 256 + threadIdx.x;
    long stride = (long)gridDim.x * 256;
    for (; gi < 3342336; gi += stride) {
        const float4* s; ushort4* d; long off;
        if (gi < 2097152)      { s = (const float4*)x;    d = (ushort4*)xb;    off = gi; }
        else if (gi < 2883584) { s = (const float4*)rin;  d = (ushort4*)rinb;  off = gi - 2097152; }
        else if (gi < 3145728) { s = (const float4*)rout; d = (ushort4*)routb; off = gi - 2883584; }
        else if (gi < 3211264) { s = (const float4*)affw; d = (ushort4*)affbw; off = gi - 3145728; }
        else if (gi < 3276800) { s = (const float4*)patt; d = (ushort4*)pattb; off = gi - 3211264; }
        else if (gi < 3325952) { s = (const float4*)iin;  d = (ushort4*)iinb;  off = gi - 3276800; }
        else                   { s = (const float4*)iout; d = (ushort4*)ioutb; off = gi - 3325952; }
        float4 v = s[off];
        ushort4 o;
        o.x = f2b(v.x); o.y = f2b(v.y); o.z = f2b(v.z); o.w = f2b(v.w);
        d[off] = o;
    }
}

// ---------------------------------------------------------------------------
// 256x256 bf16 MFMA GEMM — 4-phase/tile, fragment-pipelined counted-lgkm
// schedule. Phase p's MFMA consumes fragments read in phase p-1 (afrA/afrB
// ping-pong); only phase 0 pays fresh-read latency. Gates: vmcnt(2)@p0
// (B01,B23,A02 of tile done), vmcnt(2)@p1 (A13 done; 0 on last tile).
// lgkm chain: p0 issue 16 -> wait<=4; p1/p2 issue 4 -> wait<=4; p3 wait 0.
// ---------------------------------------------------------------------------
__global__ __launch_bounds__(512, 1)
void gemm256(const unsigned short* __restrict__ A, int lda,
             const unsigned short* __restrict__ B, int ldb,
             const float* __restrict__ bias,
             unsigned short* __restrict__ C16, int ldc,
             int K, int nbx)
{
    __shared__ __align__(16) unsigned short Abuf[2][256 * 64];
    __shared__ __align__(16) unsigned short Bbuf[2][256 * 64];
    int o = blockIdx.x;
    int cpx = gridDim.x >> 3;
    int swz = (o & 7) * cpx + (o >> 3);
    int by = swz / nbx, bx = swz - by * nbx;
    int row0 = by * 256, col0 = bx * 256;

    int t = threadIdx.x;
    int w = t >> 6, l = t & 63, l15 = l & 15, g = l >> 4;
    int wr = w >> 2, wn = w & 3;
    int srow = l >> 3;
    int sgr = (l & 7) ^ srow;
    int xr = (l15 & 7) << 4;
    int NT = K >> 6;

    f32x4 acc[8][4];
#pragma unroll
    for (int i = 0; i < 8; ++i)
#pragma unroll
        for (int j = 0; j < 4; ++j) acc[i][j] = (f32x4){0.f, 0.f, 0.f, 0.f};

    const unsigned short* Asrc = A + (long)row0 * lda + sgr * 8;
    const unsigned short* Bsrc = B + (long)col0 * ldb + sgr * 8;

    auto PART = [&](int c, int kt, int part) {
        int k0 = kt * 64;
        if (part == 0) {
            int r0 = 0 * 64 + w * 8, r1 = 1 * 64 + w * 8;
            gload16(&Bsrc[(long)(r0 + srow) * ldb + k0], &Bbuf[c][r0 * 64]);
            gload16(&Bsrc[(long)(r1 + srow) * ldb + k0], &Bbuf[c][r1 * 64]);
        } else if (part == 1) {
            int r0 = 2 * 64 + w * 8, r1 = 3 * 64 + w * 8;
            gload16(&Bsrc[(long)(r0 + srow) * ldb + k0], &Bbuf[c][r0 * 64]);
            gload16(&Bsrc[(long)(r1 + srow) * ldb + k0], &Bbuf[c][r1 * 64]);
        } else if (part == 2) {
            int r0 = 0 * 64 + w * 8, r1 = 2 * 64 + w * 8;
            gload16(&Asrc[(long)(r0 + srow) * lda + k0], &Abuf[c][r0 * 64]);
            gload16(&Asrc[(long)(r1 + srow) * lda + k0], &Abuf[c][r1 * 64]);
        } else {
            int r0 = 1 * 64 + w * 8, r1 = 3 * 64 + w * 8;
            gload16(&Asrc[(long)(r0 + srow) * lda + k0], &Abuf[c][r0 * 64]);
            gload16(&Asrc[(long)(r1 + srow) * lda + k0], &Abuf[c][r1 * 64]);
        }
    };

    PART(0, 0, 0); PART(0, 0, 1); PART(0, 0, 2); PART(0, 0, 3);

#define AFR_LOAD(AF, QQ) \
    _Pragma("unroll") for (int m2 = 0; m2 < 2; ++m2) \
    _Pragma("unroll") for (int ks = 0; ks < 2; ++ks) { \
        int row_ = wr * 128 + ((QQ) * 2 + m2) * 16 + l15; \
        int cb_ = (g * 16 + ks * 64) ^ xr; \
        AF[m2][ks] = *(const bf16x8*)(Ab_ + row_ * 128 + cb_); \
    }
#define DO_MFMA(QQ, AF) do { \
    __builtin_amdgcn_s_setprio(1); \
    _Pragma("unroll") for (int ks = 0; ks < 2; ++ks) \
    _Pragma("unroll") for (int m2 = 0; m2 < 2; ++m2) \
    _Pragma("unroll") for (int ni = 0; ni < 4; ++ni) \
        acc[(QQ) * 2 + m2][ni] = __builtin_amdgcn_mfma_f32_16x16x32_bf16( \
            AF[m2][ks], bfr[ni][ks], acc[(QQ) * 2 + m2][ni], 0, 0, 0); \
    __builtin_amdgcn_s_setprio(0); } while (0)

    for (int T = 0; T < NT; ++T) {
        int c = T & 1;
        const char* Ab_ = (const char*)&Abuf[c][0];
        const char* Bb_ = (const char*)&Bbuf[c][0];
        bool haveNext = (T + 1 < NT);
        bf16x8 bfr[4][2], afrA[2][2], afrB[2][2];

        // phase 0
        VMCNT(2);
        __builtin_amdgcn_s_barrier();
        asm volatile("" ::: "memory");
#pragma unroll
        for (int ni = 0; ni < 4; ++ni)
#pragma unroll
            for (int ks = 0; ks < 2; ++ks) {
                int row = wn * 64 + ni * 16 + l15;
                int cb = (g * 16 + ks * 64) ^ xr;
                bfr[ni][ks] = *(const bf16x8*)(Bb_ + row * 128 + cb);
            }
        AFR_LOAD(afrA, 0);
        AFR_LOAD(afrB, 1);
        if (haveNext) PART(c ^ 1, T + 1, 0);
        LGKMCNT(4);
        __builtin_amdgcn_sched_barrier(0);
        DO_MFMA(0, afrA);

        // phase 1
        if (haveNext) { VMCNT(2); } else { VMCNT(0); }
        __builtin_amdgcn_s_barrier();
        asm volatile("" ::: "memory");
        AFR_LOAD(afrA, 2);
        if (haveNext) PART(c ^ 1, T + 1, 1);
        LGKMCNT(4);
        __builtin_amdgcn_sched_barrier(0);
        DO_MFMA(1, afrB);

        // phase 2
        __builtin_amdgcn_s_barrier();
        asm volatile("" ::: "memory");
        AFR_LOAD(afrB, 3);
        if (haveNext) PART(c ^ 1, T + 1, 2);
        LGKMCNT(4);
        __builtin_amdgcn_sched_barrier(0);
        DO_MFMA(2, afrA);

        // phase 3
        __builtin_amdgcn_s_barrier();
        asm volatile("" ::: "memory");
        if (haveNext) PART(c ^ 1, T + 1, 3);
        LGKMCNT(0);
        __builtin_amdgcn_sched_barrier(0);
        DO_MFMA(3, afrB);
    }
#undef AFR_LOAD
#undef DO_MFMA

    // epilogue: paired-lane dword bf16 stores
#pragma unroll
    for (int mi = 0; mi < 8; ++mi) {
#pragma unroll
        for (int ni = 0; ni < 4; ++ni) {
            int col = col0 + wn * 64 + ni * 16 + l15;
            float bv = bias ? bias[col] : 0.f;
#pragma unroll
            for (int r = 0; r < 4; ++r) {
                int row = row0 + wr * 128 + mi * 16 + g * 4 + r;
                float v = acc[mi][ni][r] + bv;
                float vp = __shfl_xor(v, 1);
                if (!(l15 & 1)) {
                    unsigned int u = (unsigned int)f2b(v) | ((unsigned int)f2b(vp) << 16);
                    *(unsigned int*)&C16[(long)row * ldc + col] = u;
                }
            }
        }
    }
}

// ---------------------------------------------------------------------------
// bf16 MFMA GEMM, m97 structure (128x128, BK=64, 4 waves, gload_lds).
// ---------------------------------------------------------------------------
__global__ __launch_bounds__(256)
void gemm_bf16(const unsigned short* __restrict__ A, long sA, int lda,
               const unsigned short* __restrict__ B, long sB, int ldb,
               const float* __restrict__ bias,
               const float* __restrict__ resid, long sR, int ldr,
               float* __restrict__ C32, long sC32, int ldc32,
               unsigned short* __restrict__ C16, long sC16, int ldc16,
               float* __restrict__ C32b, int ldc32b,
               int M, int N, int K, int act)
{
    __shared__ __align__(16) unsigned short As[128 * 64];
    __shared__ __align__(16) unsigned short Bs[128 * 64];
    int bz = blockIdx.z;
    const unsigned short* Ab = A + (long)bz * sA;
    const unsigned short* Bb = B + (long)bz * sB;
    int row0 = blockIdx.y * 128, col0 = blockIdx.x * 128;
    int t = threadIdx.x;
    int w = t >> 6, l = t & 63, l15 = l & 15, g = l >> 4;
    int wr = w >> 1, wc = w & 1;
    int srow = l >> 3;
    int scol = (l & 7) * 8;
    f32x4 zero4 = {0.f, 0.f, 0.f, 0.f};
    f32x4 acc[4][4];
#pragma unroll
    for (int i = 0; i < 4; ++i)
#pragma unroll
        for (int j = 0; j < 4; ++j) acc[i][j] = zero4;

    for (int k0 = 0; k0 < K; k0 += 64) {
        __syncthreads();
#pragma unroll
        for (int c = 0; c < 4; ++c) {
            int r = w * 32 + c * 8;
            gload16(&Ab[(long)(row0 + r + srow) * lda + k0 + scol], &As[r * 64]);
            gload16(&Bb[(long)(col0 + r + srow) * ldb + k0 + scol], &Bs[r * 64]);
        }
        __syncthreads();
        bf16x8 af[4][2], bfr[4][2];
#pragma unroll
        for (int mi = 0; mi < 4; ++mi)
#pragma unroll
            for (int ks = 0; ks < 2; ++ks) {
                af[mi][ks] = *(const bf16x8*)&As[(wr * 64 + mi * 16 + l15) * 64 + g * 8 + ks * 32];
                bfr[mi][ks] = *(const bf16x8*)&Bs[(wc * 64 + mi * 16 + l15) * 64 + g * 8 + ks * 32];
            }
#pragma unroll
        for (int ks = 0; ks < 2; ++ks)
#pragma unroll
            for (int mi = 0; mi < 4; ++mi)
#pragma unroll
                for (int ni = 0; ni < 4; ++ni)
                    acc[mi][ni] = __builtin_amdgcn_mfma_f32_16x16x32_bf16(af[mi][ks], bfr[ni][ks], acc[mi][ni], 0, 0, 0);
    }

#pragma unroll
    for (int mi = 0; mi < 4; ++mi) {
#pragma unroll
        for (int ni = 0; ni < 4; ++ni) {
#pragma unroll
            for (int r = 0; r < 4; ++r) {
                int row = row0 + wr * 64 + mi * 16 + g * 4 + r;
                int col = col0 + wc * 64 + ni * 16 + l15;
                float v = acc[mi][ni][r];
                if (bias) v += bias[col];
                if (act == 2) {
                    if (col < 256) {
                        C32[(long)row * ldc32 + col] = v;
                    } else {
                        v = gelu_f(v);
                        C32b[(long)row * ldc32b + (col - 256)] = v;
                        C16[(long)row * ldc16 + (col - 256)] = f2b(v);
                    }
                    continue;
                }
                if (act == 1) v = gelu_f(v);
                if (resid) v += resid[(long)bz * sR + (long)row * ldr + col];
                if (C32) C32[(long)bz * sC32 + (long)row * ldc32 + col] = v;
                if (C16) C16[(long)bz * sC16 + (long)row * ldc16 + col] = f2b(v);
            }
        }
    }
}

// ---------------------------------------------------------------------------
// Flash attention v2: 4 waves x 32 q-rows (q-tile 128), kv-tile 64.
// ---------------------------------------------------------------------------
template <int D>
__global__ __launch_bounds__(256, 2)
void attn_mfma(unsigned short* __restrict__ qkv, int stride, int koff, int voff, float scale)
{
    constexpr int GRL = D / 8;
    constexpr int NITK = (64 * GRL) / 256;
    constexpr int NITV = NITK;
    constexpr int NKS = D / 32;
    constexpr int NF = D / 16;
    constexpr int LV = 72;
    constexpr int LP = 72;
    constexpr int NT = NS / 64;

    __shared__ __align__(16) unsigned short Ks[2][64 * D];
    __shared__ __align__(16) unsigned short Vt[D * LV];
    __shared__ __align__(16) unsigned short Ps[128 * LP];

    int b = blockIdx.z, h = blockIdx.y, qt = blockIdx.x;
    int t = threadIdx.x, w = t >> 6, l = t & 63, l15 = l & 15, g = l >> 4;
    int wq = w * 32;
    long qbase = ((long)b * NS + qt * 128) * stride + h * D;
    long kvbase = (long)b * NS * stride + h * D;

    bf16x8 qreg[2][NKS];
#pragma unroll
    for (int qh = 0; qh < 2; ++qh)
#pragma unroll
        for (int ks = 0; ks < NKS; ++ks)
            qreg[qh][ks] = *(const bf16x8*)&qkv[qbase + (long)(wq + qh * 16 + l15) * stride + g * 8 + ks * 32];

    auto KSTAGE = [&](int c, int kt) {
#pragma unroll
        for (int i = 0; i < NITK; ++i) {
            int gi = t + i * 256;
            int row = gi / GRL, cg = gi % GRL;
            int cgs = cg ^ (row & 7);
            gload16(&qkv[kvbase + (long)(kt * 64 + row) * stride + koff + cgs * 8],
                    &Ks[c][gi * 8]);
        }
    };
    uint4 vp[NITV];
    auto VLOAD = [&](int kt) {
#pragma unroll
        for (int i = 0; i < NITV; ++i) {
            int vgi = t + i * 256;
            int kc = vgi & 63, db = vgi >> 6;
            vp[i] = *(const uint4*)&qkv[kvbase + (long)(kt * 64 + kc) * stride + voff + db * 8];
        }
    };
    auto VWRITE = [&]() {
#pragma unroll
        for (int i = 0; i < NITV; ++i) {
            int vgi = t + i * 256;
            int kc = vgi & 63, db = vgi >> 6;
            uint4 v = vp[i];
            Vt[(db * 8 + 0) * LV + kc] = (unsigned short)(v.x & 0xffff);
            Vt[(db * 8 + 1) * LV + kc] = (unsigned short)(v.x >> 16);
            Vt[(db * 8 + 2) * LV + kc] = (unsigned short)(v.y & 0xffff);
            Vt[(db * 8 + 3) * LV + kc] = (unsigned short)(v.y >> 16);
            Vt[(db * 8 + 4) * LV + kc] = (unsigned short)(v.z & 0xffff);
            Vt[(db * 8 + 5) * LV + kc] = (unsigned short)(v.z >> 16);
            Vt[(db * 8 + 6) * LV + kc] = (unsigned short)(v.w & 0xffff);
            Vt[(db * 8 + 7) * LV + kc] = (unsigned short)(v.w >> 16);
        }
    };

    KSTAGE(0, 0);
    VLOAD(0);
    KSTAGE(1, 1);
    if constexpr (NITK == 4) { VMCNT(4); } else { VMCNT(2); }
    VWRITE();
    LGKMCNT(0);
    __builtin_amdgcn_sched_barrier(0);
    __builtin_amdgcn_s_barrier();

    float m_run[2] = {-INFINITY, -INFINITY};
    float l_run[2] = {0.f, 0.f};
    f32x4 zero4 = {0.f, 0.f, 0.f, 0.f};
    f32x4 oacc[2][NF];
#pragma unroll
    for (int qh = 0; qh < 2; ++qh)
#pragma unroll
        for (int nf = 0; nf < NF; ++nf) oacc[qh][nf] = zero4;

    int xr = (l15 & 7) << 4;
    for (int kt = 0; kt < NT; ++kt) {
        if (kt + 1 < NT) VLOAD(kt + 1);

        const char* ksb = (const char*)&Ks[kt & 1][0];
        f32x4 st[4][2];
#pragma unroll
        for (int f = 0; f < 4; ++f)
#pragma unroll
            for (int qh = 0; qh < 2; ++qh) st[f][qh] = zero4;
#pragma unroll
        for (int ks = 0; ks < NKS; ++ks) {
#pragma unroll
            for (int f = 0; f < 4; ++f) {
                int cb = (g * 16 + ks * 64) ^ xr;
                bf16x8 a = *(const bf16x8*)(ksb + (f * 16 + l15) * (D * 2) + cb);
#pragma unroll
                for (int qh = 0; qh < 2; ++qh)
                    st[f][qh] = __builtin_amdgcn_mfma_f32_16x16x32_bf16(a, qreg[qh][ks], st[f][qh], 0, 0, 0);
            }
        }
#pragma unroll
        for (int qh = 0; qh < 2; ++qh) {
            float pm = -INFINITY;
#pragma unroll
            for (int f = 0; f < 4; ++f) {
                st[f][qh] *= scale;
#pragma unroll
                for (int r = 0; r < 4; ++r) pm = fmaxf(pm, st[f][qh][r]);
            }
            pm = fmaxf(pm, __shfl_xor(pm, 16));
            pm = fmaxf(pm, __shfl_xor(pm, 32));
            float mn = fmaxf(m_run[qh], pm);
            float corr = __expf(m_run[qh] - mn);
            float rs = 0.f;
#pragma unroll
            for (int f = 0; f < 4; ++f) {
                float p0 = __expf(st[f][qh][0] - mn);
                float p1 = __expf(st[f][qh][1] - mn);
                float p2 = __expf(st[f][qh][2] - mn);
                float p3 = __expf(st[f][qh][3] - mn);
                rs += (p0 + p1) + (p2 + p3);
                ushort4 pw;
                pw.x = f2b(p0); pw.y = f2b(p1); pw.z = f2b(p2); pw.w = f2b(p3);
                *(ushort4*)&Ps[(wq + qh * 16 + l15) * LP + f * 16 + g * 4] = pw;
            }
            rs += __shfl_xor(rs, 16);
            rs += __shfl_xor(rs, 32);
            l_run[qh] = l_run[qh] * corr + rs;
            m_run[qh] = mn;
            float corrO[4];
#pragma unroll
            for (int r = 0; r < 4; ++r) corrO[r] = __shfl(corr, g * 4 + r);
#pragma unroll
            for (int nf = 0; nf < NF; ++nf)
#pragma unroll
                for (int r = 0; r < 4; ++r) oacc[qh][nf][r] *= corrO[r];
        }
#pragma unroll
        for (int ks2 = 0; ks2 < 2; ++ks2) {
            bf16x8 vb[NF];
#pragma unroll
            for (int nf = 0; nf < NF; ++nf)
                vb[nf] = *(const bf16x8*)&Vt[(nf * 16 + l15) * LV + ks2 * 32 + g * 8];
#pragma unroll
            for (int qh = 0; qh < 2; ++qh) {
                bf16x8 pa = *(const bf16x8*)&Ps[(wq + qh * 16 + l15) * LP + ks2 * 32 + g * 8];
#pragma unroll
                for (int nf = 0; nf < NF; ++nf)
                    oacc[qh][nf] = __builtin_amdgcn_mfma_f32_16x16x32_bf16(pa, vb[nf], oacc[qh][nf], 0, 0, 0);
            }
        }

        if (kt + 1 < NT) {
            LGKMCNT(0);
            __builtin_amdgcn_sched_barrier(0);
            __builtin_amdgcn_s_barrier();
            if (kt + 2 < NT) {
                KSTAGE(kt & 1, kt + 2);
                if constexpr (NITK == 4) { VMCNT(4); } else { VMCNT(2); }
            } else {
                VMCNT(0);
            }
            VWRITE();
            LGKMCNT(0);
            __builtin_amdgcn_sched_barrier(0);
            __builtin_amdgcn_s_barrier();
        }
    }

#pragma unroll
    for (int qh = 0; qh < 2; ++qh) {
        float lo[4];
#pragma unroll
        for (int r = 0; r < 4; ++r) lo[r] = __shfl(l_run[qh], g * 4 + r);
#pragma unroll
        for (int nf = 0; nf < NF; ++nf)
#pragma unroll
            for (int r = 0; r < 4; ++r) {
                float o = oacc[qh][nf][r] / lo[r];
                qkv[qbase + (long)(wq + qh * 16 + g * 4 + r) * stride + nf * 16 + l15] = f2b(o);
            }
    }
}

// ---------------------------------------------------------------------------
__global__ __launch_bounds__(256)
void maxpart_aff_kernel(const float* __restrict__ aff, float* __restrict__ part)
{
    int sc = blockIdx.x, b = blockIdx.y, t = threadIdx.x;
    float m = -INFINITY;
    for (int s = sc * 32; s < (sc + 1) * 32; ++s)
        m = fmaxf(m, aff[((long)b * NS + s) * NIN + t]);
    part[(b * 32 + sc) * NIN + t] = m;
}

__global__ __launch_bounds__(256)
void rank_input_kernel(const float* __restrict__ part, int* __restrict__ idx_out,
                       float* __restrict__ w_out)
{
    int b = blockIdx.x, t = threadIdx.x;
    __shared__ float lg[256], rv[256];
    float m = part[(b * 32) * NIN + t];
#pragma unroll
    for (int sc = 1; sc < 32; ++sc) m = fmaxf(m, part[(b * 32 + sc) * NIN + t]);
    float l = m * 0.5f;
    lg[t] = l;
    rv[t] = l;
    __syncthreads();
    for (int off = 128; off; off >>= 1) {
        if (t < off) rv[t] = fmaxf(rv[t], rv[t + off]);
        __syncthreads();
    }
    float mx = rv[0];
    __syncthreads();
    float e = expf(l - mx);
    rv[t] = e;
    __syncthreads();
    for (int off = 128; off; off >>= 1) {
        if (t < off) rv[t] += rv[t + off];
        __syncthreads();
    }
    float Zs = rv[0];
    float soft = e / Zs;
    __syncthreads();
    int rank = 0;
    for (int j = 0; j < 256; ++j) {
        float vj = lg[j];
        rank += (vj > l) || (vj == l && j < t);
    }
    rv[t] = (rank < KIN) ? soft : 0.f;
    __syncthreads();
    for (int off = 128; off; off >>= 1) {
        if (t < off) rv[t] += rv[t + off];
        __syncthreads();
    }
    float msum = rv[0];
    if (rank < KIN) {
        idx_out[b * KIN + rank] = t;
        w_out[b * KIN + rank] = soft / (msum + 1e-8f);
    }
}

__global__ __launch_bounds__(512)
void rank_proc_kernel(const float* __restrict__ finals, int* __restrict__ pidx)
{
    int b = blockIdx.x, t = threadIdx.x;
    __shared__ float v[512];
    float xv = finals[b * NPROC + t];
    v[t] = xv;
    __syncthreads();
    int rank = 0;
    for (int j = 0; j < 512; ++j) {
        float vj = v[j];
        rank += (vj > xv) || (vj == xv && j < t);
    }
    if (rank < KPROC) pidx[b * KPROC + rank] = t;
}

__global__ __launch_bounds__(256)
void ln_gather_kernel(const float* __restrict__ a, const float* __restrict__ bsrc,
                      const float* __restrict__ gg, const float* __restrict__ be,
                      const int* __restrict__ idx_in, const float* __restrict__ w_sel,
                      unsigned short* __restrict__ sel_acts)
{
    long row = blockIdx.x;
    int b = blockIdx.x >> 10;
    int t = threadIdx.x;
    float v = a[row * 256 + t] + bsrc[row * 256 + t];
    __shared__ float rv[256];
    __shared__ float lnv[256];
    rv[t] = v;
    __syncthreads();
    for (int off = 128; off; off >>= 1) {
        if (t < off) rv[t] += rv[t + off];
        __syncthreads();
    }
    float mean = rv[0] * (1.f / 256.f);
    __syncthreads();
    float d = v - mean;
    rv[t] = d * d;
    __syncthreads();
    for (int off = 128; off; off >>= 1) {
        if (t < off) rv[t] += rv[t + off];
        __syncthreads();
    }
    float var = rv[0] * (1.f / 256.f);
    lnv[t] = d * rsqrtf(var + 1e-5f) * gg[t] + be[t];
    __syncthreads();
    if (t < KIN) {
        int id = idx_in[b * KIN + t];
        sel_acts[row * KIN + t] = f2b(lnv[id] * w_sel[b * KIN + t]);
    }
}

__global__ void gather_sel_cw_b(const float* __restrict__ comb_w, const int* __restrict__ idx_in,
                                unsigned short* __restrict__ sel_cw)
{
    int gidx = blockIdx.x * 256 + threadIdx.x;
    int b = gidx >> 16;
    int rem = gidx & 65535;
    int pb = rem >> 7, j = rem & 127;
    sel_cw[gidx] = f2b(comb_w[pb * NIN + idx_in[b * KIN + j]]);
}

__global__ void gather_sel_proc_b(const float* __restrict__ proc_acts, const int* __restrict__ pidx,
                                  unsigned short* __restrict__ sel_proc)
{
    int s = blockIdx.x, b = blockIdx.y, j = threadIdx.x;
    long row = (long)b * NS + s;
    sel_proc[row * KPROC + j] = f2b(proc_acts[row * NPROC + pidx[b * KPROC + j]]);
}

__global__ void gather_sel_projT(const float* __restrict__ out_proj_w, const int* __restrict__ pidx,
                                 unsigned short* __restrict__ selT)
{
    int gidx = blockIdx.x * 256 + threadIdx.x;
    int b = gidx >> 15;
    int rem = gidx & 32767;
    int d = rem >> 5;
    int kp0 = (rem & 31) * 8;
    unsigned int u[4];
#pragma unroll
    for (int i = 0; i < 4; ++i) {
        unsigned short e0 = f2b(out_proj_w[(long)pidx[b * KPROC + kp0 + 2 * i] * ND + d]);
        unsigned short e1 = f2b(out_proj_w[(long)pidx[b * KPROC + kp0 + 2 * i + 1] * ND + d]);
        u[i] = (unsigned int)e0 | ((unsigned int)e1 << 16);
    }
    uint4 o; o.x = u[0]; o.y = u[1]; o.z = u[2]; o.w = u[3];
    *(uint4*)&selT[((long)b * ND + d) * KPROC + kp0] = o;
}

__global__ __launch_bounds__(512)
void maxpart_kernel(const float* __restrict__ proc, float* __restrict__ part)
{
    int sc = blockIdx.x, b = blockIdx.y, t = threadIdx.x;
    float m = -INFINITY;
    for (int s = sc * 32; s < (sc + 1) * 32; ++s)
        m = fmaxf(m, proc[((long)b * NS + s) * NPROC + t]);
    part[(b * 32 + sc) * NPROC + t] = m;
}

__global__ __launch_bounds__(512)
void relevance_kernel(const float* __restrict__ part, const int* __restrict__ idx_in,
                      const float* __restrict__ a1w, const float* __restrict__ a1b,
                      const float* __restrict__ a2w, const float* __restrict__ a2b,
                      float* __restrict__ finals)
{
    int b = blockIdx.x, t = threadIdx.x;
    float m = part[(b * 32) * NPROC + t];
#pragma unroll
    for (int sc = 1; sc < 32; ++sc) m = fmaxf(m, part[(b * 32 + sc) * NPROC + t]);
    __shared__ float rel1[512];
    __shared__ int sidx[KIN];
    if (t < KIN) sidx[t] = idx_in[b * KIN + t];
    __syncthreads();
    float r1 = a1b[t];
    const float* a1row = a1w + (long)t * NIN;
    for (int j = 0; j < KIN; ++j) r1 += a1row[sidx[j]];
    rel1[t] = gelu_f(r1);
    __syncthreads();
    float r = a2b[t];
    const float* a2row = a2w + (long)t * 512;
    for (int hh = 0; hh < 512; ++hh) r += rel1[hh] * a2row[hh];
    float sig = 1.f / (1.f + expf(-r));
    finals[b * NPROC + t] = m * sig;
}

// ---------------------------------------------------------------------------
extern "C" void kernel_launch(void* const* d_in, const int* in_sizes, int n_in,
                              void* d_out, int out_size, void* d_ws, size_t ws_size,
                              hipStream_t stream)
{
    const float* x       = (const float*)d_in[0];
    const float* r_in_w  = (const float*)d_in[1];
    const float* r_in_b  = (const float*)d_in[2];
    const float* r_out_w = (const float*)d_in[3];
    const float* r_out_b = (const float*)d_in[4];
    const float* aff_w   = (const float*)d_in[5];
    const float* aff_b   = (const float*)d_in[6];
    const float* patterns= (const float*)d_in[7];
    const float* i_in_w  = (const float*)d_in[8];
    const float* i_in_b  = (const float*)d_in[9];
    const float* i_out_w = (const float*)d_in[10];
    const float* i_out_b = (const float*)d_in[11];
    const float* ln_g    = (const float*)d_in[12];
    const float* ln_b    = (const float*)d_in[13];
    const float* comb_w  = (const float*)d_in[14];
    const float* out_proj_w = (const float*)d_in[15];
    const float* a1w     = (const float*)d_in[16];
    const float* a1b     = (const float*)d_in[17];
    const float* a2w     = (const float*)d_in[18];
    const float* a2b     = (const float*)d_in[19];
    float* out = (float*)d_out;

    char* ws = (char*)d_ws;
    unsigned short* qkv1b    = (unsigned short*)(ws + 0);
    unsigned short* contextb = (unsigned short*)(ws + 50331648);
    unsigned short* xb       = (unsigned short*)(ws + 67108864);
    unsigned short* w_rin_b  = (unsigned short*)(ws + 83886080);
    unsigned short* w_rout_b = (unsigned short*)(ws + 90177536);
    unsigned short* w_aff_b  = (unsigned short*)(ws + 92274688);
    unsigned short* patt_b   = (unsigned short*)(ws + 92798976);
    unsigned short* w_iin_b  = (unsigned short*)(ws + 93323264);
    unsigned short* w_iout_b = (unsigned short*)(ws + 93716480);
    float* w_sel   = (float*)(ws + 93855744);
    int*   idx_in  = (int*)(ws + 93859840);
    float* finals  = (float*)(ws + 93863936);
    int*   pidx    = (int*)(ws + 93880320);
    float* affin   = (float*)(ws + 94019584);
    float* acts0   = (float*)(ws + 102408192);
    unsigned short* acts0b = (unsigned short*)(ws + 110796800);
    unsigned short* qkv2b  = (unsigned short*)(ws + 114991104);
    float* attn2proj = (float*)(ws + 0);
    float* proc_acts = (float*)(ws + 16777216);
    unsigned short* sel_actsb = (unsigned short*)(ws + 33554432);
    unsigned short* sel_cwb   = (unsigned short*)(ws + 35651584);
    unsigned short* sel_procb = (unsigned short*)(ws + 36700160);
    unsigned short* sel_projT = (unsigned short*)(ws + 40894464);
    float* biascat  = (float*)(ws + 45088768);
    float* part_aff = (float*)(ws + 45091840);
    float* maxpart  = (float*)(ws + 45353984);

    // 0. all conversions + biascat init in one launch
    cvt_all_kernel<<<2048, 256, 0, stream>>>(
        x, r_in_w, r_out_w, aff_w, patterns, i_in_w, i_out_w, aff_b,
        xb, w_rin_b, w_rout_b, w_aff_b, patt_b, w_iin_b, w_iout_b, biascat);

    // 1. qkv1 = x @ r_in_w^T + b (frag-pipelined 256^2, 384 blocks)
    gemm256<<<384, 512, 0, stream>>>(xb, ND, w_rin_b, ND, r_in_b, qkv1b, 3 * ND, ND, 12);
    // 2. MHA-1
    attn_mfma<128><<<dim3(8, 8, 8), 256, 0, stream>>>(qkv1b, 3 * ND, ND, 2 * ND, 0.088388347648318447f);
    // 3. context (frag-pipelined 256^2, 128 blocks)
    gemm256<<<128, 512, 0, stream>>>(qkv1b, 3 * ND, w_rout_b, ND, r_out_b, contextb, ND, ND, 4);
    // 4. fused affinity+patterns (split epilogue)
    gemm_bf16<<<dim3(4, 64, 1), 256, 0, stream>>>(
        contextb, 0, ND, w_aff_b, 0, ND, biascat, nullptr, 0, 0,
        affin, 0, NIN, acts0b, 0, NIN, acts0, NIN, NB * NS, 2 * NIN, ND, 2);
    // 5. routing
    maxpart_aff_kernel<<<dim3(32, NB), 256, 0, stream>>>(affin, part_aff);
    rank_input_kernel<<<NB, 256, 0, stream>>>(part_aff, idx_in, w_sel);
    // 6. qkv2 (frag-pipelined 256^2, 96 blocks)
    gemm256<<<96, 512, 0, stream>>>(acts0b, NIN, w_iin_b, NIN, i_in_b, qkv2b, 3 * NIN, NIN, 3);
    // 7. MHA-2
    attn_mfma<64><<<dim3(8, 4, 8), 256, 0, stream>>>(qkv2b, 3 * NIN, NIN, 2 * NIN, 0.125f);
    // 8. attn2 out-proj
    gemm_bf16<<<dim3(2, 64, 1), 256, 0, stream>>>(
        qkv2b, 0, 3 * NIN, w_iout_b, 0, NIN, i_out_b, nullptr, 0, 0,
        attn2proj, 0, NIN, nullptr, 0, 0, nullptr, 0, NB * NS, NIN, NIN, 0);
    // 9. LN + routed gather (fused)
    ln_gather_kernel<<<NB * NS, 256, 0, stream>>>(acts0, attn2proj, ln_g, ln_b,
                                                  idx_in, w_sel, sel_actsb);
    gather_sel_cw_b<<<2048, 256, 0, stream>>>(comb_w, idx_in, sel_cwb);
    // 10. proc_acts
    gemm_bf16<<<dim3(4, 8, NB), 256, 0, stream>>>(
        sel_actsb, (long)NS * KIN, KIN, sel_cwb, (long)NPROC * KIN, KIN,
        nullptr, nullptr, 0, 0,
        proc_acts, (long)NS * NPROC, NPROC, nullptr, 0, 0, nullptr, 0, NS, NPROC, KIN, 1);
    // 11. final scores + top-256
    maxpart_kernel<<<dim3(32, NB), 512, 0, stream>>>(proc_acts, maxpart);
    relevance_kernel<<<NB, 512, 0, stream>>>(maxpart, idx_in, a1w, a1b, a2w, a2b, finals);
    rank_proc_kernel<<<NB, 512, 0, stream>>>(finals, pidx);
    // 12. output gathers + GEMM + residual
    gather_sel_proc_b<<<dim3(NS, NB), KPROC, 0, stream>>>(proc_acts, pidx, sel_procb);
    gather_sel_projT<<<1024, 256, 0, stream>>>(out_proj_w, pidx, sel_projT);
    gemm_bf16<<<dim3(8, 8, NB), 256, 0, stream>>>(
        sel_procb, (long)NS * KPROC, KPROC, sel_projT, (long)ND * KPROC, KPROC,
        nullptr, x, (long)NS * ND, ND,
        out, (long)NS * ND, ND, nullptr, 0, 0, nullptr, 0, NS, ND, KPROC, 0);
    (void)in_sizes; (void)n_in; (void)out_size; (void)ws_size;
}

// Round 14
// 479.808 us; speedup vs baseline: 11.5889x; 1.0590x over previous
//
#include <hip/hip_runtime.h>
#include <hip/hip_bf16.h>
#include <math.h>

constexpr int NB = 8, NS = 1024, ND = 1024, NIN = 256, NPROC = 512, KIN = 128, KPROC = 256;

typedef __attribute__((ext_vector_type(8))) short bf16x8;
typedef __attribute__((ext_vector_type(4))) float f32x4;

#define VMCNT(n) asm volatile("s_waitcnt vmcnt(" #n ")" ::: "memory")
#define LGKMCNT(n) asm volatile("s_waitcnt lgkmcnt(" #n ")" ::: "memory")

__device__ inline float gelu_f(float x) {
    return 0.5f * x * (1.0f + erff(x * 0.7071067811865476f));
}
__device__ inline unsigned short f2b(float f) {
    __hip_bfloat16 h = __float2bfloat16(f);
    return *reinterpret_cast<unsigned short*>(&h);
}
__device__ inline void gload16(const void* g, void* l) {
    __builtin_amdgcn_global_load_lds(
        (const __attribute__((address_space(1))) void*)g,
        (__attribute__((address_space(3))) void*)l, 16, 0, 0);
}

// ---------------------------------------------------------------------------
// Fused f32->bf16 conversions + biascat init.
// ---------------------------------------------------------------------------
__global__ __launch_bounds__(256)
void cvt_all_kernel(const float* __restrict__ x, const float* __restrict__ rin,
                    const float* __restrict__ rout, const float* __restrict__ affw,
                    const float* __restrict__ patt, const float* __restrict__ iin,
                    const float* __restrict__ iout, const float* __restrict__ aff_b,
                    unsigned short* __restrict__ xb, unsigned short* __restrict__ rinb,
                    unsigned short* __restrict__ routb, unsigned short* __restrict__ affbw,
                    unsigned short* __restrict__ pattb, unsigned short* __restrict__ iinb,
                    unsigned short* __restrict__ ioutb, float* __restrict__ biascat)
{
    if (blockIdx.x == 0) {
        int t = threadIdx.x;
        biascat[t] = aff_b[t];
        biascat[256 + t] = 0.f;
    }
    long gi = (long)blockIdx.x * 256 + threadIdx.x;
    long stride = (long)gridDim.x * 256;
    for (; gi < 3342336; gi += stride) {
        const float4* s; ushort4* d; long off;
        if (gi < 2097152)      { s = (const float4*)x;    d = (ushort4*)xb;    off = gi; }
        else if (gi < 2883584) { s = (const float4*)rin;  d = (ushort4*)rinb;  off = gi - 2097152; }
        else if (gi < 3145728) { s = (const float4*)rout; d = (ushort4*)routb; off = gi - 2883584; }
        else if (gi < 3211264) { s = (const float4*)affw; d = (ushort4*)affbw; off = gi - 3145728; }
        else if (gi < 3276800) { s = (const float4*)patt; d = (ushort4*)pattb; off = gi - 3211264; }
        else if (gi < 3325952) { s = (const float4*)iin;  d = (ushort4*)iinb;  off = gi - 3276800; }
        else                   { s = (const float4*)iout; d = (ushort4*)ioutb; off = gi - 3325952; }
        float4 v = s[off];
        ushort4 o;
        o.x = f2b(v.x); o.y = f2b(v.y); o.z = f2b(v.z); o.w = f2b(v.w);
        d[off] = o;
    }
}

// ---------------------------------------------------------------------------
// 128x128 bf16 MFMA GEMM, BK=32 double-buffer, 4 waves, counted-vmcnt
// 2-barrier pipeline + XOR swizzle + XCD grid swizzle. ~160 regs/thread ->
// 3 blocks/CU (12 waves), 32KB LDS. C16 = A @ B^T + bias.
// Grid 1D (M/128)*(N/128), %8==0. K%32==0, K>=96.
// ---------------------------------------------------------------------------
__global__ __launch_bounds__(256)
void gemm128s(const unsigned short* __restrict__ A, int lda,
              const unsigned short* __restrict__ B, int ldb,
              const float* __restrict__ bias,
              unsigned short* __restrict__ C16, int ldc,
              int K, int nbx)
{
    __shared__ __align__(16) unsigned short Ab[2][128 * 32];
    __shared__ __align__(16) unsigned short Bb[2][128 * 32];
    int o = blockIdx.x;
    int cpx = gridDim.x >> 3;
    int swz = (o & 7) * cpx + (o >> 3);
    int by = swz / nbx, bx = swz - by * nbx;
    int row0 = by * 128, col0 = bx * 128;

    int t = threadIdx.x;
    int w = t >> 6, l = t & 63, l15 = l & 15, g = l >> 4;
    int wr = w >> 1, wc = w & 1;
    int NT = K >> 5;

    f32x4 acc[4][4];
#pragma unroll
    for (int i = 0; i < 4; ++i)
#pragma unroll
        for (int j = 0; j < 4; ++j) acc[i][j] = (f32x4){0.f, 0.f, 0.f, 0.f};

    // staging map: granule gi = t + i*256 in [0,512): row = gi>>2, slot cg = gi&3,
    // source granule = cg ^ (row&1) (matches read-side XOR).
    auto STAGE = [&](int c, int kt) {
        int k0 = kt * 32;
#pragma unroll
        for (int i = 0; i < 2; ++i) {
            int gi = t + i * 256;
            int row = gi >> 2, cg = gi & 3;
            int cgs = cg ^ (row & 1);
            gload16(&A[(long)(row0 + row) * lda + k0 + cgs * 8], &Ab[c][gi * 8]);
        }
#pragma unroll
        for (int i = 0; i < 2; ++i) {
            int gi = t + i * 256;
            int row = gi >> 2, cg = gi & 3;
            int cgs = cg ^ (row & 1);
            gload16(&B[(long)(col0 + row) * ldb + k0 + cgs * 8], &Bb[c][gi * 8]);
        }
    };

    STAGE(0, 0);
    STAGE(1, 1);

    int cbr = (g * 16) ^ ((l15 & 1) << 4);  // read-side byte col (XOR swizzle)

    for (int T = 0; T < NT; ++T) {
        int c = T & 1;
        if (T + 1 < NT) { VMCNT(4); } else { VMCNT(0); }
        __builtin_amdgcn_s_barrier();
        asm volatile("" ::: "memory");

        const char* Ab_ = (const char*)&Ab[c][0];
        const char* Bb_ = (const char*)&Bb[c][0];
        bf16x8 af[4], bfr[4];
#pragma unroll
        for (int mi = 0; mi < 4; ++mi)
            af[mi] = *(const bf16x8*)(Ab_ + (wr * 64 + mi * 16 + l15) * 64 + cbr);
#pragma unroll
        for (int ni = 0; ni < 4; ++ni)
            bfr[ni] = *(const bf16x8*)(Bb_ + (wc * 64 + ni * 16 + l15) * 64 + cbr);

        LGKMCNT(0);
        __builtin_amdgcn_sched_barrier(0);
        __builtin_amdgcn_s_barrier();
        asm volatile("" ::: "memory");
        if (T + 2 < NT) STAGE(c, T + 2);

        __builtin_amdgcn_s_setprio(1);
#pragma unroll
        for (int mi = 0; mi < 4; ++mi)
#pragma unroll
            for (int ni = 0; ni < 4; ++ni)
                acc[mi][ni] = __builtin_amdgcn_mfma_f32_16x16x32_bf16(
                    af[mi], bfr[ni], acc[mi][ni], 0, 0, 0);
        __builtin_amdgcn_s_setprio(0);
    }

    // epilogue: paired-lane dword bf16 stores
#pragma unroll
    for (int mi = 0; mi < 4; ++mi) {
#pragma unroll
        for (int ni = 0; ni < 4; ++ni) {
            int col = col0 + wc * 64 + ni * 16 + l15;
            float bv = bias ? bias[col] : 0.f;
#pragma unroll
            for (int r = 0; r < 4; ++r) {
                int row = row0 + wr * 64 + mi * 16 + g * 4 + r;
                float v = acc[mi][ni][r] + bv;
                float vp = __shfl_xor(v, 1);
                if (!(l15 & 1)) {
                    unsigned int u = (unsigned int)f2b(v) | ((unsigned int)f2b(vp) << 16);
                    *(unsigned int*)&C16[(long)row * ldc + col] = u;
                }
            }
        }
    }
}

// ---------------------------------------------------------------------------
// bf16 MFMA GEMM, m97 structure (128x128, BK=64, 4 waves, gload_lds).
// Used for epilogue-fused call sites (split aff+patt, attn2proj, proc, out).
// ---------------------------------------------------------------------------
__global__ __launch_bounds__(256)
void gemm_bf16(const unsigned short* __restrict__ A, long sA, int lda,
               const unsigned short* __restrict__ B, long sB, int ldb,
               const float* __restrict__ bias,
               const float* __restrict__ resid, long sR, int ldr,
               float* __restrict__ C32, long sC32, int ldc32,
               unsigned short* __restrict__ C16, long sC16, int ldc16,
               float* __restrict__ C32b, int ldc32b,
               int M, int N, int K, int act)
{
    __shared__ __align__(16) unsigned short As[128 * 64];
    __shared__ __align__(16) unsigned short Bs[128 * 64];
    int bz = blockIdx.z;
    const unsigned short* Abp = A + (long)bz * sA;
    const unsigned short* Bbp = B + (long)bz * sB;
    int row0 = blockIdx.y * 128, col0 = blockIdx.x * 128;
    int t = threadIdx.x;
    int w = t >> 6, l = t & 63, l15 = l & 15, g = l >> 4;
    int wr = w >> 1, wc = w & 1;
    int srow = l >> 3;
    int scol = (l & 7) * 8;
    f32x4 zero4 = {0.f, 0.f, 0.f, 0.f};
    f32x4 acc[4][4];
#pragma unroll
    for (int i = 0; i < 4; ++i)
#pragma unroll
        for (int j = 0; j < 4; ++j) acc[i][j] = zero4;

    for (int k0 = 0; k0 < K; k0 += 64) {
        __syncthreads();
#pragma unroll
        for (int c = 0; c < 4; ++c) {
            int r = w * 32 + c * 8;
            gload16(&Abp[(long)(row0 + r + srow) * lda + k0 + scol], &As[r * 64]);
            gload16(&Bbp[(long)(col0 + r + srow) * ldb + k0 + scol], &Bs[r * 64]);
        }
        __syncthreads();
        bf16x8 af[4][2], bfr[4][2];
#pragma unroll
        for (int mi = 0; mi < 4; ++mi)
#pragma unroll
            for (int ks = 0; ks < 2; ++ks) {
                af[mi][ks] = *(const bf16x8*)&As[(wr * 64 + mi * 16 + l15) * 64 + g * 8 + ks * 32];
                bfr[mi][ks] = *(const bf16x8*)&Bs[(wc * 64 + mi * 16 + l15) * 64 + g * 8 + ks * 32];
            }
#pragma unroll
        for (int ks = 0; ks < 2; ++ks)
#pragma unroll
            for (int mi = 0; mi < 4; ++mi)
#pragma unroll
                for (int ni = 0; ni < 4; ++ni)
                    acc[mi][ni] = __builtin_amdgcn_mfma_f32_16x16x32_bf16(af[mi][ks], bfr[ni][ks], acc[mi][ni], 0, 0, 0);
    }

#pragma unroll
    for (int mi = 0; mi < 4; ++mi) {
#pragma unroll
        for (int ni = 0; ni < 4; ++ni) {
#pragma unroll
            for (int r = 0; r < 4; ++r) {
                int row = row0 + wr * 64 + mi * 16 + g * 4 + r;
                int col = col0 + wc * 64 + ni * 16 + l15;
                float v = acc[mi][ni][r];
                if (bias) v += bias[col];
                if (act == 2) {
                    if (col < 256) {
                        C32[(long)row * ldc32 + col] = v;
                    } else {
                        v = gelu_f(v);
                        C32b[(long)row * ldc32b + (col - 256)] = v;
                        C16[(long)row * ldc16 + (col - 256)] = f2b(v);
                    }
                    continue;
                }
                if (act == 1) v = gelu_f(v);
                if (resid) v += resid[(long)bz * sR + (long)row * ldr + col];
                if (C32) C32[(long)bz * sC32 + (long)row * ldc32 + col] = v;
                if (C16) C16[(long)bz * sC16 + (long)row * ldc16 + col] = f2b(v);
            }
        }
    }
}

// ---------------------------------------------------------------------------
// Flash attention v2: 4 waves x 32 q-rows (q-tile 128), kv-tile 64.
// ---------------------------------------------------------------------------
template <int D>
__global__ __launch_bounds__(256, 2)
void attn_mfma(unsigned short* __restrict__ qkv, int stride, int koff, int voff, float scale)
{
    constexpr int GRL = D / 8;
    constexpr int NITK = (64 * GRL) / 256;
    constexpr int NITV = NITK;
    constexpr int NKS = D / 32;
    constexpr int NF = D / 16;
    constexpr int LV = 72;
    constexpr int LP = 72;
    constexpr int NT = NS / 64;

    __shared__ __align__(16) unsigned short Ks[2][64 * D];
    __shared__ __align__(16) unsigned short Vt[D * LV];
    __shared__ __align__(16) unsigned short Ps[128 * LP];

    int b = blockIdx.z, h = blockIdx.y, qt = blockIdx.x;
    int t = threadIdx.x, w = t >> 6, l = t & 63, l15 = l & 15, g = l >> 4;
    int wq = w * 32;
    long qbase = ((long)b * NS + qt * 128) * stride + h * D;
    long kvbase = (long)b * NS * stride + h * D;

    bf16x8 qreg[2][NKS];
#pragma unroll
    for (int qh = 0; qh < 2; ++qh)
#pragma unroll
        for (int ks = 0; ks < NKS; ++ks)
            qreg[qh][ks] = *(const bf16x8*)&qkv[qbase + (long)(wq + qh * 16 + l15) * stride + g * 8 + ks * 32];

    auto KSTAGE = [&](int c, int kt) {
#pragma unroll
        for (int i = 0; i < NITK; ++i) {
            int gi = t + i * 256;
            int row = gi / GRL, cg = gi % GRL;
            int cgs = cg ^ (row & 7);
            gload16(&qkv[kvbase + (long)(kt * 64 + row) * stride + koff + cgs * 8],
                    &Ks[c][gi * 8]);
        }
    };
    uint4 vp[NITV];
    auto VLOAD = [&](int kt) {
#pragma unroll
        for (int i = 0; i < NITV; ++i) {
            int vgi = t + i * 256;
            int kc = vgi & 63, db = vgi >> 6;
            vp[i] = *(const uint4*)&qkv[kvbase + (long)(kt * 64 + kc) * stride + voff + db * 8];
        }
    };
    auto VWRITE = [&]() {
#pragma unroll
        for (int i = 0; i < NITV; ++i) {
            int vgi = t + i * 256;
            int kc = vgi & 63, db = vgi >> 6;
            uint4 v = vp[i];
            Vt[(db * 8 + 0) * LV + kc] = (unsigned short)(v.x & 0xffff);
            Vt[(db * 8 + 1) * LV + kc] = (unsigned short)(v.x >> 16);
            Vt[(db * 8 + 2) * LV + kc] = (unsigned short)(v.y & 0xffff);
            Vt[(db * 8 + 3) * LV + kc] = (unsigned short)(v.y >> 16);
            Vt[(db * 8 + 4) * LV + kc] = (unsigned short)(v.z & 0xffff);
            Vt[(db * 8 + 5) * LV + kc] = (unsigned short)(v.z >> 16);
            Vt[(db * 8 + 6) * LV + kc] = (unsigned short)(v.w & 0xffff);
            Vt[(db * 8 + 7) * LV + kc] = (unsigned short)(v.w >> 16);
        }
    };

    KSTAGE(0, 0);
    VLOAD(0);
    KSTAGE(1, 1);
    if constexpr (NITK == 4) { VMCNT(4); } else { VMCNT(2); }
    VWRITE();
    LGKMCNT(0);
    __builtin_amdgcn_sched_barrier(0);
    __builtin_amdgcn_s_barrier();

    float m_run[2] = {-INFINITY, -INFINITY};
    float l_run[2] = {0.f, 0.f};
    f32x4 zero4 = {0.f, 0.f, 0.f, 0.f};
    f32x4 oacc[2][NF];
#pragma unroll
    for (int qh = 0; qh < 2; ++qh)
#pragma unroll
        for (int nf = 0; nf < NF; ++nf) oacc[qh][nf] = zero4;

    int xr = (l15 & 7) << 4;
    for (int kt = 0; kt < NT; ++kt) {
        if (kt + 1 < NT) VLOAD(kt + 1);

        const char* ksb = (const char*)&Ks[kt & 1][0];
        f32x4 st[4][2];
#pragma unroll
        for (int f = 0; f < 4; ++f)
#pragma unroll
            for (int qh = 0; qh < 2; ++qh) st[f][qh] = zero4;
#pragma unroll
        for (int ks = 0; ks < NKS; ++ks) {
#pragma unroll
            for (int f = 0; f < 4; ++f) {
                int cb = (g * 16 + ks * 64) ^ xr;
                bf16x8 a = *(const bf16x8*)(ksb + (f * 16 + l15) * (D * 2) + cb);
#pragma unroll
                for (int qh = 0; qh < 2; ++qh)
                    st[f][qh] = __builtin_amdgcn_mfma_f32_16x16x32_bf16(a, qreg[qh][ks], st[f][qh], 0, 0, 0);
            }
        }
#pragma unroll
        for (int qh = 0; qh < 2; ++qh) {
            float pm = -INFINITY;
#pragma unroll
            for (int f = 0; f < 4; ++f) {
                st[f][qh] *= scale;
#pragma unroll
                for (int r = 0; r < 4; ++r) pm = fmaxf(pm, st[f][qh][r]);
            }
            pm = fmaxf(pm, __shfl_xor(pm, 16));
            pm = fmaxf(pm, __shfl_xor(pm, 32));
            float mn = fmaxf(m_run[qh], pm);
            float corr = __expf(m_run[qh] - mn);
            float rs = 0.f;
#pragma unroll
            for (int f = 0; f < 4; ++f) {
                float p0 = __expf(st[f][qh][0] - mn);
                float p1 = __expf(st[f][qh][1] - mn);
                float p2 = __expf(st[f][qh][2] - mn);
                float p3 = __expf(st[f][qh][3] - mn);
                rs += (p0 + p1) + (p2 + p3);
                ushort4 pw;
                pw.x = f2b(p0); pw.y = f2b(p1); pw.z = f2b(p2); pw.w = f2b(p3);
                *(ushort4*)&Ps[(wq + qh * 16 + l15) * LP + f * 16 + g * 4] = pw;
            }
            rs += __shfl_xor(rs, 16);
            rs += __shfl_xor(rs, 32);
            l_run[qh] = l_run[qh] * corr + rs;
            m_run[qh] = mn;
            float corrO[4];
#pragma unroll
            for (int r = 0; r < 4; ++r) corrO[r] = __shfl(corr, g * 4 + r);
#pragma unroll
            for (int nf = 0; nf < NF; ++nf)
#pragma unroll
                for (int r = 0; r < 4; ++r) oacc[qh][nf][r] *= corrO[r];
        }
#pragma unroll
        for (int ks2 = 0; ks2 < 2; ++ks2) {
            bf16x8 vb[NF];
#pragma unroll
            for (int nf = 0; nf < NF; ++nf)
                vb[nf] = *(const bf16x8*)&Vt[(nf * 16 + l15) * LV + ks2 * 32 + g * 8];
#pragma unroll
            for (int qh = 0; qh < 2; ++qh) {
                bf16x8 pa = *(const bf16x8*)&Ps[(wq + qh * 16 + l15) * LP + ks2 * 32 + g * 8];
#pragma unroll
                for (int nf = 0; nf < NF; ++nf)
                    oacc[qh][nf] = __builtin_amdgcn_mfma_f32_16x16x32_bf16(pa, vb[nf], oacc[qh][nf], 0, 0, 0);
            }
        }

        if (kt + 1 < NT) {
            LGKMCNT(0);
            __builtin_amdgcn_sched_barrier(0);
            __builtin_amdgcn_s_barrier();
            if (kt + 2 < NT) {
                KSTAGE(kt & 1, kt + 2);
                if constexpr (NITK == 4) { VMCNT(4); } else { VMCNT(2); }
            } else {
                VMCNT(0);
            }
            VWRITE();
            LGKMCNT(0);
            __builtin_amdgcn_sched_barrier(0);
            __builtin_amdgcn_s_barrier();
        }
    }

#pragma unroll
    for (int qh = 0; qh < 2; ++qh) {
        float lo[4];
#pragma unroll
        for (int r = 0; r < 4; ++r) lo[r] = __shfl(l_run[qh], g * 4 + r);
#pragma unroll
        for (int nf = 0; nf < NF; ++nf)
#pragma unroll
            for (int r = 0; r < 4; ++r) {
                float o = oacc[qh][nf][r] / lo[r];
                qkv[qbase + (long)(wq + qh * 16 + g * 4 + r) * stride + nf * 16 + l15] = f2b(o);
            }
    }
}

// ---------------------------------------------------------------------------
__global__ __launch_bounds__(256)
void maxpart_aff_kernel(const float* __restrict__ aff, float* __restrict__ part)
{
    int sc = blockIdx.x, b = blockIdx.y, t = threadIdx.x;
    float m = -INFINITY;
    for (int s = sc * 32; s < (sc + 1) * 32; ++s)
        m = fmaxf(m, aff[((long)b * NS + s) * NIN + t]);
    part[(b * 32 + sc) * NIN + t] = m;
}

__global__ __launch_bounds__(256)
void rank_input_kernel(const float* __restrict__ part, int* __restrict__ idx_out,
                       float* __restrict__ w_out)
{
    int b = blockIdx.x, t = threadIdx.x;
    __shared__ float lg[256], rv[256];
    float m = part[(b * 32) * NIN + t];
#pragma unroll
    for (int sc = 1; sc < 32; ++sc) m = fmaxf(m, part[(b * 32 + sc) * NIN + t]);
    float l = m * 0.5f;
    lg[t] = l;
    rv[t] = l;
    __syncthreads();
    for (int off = 128; off; off >>= 1) {
        if (t < off) rv[t] = fmaxf(rv[t], rv[t + off]);
        __syncthreads();
    }
    float mx = rv[0];
    __syncthreads();
    float e = expf(l - mx);
    rv[t] = e;
    __syncthreads();
    for (int off = 128; off; off >>= 1) {
        if (t < off) rv[t] += rv[t + off];
        __syncthreads();
    }
    float Zs = rv[0];
    float soft = e / Zs;
    __syncthreads();
    int rank = 0;
    for (int j = 0; j < 256; ++j) {
        float vj = lg[j];
        rank += (vj > l) || (vj == l && j < t);
    }
    rv[t] = (rank < KIN) ? soft : 0.f;
    __syncthreads();
    for (int off = 128; off; off >>= 1) {
        if (t < off) rv[t] += rv[t + off];
        __syncthreads();
    }
    float msum = rv[0];
    if (rank < KIN) {
        idx_out[b * KIN + rank] = t;
        w_out[b * KIN + rank] = soft / (msum + 1e-8f);
    }
}

__global__ __launch_bounds__(512)
void rank_proc_kernel(const float* __restrict__ finals, int* __restrict__ pidx)
{
    int b = blockIdx.x, t = threadIdx.x;
    __shared__ float v[512];
    float xv = finals[b * NPROC + t];
    v[t] = xv;
    __syncthreads();
    int rank = 0;
    for (int j = 0; j < 512; ++j) {
        float vj = v[j];
        rank += (vj > xv) || (vj == xv && j < t);
    }
    if (rank < KPROC) pidx[b * KPROC + rank] = t;
}

__global__ __launch_bounds__(256)
void ln_gather_kernel(const float* __restrict__ a, const float* __restrict__ bsrc,
                      const float* __restrict__ gg, const float* __restrict__ be,
                      const int* __restrict__ idx_in, const float* __restrict__ w_sel,
                      unsigned short* __restrict__ sel_acts)
{
    long row = blockIdx.x;
    int b = blockIdx.x >> 10;
    int t = threadIdx.x;
    float v = a[row * 256 + t] + bsrc[row * 256 + t];
    __shared__ float rv[256];
    __shared__ float lnv[256];
    rv[t] = v;
    __syncthreads();
    for (int off = 128; off; off >>= 1) {
        if (t < off) rv[t] += rv[t + off];
        __syncthreads();
    }
    float mean = rv[0] * (1.f / 256.f);
    __syncthreads();
    float d = v - mean;
    rv[t] = d * d;
    __syncthreads();
    for (int off = 128; off; off >>= 1) {
        if (t < off) rv[t] += rv[t + off];
        __syncthreads();
    }
    float var = rv[0] * (1.f / 256.f);
    lnv[t] = d * rsqrtf(var + 1e-5f) * gg[t] + be[t];
    __syncthreads();
    if (t < KIN) {
        int id = idx_in[b * KIN + t];
        sel_acts[row * KIN + t] = f2b(lnv[id] * w_sel[b * KIN + t]);
    }
}

__global__ void gather_sel_cw_b(const float* __restrict__ comb_w, const int* __restrict__ idx_in,
                                unsigned short* __restrict__ sel_cw)
{
    int gidx = blockIdx.x * 256 + threadIdx.x;
    int b = gidx >> 16;
    int rem = gidx & 65535;
    int pb = rem >> 7, j = rem & 127;
    sel_cw[gidx] = f2b(comb_w[pb * NIN + idx_in[b * KIN + j]]);
}

__global__ void gather_sel_proc_b(const float* __restrict__ proc_acts, const int* __restrict__ pidx,
                                  unsigned short* __restrict__ sel_proc)
{
    int s = blockIdx.x, b = blockIdx.y, j = threadIdx.x;
    long row = (long)b * NS + s;
    sel_proc[row * KPROC + j] = f2b(proc_acts[row * NPROC + pidx[b * KPROC + j]]);
}

__global__ void gather_sel_projT(const float* __restrict__ out_proj_w, const int* __restrict__ pidx,
                                 unsigned short* __restrict__ selT)
{
    int gidx = blockIdx.x * 256 + threadIdx.x;
    int b = gidx >> 15;
    int rem = gidx & 32767;
    int d = rem >> 5;
    int kp0 = (rem & 31) * 8;
    unsigned int u[4];
#pragma unroll
    for (int i = 0; i < 4; ++i) {
        unsigned short e0 = f2b(out_proj_w[(long)pidx[b * KPROC + kp0 + 2 * i] * ND + d]);
        unsigned short e1 = f2b(out_proj_w[(long)pidx[b * KPROC + kp0 + 2 * i + 1] * ND + d]);
        u[i] = (unsigned int)e0 | ((unsigned int)e1 << 16);
    }
    uint4 o; o.x = u[0]; o.y = u[1]; o.z = u[2]; o.w = u[3];
    *(uint4*)&selT[((long)b * ND + d) * KPROC + kp0] = o;
}

__global__ __launch_bounds__(512)
void maxpart_kernel(const float* __restrict__ proc, float* __restrict__ part)
{
    int sc = blockIdx.x, b = blockIdx.y, t = threadIdx.x;
    float m = -INFINITY;
    for (int s = sc * 32; s < (sc + 1) * 32; ++s)
        m = fmaxf(m, proc[((long)b * NS + s) * NPROC + t]);
    part[(b * 32 + sc) * NPROC + t] = m;
}

__global__ __launch_bounds__(512)
void relevance_kernel(const float* __restrict__ part, const int* __restrict__ idx_in,
                      const float* __restrict__ a1w, const float* __restrict__ a1b,
                      const float* __restrict__ a2w, const float* __restrict__ a2b,
                      float* __restrict__ finals)
{
    int b = blockIdx.x, t = threadIdx.x;
    float m = part[(b * 32) * NPROC + t];
#pragma unroll
    for (int sc = 1; sc < 32; ++sc) m = fmaxf(m, part[(b * 32 + sc) * NPROC + t]);
    __shared__ float rel1[512];
    __shared__ int sidx[KIN];
    if (t < KIN) sidx[t] = idx_in[b * KIN + t];
    __syncthreads();
    float r1 = a1b[t];
    const float* a1row = a1w + (long)t * NIN;
    for (int j = 0; j < KIN; ++j) r1 += a1row[sidx[j]];
    rel1[t] = gelu_f(r1);
    __syncthreads();
    float r = a2b[t];
    const float* a2row = a2w + (long)t * 512;
    for (int hh = 0; hh < 512; ++hh) r += rel1[hh] * a2row[hh];
    float sig = 1.f / (1.f + expf(-r));
    finals[b * NPROC + t] = m * sig;
}

// ---------------------------------------------------------------------------
extern "C" void kernel_launch(void* const* d_in, const int* in_sizes, int n_in,
                              void* d_out, int out_size, void* d_ws, size_t ws_size,
                              hipStream_t stream)
{
    const float* x       = (const float*)d_in[0];
    const float* r_in_w  = (const float*)d_in[1];
    const float* r_in_b  = (const float*)d_in[2];
    const float* r_out_w = (const float*)d_in[3];
    const float* r_out_b = (const float*)d_in[4];
    const float* aff_w   = (const float*)d_in[5];
    const float* aff_b   = (const float*)d_in[6];
    const float* patterns= (const float*)d_in[7];
    const float* i_in_w  = (const float*)d_in[8];
    const float* i_in_b  = (const float*)d_in[9];
    const float* i_out_w = (const float*)d_in[10];
    const float* i_out_b = (const float*)d_in[11];
    const float* ln_g    = (const float*)d_in[12];
    const float* ln_b    = (const float*)d_in[13];
    const float* comb_w  = (const float*)d_in[14];
    const float* out_proj_w = (const float*)d_in[15];
    const float* a1w     = (const float*)d_in[16];
    const float* a1b     = (const float*)d_in[17];
    const float* a2w     = (const float*)d_in[18];
    const float* a2b     = (const float*)d_in[19];
    float* out = (float*)d_out;

    char* ws = (char*)d_ws;
    unsigned short* qkv1b    = (unsigned short*)(ws + 0);
    unsigned short* contextb = (unsigned short*)(ws + 50331648);
    unsigned short* xb       = (unsigned short*)(ws + 67108864);
    unsigned short* w_rin_b  = (unsigned short*)(ws + 83886080);
    unsigned short* w_rout_b = (unsigned short*)(ws + 90177536);
    unsigned short* w_aff_b  = (unsigned short*)(ws + 92274688);
    unsigned short* patt_b   = (unsigned short*)(ws + 92798976);
    unsigned short* w_iin_b  = (unsigned short*)(ws + 93323264);
    unsigned short* w_iout_b = (unsigned short*)(ws + 93716480);
    float* w_sel   = (float*)(ws + 93855744);
    int*   idx_in  = (int*)(ws + 93859840);
    float* finals  = (float*)(ws + 93863936);
    int*   pidx    = (int*)(ws + 93880320);
    float* affin   = (float*)(ws + 94019584);
    float* acts0   = (float*)(ws + 102408192);
    unsigned short* acts0b = (unsigned short*)(ws + 110796800);
    unsigned short* qkv2b  = (unsigned short*)(ws + 114991104);
    float* attn2proj = (float*)(ws + 0);
    float* proc_acts = (float*)(ws + 16777216);
    unsigned short* sel_actsb = (unsigned short*)(ws + 33554432);
    unsigned short* sel_cwb   = (unsigned short*)(ws + 35651584);
    unsigned short* sel_procb = (unsigned short*)(ws + 36700160);
    unsigned short* sel_projT = (unsigned short*)(ws + 40894464);
    float* biascat  = (float*)(ws + 45088768);
    float* part_aff = (float*)(ws + 45091840);
    float* maxpart  = (float*)(ws + 45353984);

    // 0. all conversions + biascat init in one launch
    cvt_all_kernel<<<2048, 256, 0, stream>>>(
        x, r_in_w, r_out_w, aff_w, patterns, i_in_w, i_out_w, aff_b,
        xb, w_rin_b, w_rout_b, w_aff_b, patt_b, w_iin_b, w_iout_b, biascat);

    // 1. qkv1 = x @ r_in_w^T + b (128x128 BK=32 pipeline, 1536 blocks, 3/CU)
    gemm128s<<<1536, 256, 0, stream>>>(xb, ND, w_rin_b, ND, r_in_b, qkv1b, 3 * ND, ND, 24);
    // 2. MHA-1
    attn_mfma<128><<<dim3(8, 8, 8), 256, 0, stream>>>(qkv1b, 3 * ND, ND, 2 * ND, 0.088388347648318447f);
    // 3. context (512 blocks)
    gemm128s<<<512, 256, 0, stream>>>(qkv1b, 3 * ND, w_rout_b, ND, r_out_b, contextb, ND, ND, 8);
    // 4. fused affinity+patterns (split epilogue)
    gemm_bf16<<<dim3(4, 64, 1), 256, 0, stream>>>(
        contextb, 0, ND, w_aff_b, 0, ND, biascat, nullptr, 0, 0,
        affin, 0, NIN, acts0b, 0, NIN, acts0, NIN, NB * NS, 2 * NIN, ND, 2);
    // 5. routing
    maxpart_aff_kernel<<<dim3(32, NB), 256, 0, stream>>>(affin, part_aff);
    rank_input_kernel<<<NB, 256, 0, stream>>>(part_aff, idx_in, w_sel);
    // 6. qkv2 (384 blocks)
    gemm128s<<<384, 256, 0, stream>>>(acts0b, NIN, w_iin_b, NIN, i_in_b, qkv2b, 3 * NIN, NIN, 6);
    // 7. MHA-2
    attn_mfma<64><<<dim3(8, 4, 8), 256, 0, stream>>>(qkv2b, 3 * NIN, NIN, 2 * NIN, 0.125f);
    // 8. attn2 out-proj
    gemm_bf16<<<dim3(2, 64, 1), 256, 0, stream>>>(
        qkv2b, 0, 3 * NIN, w_iout_b, 0, NIN, i_out_b, nullptr, 0, 0,
        attn2proj, 0, NIN, nullptr, 0, 0, nullptr, 0, NB * NS, NIN, NIN, 0);
    // 9. LN + routed gather (fused)
    ln_gather_kernel<<<NB * NS, 256, 0, stream>>>(acts0, attn2proj, ln_g, ln_b,
                                                  idx_in, w_sel, sel_actsb);
    gather_sel_cw_b<<<2048, 256, 0, stream>>>(comb_w, idx_in, sel_cwb);
    // 10. proc_acts
    gemm_bf16<<<dim3(4, 8, NB), 256, 0, stream>>>(
        sel_actsb, (long)NS * KIN, KIN, sel_cwb, (long)NPROC * KIN, KIN,
        nullptr, nullptr, 0, 0,
        proc_acts, (long)NS * NPROC, NPROC, nullptr, 0, 0, nullptr, 0, NS, NPROC, KIN, 1);
    // 11. final scores + top-256
    maxpart_kernel<<<dim3(32, NB), 512, 0, stream>>>(proc_acts, maxpart);
    relevance_kernel<<<NB, 512, 0, stream>>>(maxpart, idx_in, a1w, a1b, a2w, a2b, finals);
    rank_proc_kernel<<<NB, 512, 0, stream>>>(finals, pidx);
    // 12. output gathers + GEMM + residual
    gather_sel_proc_b<<<dim3(NS, NB), KPROC, 0, stream>>>(proc_acts, pidx, sel_procb);
    gather_sel_projT<<<1024, 256, 0, stream>>>(out_proj_w, pidx, sel_projT);
    gemm_bf16<<<dim3(8, 8, NB), 256, 0, stream>>>(
        sel_procb, (long)NS * KPROC, KPROC, sel_projT, (long)ND * KPROC, KPROC,
        nullptr, x, (long)NS * ND, ND,
        out, (long)NS * ND, ND, nullptr, 0, 0, nullptr, 0, NS, ND, KPROC, 0);
    (void)in_sizes; (void)n_in; (void)out_size; (void)ws_size;
}

// Round 15
// 476.723 us; speedup vs baseline: 11.6639x; 1.0065x over previous
//
#include <hip/hip_runtime.h>
#include <hip/hip_bf16.h>
#include <math.h>

constexpr int NB = 8, NS = 1024, ND = 1024, NIN = 256, NPROC = 512, KIN = 128, KPROC = 256;

typedef __attribute__((ext_vector_type(8))) short bf16x8;
typedef __attribute__((ext_vector_type(4))) float f32x4;

#define VMCNT(n) asm volatile("s_waitcnt vmcnt(" #n ")" ::: "memory")
#define LGKMCNT(n) asm volatile("s_waitcnt lgkmcnt(" #n ")" ::: "memory")

__device__ inline float gelu_f(float x) {
    return 0.5f * x * (1.0f + erff(x * 0.7071067811865476f));
}
__device__ inline unsigned short f2b(float f) {
    __hip_bfloat16 h = __float2bfloat16(f);
    return *reinterpret_cast<unsigned short*>(&h);
}
__device__ inline void gload16(const void* g, void* l) {
    __builtin_amdgcn_global_load_lds(
        (const __attribute__((address_space(1))) void*)g,
        (__attribute__((address_space(3))) void*)l, 16, 0, 0);
}

// ---------------------------------------------------------------------------
// Fused f32->bf16 conversions + biascat init.
// ---------------------------------------------------------------------------
__global__ __launch_bounds__(256)
void cvt_all_kernel(const float* __restrict__ x, const float* __restrict__ rin,
                    const float* __restrict__ rout, const float* __restrict__ affw,
                    const float* __restrict__ patt, const float* __restrict__ iin,
                    const float* __restrict__ iout, const float* __restrict__ aff_b,
                    unsigned short* __restrict__ xb, unsigned short* __restrict__ rinb,
                    unsigned short* __restrict__ routb, unsigned short* __restrict__ affbw,
                    unsigned short* __restrict__ pattb, unsigned short* __restrict__ iinb,
                    unsigned short* __restrict__ ioutb, float* __restrict__ biascat)
{
    if (blockIdx.x == 0) {
        int t = threadIdx.x;
        biascat[t] = aff_b[t];
        biascat[256 + t] = 0.f;
    }
    long gi = (long)blockIdx.x * 256 + threadIdx.x;
    long stride = (long)gridDim.x * 256;
    for (; gi < 3342336; gi += stride) {
        const float4* s; ushort4* d; long off;
        if (gi < 2097152)      { s = (const float4*)x;    d = (ushort4*)xb;    off = gi; }
        else if (gi < 2883584) { s = (const float4*)rin;  d = (ushort4*)rinb;  off = gi - 2097152; }
        else if (gi < 3145728) { s = (const float4*)rout; d = (ushort4*)routb; off = gi - 2883584; }
        else if (gi < 3211264) { s = (const float4*)affw; d = (ushort4*)affbw; off = gi - 3145728; }
        else if (gi < 3276800) { s = (const float4*)patt; d = (ushort4*)pattb; off = gi - 3211264; }
        else if (gi < 3325952) { s = (const float4*)iin;  d = (ushort4*)iinb;  off = gi - 3276800; }
        else                   { s = (const float4*)iout; d = (ushort4*)ioutb; off = gi - 3325952; }
        float4 v = s[off];
        ushort4 o;
        o.x = f2b(v.x); o.y = f2b(v.y); o.z = f2b(v.z); o.w = f2b(v.w);
        d[off] = o;
    }
}

// ---------------------------------------------------------------------------
// 128x128 bf16 MFMA GEMM, BK=32 double-buffer, 4 waves, counted-vmcnt
// 2-barrier pipeline + 2-bit XOR swizzle (2-way banks = free) + XCD grid
// swizzle. 3 blocks/CU, 32KB LDS. C16 = A @ B^T + bias.
// Grid 1D (M/128)*(N/128), %8==0. K%32==0, K>=96.
// ---------------------------------------------------------------------------
__global__ __launch_bounds__(256)
void gemm128s(const unsigned short* __restrict__ A, int lda,
              const unsigned short* __restrict__ B, int ldb,
              const float* __restrict__ bias,
              unsigned short* __restrict__ C16, int ldc,
              int K, int nbx)
{
    __shared__ __align__(16) unsigned short Ab[2][128 * 32];
    __shared__ __align__(16) unsigned short Bb[2][128 * 32];
    int o = blockIdx.x;
    int cpx = gridDim.x >> 3;
    int swz = (o & 7) * cpx + (o >> 3);
    int by = swz / nbx, bx = swz - by * nbx;
    int row0 = by * 128, col0 = bx * 128;

    int t = threadIdx.x;
    int w = t >> 6, l = t & 63, l15 = l & 15, g = l >> 4;
    int wr = w >> 1, wc = w & 1;
    int NT = K >> 5;

    f32x4 acc[4][4];
#pragma unroll
    for (int i = 0; i < 4; ++i)
#pragma unroll
        for (int j = 0; j < 4; ++j) acc[i][j] = (f32x4){0.f, 0.f, 0.f, 0.f};

    // staging: granule gi = t + i*256 in [0,512): row = gi>>2, slot cg = gi&3,
    // source granule = cg ^ ((row>>1)&3)  (matches read-side 2-bit XOR).
    auto STAGE = [&](int c, int kt) {
        int k0 = kt * 32;
#pragma unroll
        for (int i = 0; i < 2; ++i) {
            int gi = t + i * 256;
            int row = gi >> 2, cg = gi & 3;
            int cgs = cg ^ ((row >> 1) & 3);
            gload16(&A[(long)(row0 + row) * lda + k0 + cgs * 8], &Ab[c][gi * 8]);
        }
#pragma unroll
        for (int i = 0; i < 2; ++i) {
            int gi = t + i * 256;
            int row = gi >> 2, cg = gi & 3;
            int cgs = cg ^ ((row >> 1) & 3);
            gload16(&B[(long)(col0 + row) * ldb + k0 + cgs * 8], &Bb[c][gi * 8]);
        }
    };

    STAGE(0, 0);
    STAGE(1, 1);

    int cbr = (g ^ ((l15 >> 1) & 3)) * 16;  // read-side byte col (2-bit XOR swizzle)

    for (int T = 0; T < NT; ++T) {
        int c = T & 1;
        if (T + 1 < NT) { VMCNT(4); } else { VMCNT(0); }
        __builtin_amdgcn_s_barrier();
        asm volatile("" ::: "memory");

        const char* Ab_ = (const char*)&Ab[c][0];
        const char* Bb_ = (const char*)&Bb[c][0];
        bf16x8 af[4], bfr[4];
#pragma unroll
        for (int mi = 0; mi < 4; ++mi)
            af[mi] = *(const bf16x8*)(Ab_ + (wr * 64 + mi * 16 + l15) * 64 + cbr);
#pragma unroll
        for (int ni = 0; ni < 4; ++ni)
            bfr[ni] = *(const bf16x8*)(Bb_ + (wc * 64 + ni * 16 + l15) * 64 + cbr);

        LGKMCNT(0);
        __builtin_amdgcn_sched_barrier(0);
        __builtin_amdgcn_s_barrier();
        asm volatile("" ::: "memory");
        if (T + 2 < NT) STAGE(c, T + 2);

        __builtin_amdgcn_s_setprio(1);
#pragma unroll
        for (int mi = 0; mi < 4; ++mi)
#pragma unroll
            for (int ni = 0; ni < 4; ++ni)
                acc[mi][ni] = __builtin_amdgcn_mfma_f32_16x16x32_bf16(
                    af[mi], bfr[ni], acc[mi][ni], 0, 0, 0);
        __builtin_amdgcn_s_setprio(0);
    }

    // epilogue: paired-lane dword bf16 stores
#pragma unroll
    for (int mi = 0; mi < 4; ++mi) {
#pragma unroll
        for (int ni = 0; ni < 4; ++ni) {
            int col = col0 + wc * 64 + ni * 16 + l15;
            float bv = bias ? bias[col] : 0.f;
#pragma unroll
            for (int r = 0; r < 4; ++r) {
                int row = row0 + wr * 64 + mi * 16 + g * 4 + r;
                float v = acc[mi][ni][r] + bv;
                float vp = __shfl_xor(v, 1);
                if (!(l15 & 1)) {
                    unsigned int u = (unsigned int)f2b(v) | ((unsigned int)f2b(vp) << 16);
                    *(unsigned int*)&C16[(long)row * ldc + col] = u;
                }
            }
        }
    }
}

// ---------------------------------------------------------------------------
// bf16 MFMA GEMM, m97 structure (128x128, BK=64, 4 waves, gload_lds).
// Used for epilogue-fused call sites (split aff+patt, attn2proj, proc, out).
// ---------------------------------------------------------------------------
__global__ __launch_bounds__(256)
void gemm_bf16(const unsigned short* __restrict__ A, long sA, int lda,
               const unsigned short* __restrict__ B, long sB, int ldb,
               const float* __restrict__ bias,
               const float* __restrict__ resid, long sR, int ldr,
               float* __restrict__ C32, long sC32, int ldc32,
               unsigned short* __restrict__ C16, long sC16, int ldc16,
               float* __restrict__ C32b, int ldc32b,
               int M, int N, int K, int act)
{
    __shared__ __align__(16) unsigned short As[128 * 64];
    __shared__ __align__(16) unsigned short Bs[128 * 64];
    int bz = blockIdx.z;
    const unsigned short* Abp = A + (long)bz * sA;
    const unsigned short* Bbp = B + (long)bz * sB;
    int row0 = blockIdx.y * 128, col0 = blockIdx.x * 128;
    int t = threadIdx.x;
    int w = t >> 6, l = t & 63, l15 = l & 15, g = l >> 4;
    int wr = w >> 1, wc = w & 1;
    int srow = l >> 3;
    int scol = (l & 7) * 8;
    f32x4 zero4 = {0.f, 0.f, 0.f, 0.f};
    f32x4 acc[4][4];
#pragma unroll
    for (int i = 0; i < 4; ++i)
#pragma unroll
        for (int j = 0; j < 4; ++j) acc[i][j] = zero4;

    for (int k0 = 0; k0 < K; k0 += 64) {
        __syncthreads();
#pragma unroll
        for (int c = 0; c < 4; ++c) {
            int r = w * 32 + c * 8;
            gload16(&Abp[(long)(row0 + r + srow) * lda + k0 + scol], &As[r * 64]);
            gload16(&Bbp[(long)(col0 + r + srow) * ldb + k0 + scol], &Bs[r * 64]);
        }
        __syncthreads();
        bf16x8 af[4][2], bfr[4][2];
#pragma unroll
        for (int mi = 0; mi < 4; ++mi)
#pragma unroll
            for (int ks = 0; ks < 2; ++ks) {
                af[mi][ks] = *(const bf16x8*)&As[(wr * 64 + mi * 16 + l15) * 64 + g * 8 + ks * 32];
                bfr[mi][ks] = *(const bf16x8*)&Bs[(wc * 64 + mi * 16 + l15) * 64 + g * 8 + ks * 32];
            }
#pragma unroll
        for (int ks = 0; ks < 2; ++ks)
#pragma unroll
            for (int mi = 0; mi < 4; ++mi)
#pragma unroll
                for (int ni = 0; ni < 4; ++ni)
                    acc[mi][ni] = __builtin_amdgcn_mfma_f32_16x16x32_bf16(af[mi][ks], bfr[ni][ks], acc[mi][ni], 0, 0, 0);
    }

#pragma unroll
    for (int mi = 0; mi < 4; ++mi) {
#pragma unroll
        for (int ni = 0; ni < 4; ++ni) {
#pragma unroll
            for (int r = 0; r < 4; ++r) {
                int row = row0 + wr * 64 + mi * 16 + g * 4 + r;
                int col = col0 + wc * 64 + ni * 16 + l15;
                float v = acc[mi][ni][r];
                if (bias) v += bias[col];
                if (act == 2) {
                    if (col < 256) {
                        C32[(long)row * ldc32 + col] = v;
                    } else {
                        v = gelu_f(v);
                        C32b[(long)row * ldc32b + (col - 256)] = v;
                        C16[(long)row * ldc16 + (col - 256)] = f2b(v);
                    }
                    continue;
                }
                if (act == 1) v = gelu_f(v);
                if (resid) v += resid[(long)bz * sR + (long)row * ldr + col];
                if (C32) C32[(long)bz * sC32 + (long)row * ldc32 + col] = v;
                if (C16) C16[(long)bz * sC16 + (long)row * ldc16 + col] = f2b(v);
            }
        }
    }
}

// ---------------------------------------------------------------------------
// Flash attention v2: 4 waves x 32 q-rows (q-tile 128), kv-tile 64.
// ---------------------------------------------------------------------------
template <int D>
__global__ __launch_bounds__(256, 2)
void attn_mfma(unsigned short* __restrict__ qkv, int stride, int koff, int voff, float scale)
{
    constexpr int GRL = D / 8;
    constexpr int NITK = (64 * GRL) / 256;
    constexpr int NITV = NITK;
    constexpr int NKS = D / 32;
    constexpr int NF = D / 16;
    constexpr int LV = 72;
    constexpr int LP = 72;
    constexpr int NT = NS / 64;

    __shared__ __align__(16) unsigned short Ks[2][64 * D];
    __shared__ __align__(16) unsigned short Vt[D * LV];
    __shared__ __align__(16) unsigned short Ps[128 * LP];

    int b = blockIdx.z, h = blockIdx.y, qt = blockIdx.x;
    int t = threadIdx.x, w = t >> 6, l = t & 63, l15 = l & 15, g = l >> 4;
    int wq = w * 32;
    long qbase = ((long)b * NS + qt * 128) * stride + h * D;
    long kvbase = (long)b * NS * stride + h * D;

    bf16x8 qreg[2][NKS];
#pragma unroll
    for (int qh = 0; qh < 2; ++qh)
#pragma unroll
        for (int ks = 0; ks < NKS; ++ks)
            qreg[qh][ks] = *(const bf16x8*)&qkv[qbase + (long)(wq + qh * 16 + l15) * stride + g * 8 + ks * 32];

    auto KSTAGE = [&](int c, int kt) {
#pragma unroll
        for (int i = 0; i < NITK; ++i) {
            int gi = t + i * 256;
            int row = gi / GRL, cg = gi % GRL;
            int cgs = cg ^ (row & 7);
            gload16(&qkv[kvbase + (long)(kt * 64 + row) * stride + koff + cgs * 8],
                    &Ks[c][gi * 8]);
        }
    };
    uint4 vp[NITV];
    auto VLOAD = [&](int kt) {
#pragma unroll
        for (int i = 0; i < NITV; ++i) {
            int vgi = t + i * 256;
            int kc = vgi & 63, db = vgi >> 6;
            vp[i] = *(const uint4*)&qkv[kvbase + (long)(kt * 64 + kc) * stride + voff + db * 8];
        }
    };
    auto VWRITE = [&]() {
#pragma unroll
        for (int i = 0; i < NITV; ++i) {
            int vgi = t + i * 256;
            int kc = vgi & 63, db = vgi >> 6;
            uint4 v = vp[i];
            Vt[(db * 8 + 0) * LV + kc] = (unsigned short)(v.x & 0xffff);
            Vt[(db * 8 + 1) * LV + kc] = (unsigned short)(v.x >> 16);
            Vt[(db * 8 + 2) * LV + kc] = (unsigned short)(v.y & 0xffff);
            Vt[(db * 8 + 3) * LV + kc] = (unsigned short)(v.y >> 16);
            Vt[(db * 8 + 4) * LV + kc] = (unsigned short)(v.z & 0xffff);
            Vt[(db * 8 + 5) * LV + kc] = (unsigned short)(v.z >> 16);
            Vt[(db * 8 + 6) * LV + kc] = (unsigned short)(v.w & 0xffff);
            Vt[(db * 8 + 7) * LV + kc] = (unsigned short)(v.w >> 16);
        }
    };

    KSTAGE(0, 0);
    VLOAD(0);
    KSTAGE(1, 1);
    if constexpr (NITK == 4) { VMCNT(4); } else { VMCNT(2); }
    VWRITE();
    LGKMCNT(0);
    __builtin_amdgcn_sched_barrier(0);
    __builtin_amdgcn_s_barrier();

    float m_run[2] = {-INFINITY, -INFINITY};
    float l_run[2] = {0.f, 0.f};
    f32x4 zero4 = {0.f, 0.f, 0.f, 0.f};
    f32x4 oacc[2][NF];
#pragma unroll
    for (int qh = 0; qh < 2; ++qh)
#pragma unroll
        for (int nf = 0; nf < NF; ++nf) oacc[qh][nf] = zero4;

    int xr = (l15 & 7) << 4;
    for (int kt = 0; kt < NT; ++kt) {
        if (kt + 1 < NT) VLOAD(kt + 1);

        const char* ksb = (const char*)&Ks[kt & 1][0];
        f32x4 st[4][2];
#pragma unroll
        for (int f = 0; f < 4; ++f)
#pragma unroll
            for (int qh = 0; qh < 2; ++qh) st[f][qh] = zero4;
#pragma unroll
        for (int ks = 0; ks < NKS; ++ks) {
#pragma unroll
            for (int f = 0; f < 4; ++f) {
                int cb = (g * 16 + ks * 64) ^ xr;
                bf16x8 a = *(const bf16x8*)(ksb + (f * 16 + l15) * (D * 2) + cb);
#pragma unroll
                for (int qh = 0; qh < 2; ++qh)
                    st[f][qh] = __builtin_amdgcn_mfma_f32_16x16x32_bf16(a, qreg[qh][ks], st[f][qh], 0, 0, 0);
            }
        }
#pragma unroll
        for (int qh = 0; qh < 2; ++qh) {
            float pm = -INFINITY;
#pragma unroll
            for (int f = 0; f < 4; ++f) {
                st[f][qh] *= scale;
#pragma unroll
                for (int r = 0; r < 4; ++r) pm = fmaxf(pm, st[f][qh][r]);
            }
            pm = fmaxf(pm, __shfl_xor(pm, 16));
            pm = fmaxf(pm, __shfl_xor(pm, 32));
            float mn = fmaxf(m_run[qh], pm);
            float corr = __expf(m_run[qh] - mn);
            float rs = 0.f;
#pragma unroll
            for (int f = 0; f < 4; ++f) {
                float p0 = __expf(st[f][qh][0] - mn);
                float p1 = __expf(st[f][qh][1] - mn);
                float p2 = __expf(st[f][qh][2] - mn);
                float p3 = __expf(st[f][qh][3] - mn);
                rs += (p0 + p1) + (p2 + p3);
                ushort4 pw;
                pw.x = f2b(p0); pw.y = f2b(p1); pw.z = f2b(p2); pw.w = f2b(p3);
                *(ushort4*)&Ps[(wq + qh * 16 + l15) * LP + f * 16 + g * 4] = pw;
            }
            rs += __shfl_xor(rs, 16);
            rs += __shfl_xor(rs, 32);
            l_run[qh] = l_run[qh] * corr + rs;
            m_run[qh] = mn;
            float corrO[4];
#pragma unroll
            for (int r = 0; r < 4; ++r) corrO[r] = __shfl(corr, g * 4 + r);
#pragma unroll
            for (int nf = 0; nf < NF; ++nf)
#pragma unroll
                for (int r = 0; r < 4; ++r) oacc[qh][nf][r] *= corrO[r];
        }
#pragma unroll
        for (int ks2 = 0; ks2 < 2; ++ks2) {
            bf16x8 vb[NF];
#pragma unroll
            for (int nf = 0; nf < NF; ++nf)
                vb[nf] = *(const bf16x8*)&Vt[(nf * 16 + l15) * LV + ks2 * 32 + g * 8];
#pragma unroll
            for (int qh = 0; qh < 2; ++qh) {
                bf16x8 pa = *(const bf16x8*)&Ps[(wq + qh * 16 + l15) * LP + ks2 * 32 + g * 8];
#pragma unroll
                for (int nf = 0; nf < NF; ++nf)
                    oacc[qh][nf] = __builtin_amdgcn_mfma_f32_16x16x32_bf16(pa, vb[nf], oacc[qh][nf], 0, 0, 0);
            }
        }

        if (kt + 1 < NT) {
            LGKMCNT(0);
            __builtin_amdgcn_sched_barrier(0);
            __builtin_amdgcn_s_barrier();
            if (kt + 2 < NT) {
                KSTAGE(kt & 1, kt + 2);
                if constexpr (NITK == 4) { VMCNT(4); } else { VMCNT(2); }
            } else {
                VMCNT(0);
            }
            VWRITE();
            LGKMCNT(0);
            __builtin_amdgcn_sched_barrier(0);
            __builtin_amdgcn_s_barrier();
        }
    }

#pragma unroll
    for (int qh = 0; qh < 2; ++qh) {
        float lo[4];
#pragma unroll
        for (int r = 0; r < 4; ++r) lo[r] = __shfl(l_run[qh], g * 4 + r);
#pragma unroll
        for (int nf = 0; nf < NF; ++nf)
#pragma unroll
            for (int r = 0; r < 4; ++r) {
                float o = oacc[qh][nf][r] / lo[r];
                qkv[qbase + (long)(wq + qh * 16 + g * 4 + r) * stride + nf * 16 + l15] = f2b(o);
            }
    }
}

// ---------------------------------------------------------------------------
__global__ __launch_bounds__(256)
void maxpart_aff_kernel(const float* __restrict__ aff, float* __restrict__ part)
{
    int sc = blockIdx.x, b = blockIdx.y, t = threadIdx.x;
    float m = -INFINITY;
    for (int s = sc * 32; s < (sc + 1) * 32; ++s)
        m = fmaxf(m, aff[((long)b * NS + s) * NIN + t]);
    part[(b * 32 + sc) * NIN + t] = m;
}

__global__ __launch_bounds__(256)
void rank_input_kernel(const float* __restrict__ part, int* __restrict__ idx_out,
                       float* __restrict__ w_out)
{
    int b = blockIdx.x, t = threadIdx.x;
    __shared__ float lg[256], rv[256];
    float m = part[(b * 32) * NIN + t];
#pragma unroll
    for (int sc = 1; sc < 32; ++sc) m = fmaxf(m, part[(b * 32 + sc) * NIN + t]);
    float l = m * 0.5f;
    lg[t] = l;
    rv[t] = l;
    __syncthreads();
    for (int off = 128; off; off >>= 1) {
        if (t < off) rv[t] = fmaxf(rv[t], rv[t + off]);
        __syncthreads();
    }
    float mx = rv[0];
    __syncthreads();
    float e = expf(l - mx);
    rv[t] = e;
    __syncthreads();
    for (int off = 128; off; off >>= 1) {
        if (t < off) rv[t] += rv[t + off];
        __syncthreads();
    }
    float Zs = rv[0];
    float soft = e / Zs;
    __syncthreads();
    int rank = 0;
    for (int j = 0; j < 256; ++j) {
        float vj = lg[j];
        rank += (vj > l) || (vj == l && j < t);
    }
    rv[t] = (rank < KIN) ? soft : 0.f;
    __syncthreads();
    for (int off = 128; off; off >>= 1) {
        if (t < off) rv[t] += rv[t + off];
        __syncthreads();
    }
    float msum = rv[0];
    if (rank < KIN) {
        idx_out[b * KIN + rank] = t;
        w_out[b * KIN + rank] = soft / (msum + 1e-8f);
    }
}

__global__ __launch_bounds__(512)
void rank_proc_kernel(const float* __restrict__ finals, int* __restrict__ pidx)
{
    int b = blockIdx.x, t = threadIdx.x;
    __shared__ float v[512];
    float xv = finals[b * NPROC + t];
    v[t] = xv;
    __syncthreads();
    int rank = 0;
    for (int j = 0; j < 512; ++j) {
        float vj = v[j];
        rank += (vj > xv) || (vj == xv && j < t);
    }
    if (rank < KPROC) pidx[b * KPROC + rank] = t;
}

__global__ __launch_bounds__(256)
void ln_gather_kernel(const float* __restrict__ a, const float* __restrict__ bsrc,
                      const float* __restrict__ gg, const float* __restrict__ be,
                      const int* __restrict__ idx_in, const float* __restrict__ w_sel,
                      unsigned short* __restrict__ sel_acts)
{
    long row = blockIdx.x;
    int b = blockIdx.x >> 10;
    int t = threadIdx.x;
    float v = a[row * 256 + t] + bsrc[row * 256 + t];
    __shared__ float rv[256];
    __shared__ float lnv[256];
    rv[t] = v;
    __syncthreads();
    for (int off = 128; off; off >>= 1) {
        if (t < off) rv[t] += rv[t + off];
        __syncthreads();
    }
    float mean = rv[0] * (1.f / 256.f);
    __syncthreads();
    float d = v - mean;
    rv[t] = d * d;
    __syncthreads();
    for (int off = 128; off; off >>= 1) {
        if (t < off) rv[t] += rv[t + off];
        __syncthreads();
    }
    float var = rv[0] * (1.f / 256.f);
    lnv[t] = d * rsqrtf(var + 1e-5f) * gg[t] + be[t];
    __syncthreads();
    if (t < KIN) {
        int id = idx_in[b * KIN + t];
        sel_acts[row * KIN + t] = f2b(lnv[id] * w_sel[b * KIN + t]);
    }
}

__global__ void gather_sel_cw_b(const float* __restrict__ comb_w, const int* __restrict__ idx_in,
                                unsigned short* __restrict__ sel_cw)
{
    int gidx = blockIdx.x * 256 + threadIdx.x;
    int b = gidx >> 16;
    int rem = gidx & 65535;
    int pb = rem >> 7, j = rem & 127;
    sel_cw[gidx] = f2b(comb_w[pb * NIN + idx_in[b * KIN + j]]);
}

__global__ void gather_sel_proc_b(const float* __restrict__ proc_acts, const int* __restrict__ pidx,
                                  unsigned short* __restrict__ sel_proc)
{
    int s = blockIdx.x, b = blockIdx.y, j = threadIdx.x;
    long row = (long)b * NS + s;
    sel_proc[row * KPROC + j] = f2b(proc_acts[row * NPROC + pidx[b * KPROC + j]]);
}

__global__ void gather_sel_projT(const float* __restrict__ out_proj_w, const int* __restrict__ pidx,
                                 unsigned short* __restrict__ selT)
{
    int gidx = blockIdx.x * 256 + threadIdx.x;
    int b = gidx >> 15;
    int rem = gidx & 32767;
    int d = rem >> 5;
    int kp0 = (rem & 31) * 8;
    unsigned int u[4];
#pragma unroll
    for (int i = 0; i < 4; ++i) {
        unsigned short e0 = f2b(out_proj_w[(long)pidx[b * KPROC + kp0 + 2 * i] * ND + d]);
        unsigned short e1 = f2b(out_proj_w[(long)pidx[b * KPROC + kp0 + 2 * i + 1] * ND + d]);
        u[i] = (unsigned int)e0 | ((unsigned int)e1 << 16);
    }
    uint4 o; o.x = u[0]; o.y = u[1]; o.z = u[2]; o.w = u[3];
    *(uint4*)&selT[((long)b * ND + d) * KPROC + kp0] = o;
}

__global__ __launch_bounds__(512)
void maxpart_kernel(const float* __restrict__ proc, float* __restrict__ part)
{
    int sc = blockIdx.x, b = blockIdx.y, t = threadIdx.x;
    float m = -INFINITY;
    for (int s = sc * 32; s < (sc + 1) * 32; ++s)
        m = fmaxf(m, proc[((long)b * NS + s) * NPROC + t]);
    part[(b * 32 + sc) * NPROC + t] = m;
}

__global__ __launch_bounds__(512)
void relevance_kernel(const float* __restrict__ part, const int* __restrict__ idx_in,
                      const float* __restrict__ a1w, const float* __restrict__ a1b,
                      const float* __restrict__ a2w, const float* __restrict__ a2b,
                      float* __restrict__ finals)
{
    int b = blockIdx.x, t = threadIdx.x;
    float m = part[(b * 32) * NPROC + t];
#pragma unroll
    for (int sc = 1; sc < 32; ++sc) m = fmaxf(m, part[(b * 32 + sc) * NPROC + t]);
    __shared__ float rel1[512];
    __shared__ int sidx[KIN];
    if (t < KIN) sidx[t] = idx_in[b * KIN + t];
    __syncthreads();
    float r1 = a1b[t];
    const float* a1row = a1w + (long)t * NIN;
    for (int j = 0; j < KIN; ++j) r1 += a1row[sidx[j]];
    rel1[t] = gelu_f(r1);
    __syncthreads();
    float r = a2b[t];
    const float* a2row = a2w + (long)t * 512;
    for (int hh = 0; hh < 512; ++hh) r += rel1[hh] * a2row[hh];
    float sig = 1.f / (1.f + expf(-r));
    finals[b * NPROC + t] = m * sig;
}

// ---------------------------------------------------------------------------
extern "C" void kernel_launch(void* const* d_in, const int* in_sizes, int n_in,
                              void* d_out, int out_size, void* d_ws, size_t ws_size,
                              hipStream_t stream)
{
    const float* x       = (const float*)d_in[0];
    const float* r_in_w  = (const float*)d_in[1];
    const float* r_in_b  = (const float*)d_in[2];
    const float* r_out_w = (const float*)d_in[3];
    const float* r_out_b = (const float*)d_in[4];
    const float* aff_w   = (const float*)d_in[5];
    const float* aff_b   = (const float*)d_in[6];
    const float* patterns= (const float*)d_in[7];
    const float* i_in_w  = (const float*)d_in[8];
    const float* i_in_b  = (const float*)d_in[9];
    const float* i_out_w = (const float*)d_in[10];
    const float* i_out_b = (const float*)d_in[11];
    const float* ln_g    = (const float*)d_in[12];
    const float* ln_b    = (const float*)d_in[13];
    const float* comb_w  = (const float*)d_in[14];
    const float* out_proj_w = (const float*)d_in[15];
    const float* a1w     = (const float*)d_in[16];
    const float* a1b     = (const float*)d_in[17];
    const float* a2w     = (const float*)d_in[18];
    const float* a2b     = (const float*)d_in[19];
    float* out = (float*)d_out;

    char* ws = (char*)d_ws;
    unsigned short* qkv1b    = (unsigned short*)(ws + 0);
    unsigned short* contextb = (unsigned short*)(ws + 50331648);
    unsigned short* xb       = (unsigned short*)(ws + 67108864);
    unsigned short* w_rin_b  = (unsigned short*)(ws + 83886080);
    unsigned short* w_rout_b = (unsigned short*)(ws + 90177536);
    unsigned short* w_aff_b  = (unsigned short*)(ws + 92274688);
    unsigned short* patt_b   = (unsigned short*)(ws + 92798976);
    unsigned short* w_iin_b  = (unsigned short*)(ws + 93323264);
    unsigned short* w_iout_b = (unsigned short*)(ws + 93716480);
    float* w_sel   = (float*)(ws + 93855744);
    int*   idx_in  = (int*)(ws + 93859840);
    float* finals  = (float*)(ws + 93863936);
    int*   pidx    = (int*)(ws + 93880320);
    float* affin   = (float*)(ws + 94019584);
    float* acts0   = (float*)(ws + 102408192);
    unsigned short* acts0b = (unsigned short*)(ws + 110796800);
    unsigned short* qkv2b  = (unsigned short*)(ws + 114991104);
    float* attn2proj = (float*)(ws + 0);
    float* proc_acts = (float*)(ws + 16777216);
    unsigned short* sel_actsb = (unsigned short*)(ws + 33554432);
    unsigned short* sel_cwb   = (unsigned short*)(ws + 35651584);
    unsigned short* sel_procb = (unsigned short*)(ws + 36700160);
    unsigned short* sel_projT = (unsigned short*)(ws + 40894464);
    float* biascat  = (float*)(ws + 45088768);
    float* part_aff = (float*)(ws + 45091840);
    float* maxpart  = (float*)(ws + 45353984);

    // 0. all conversions + biascat init in one launch
    cvt_all_kernel<<<2048, 256, 0, stream>>>(
        x, r_in_w, r_out_w, aff_w, patterns, i_in_w, i_out_w, aff_b,
        xb, w_rin_b, w_rout_b, w_aff_b, patt_b, w_iin_b, w_iout_b, biascat);

    // 1. qkv1 = x @ r_in_w^T + b (128x128 BK=32 pipeline, 1536 blocks, 3/CU)
    gemm128s<<<1536, 256, 0, stream>>>(xb, ND, w_rin_b, ND, r_in_b, qkv1b, 3 * ND, ND, 24);
    // 2. MHA-1
    attn_mfma<128><<<dim3(8, 8, 8), 256, 0, stream>>>(qkv1b, 3 * ND, ND, 2 * ND, 0.088388347648318447f);
    // 3. context (512 blocks)
    gemm128s<<<512, 256, 0, stream>>>(qkv1b, 3 * ND, w_rout_b, ND, r_out_b, contextb, ND, ND, 8);
    // 4. fused affinity+patterns (split epilogue)
    gemm_bf16<<<dim3(4, 64, 1), 256, 0, stream>>>(
        contextb, 0, ND, w_aff_b, 0, ND, biascat, nullptr, 0, 0,
        affin, 0, NIN, acts0b, 0, NIN, acts0, NIN, NB * NS, 2 * NIN, ND, 2);
    // 5. routing
    maxpart_aff_kernel<<<dim3(32, NB), 256, 0, stream>>>(affin, part_aff);
    rank_input_kernel<<<NB, 256, 0, stream>>>(part_aff, idx_in, w_sel);
    // 6. qkv2 (384 blocks)
    gemm128s<<<384, 256, 0, stream>>>(acts0b, NIN, w_iin_b, NIN, i_in_b, qkv2b, 3 * NIN, NIN, 6);
    // 7. MHA-2
    attn_mfma<64><<<dim3(8, 4, 8), 256, 0, stream>>>(qkv2b, 3 * NIN, NIN, 2 * NIN, 0.125f);
    // 8. attn2 out-proj
    gemm_bf16<<<dim3(2, 64, 1), 256, 0, stream>>>(
        qkv2b, 0, 3 * NIN, w_iout_b, 0, NIN, i_out_b, nullptr, 0, 0,
        attn2proj, 0, NIN, nullptr, 0, 0, nullptr, 0, NB * NS, NIN, NIN, 0);
    // 9. LN + routed gather (fused)
    ln_gather_kernel<<<NB * NS, 256, 0, stream>>>(acts0, attn2proj, ln_g, ln_b,
                                                  idx_in, w_sel, sel_actsb);
    gather_sel_cw_b<<<2048, 256, 0, stream>>>(comb_w, idx_in, sel_cwb);
    // 10. proc_acts
    gemm_bf16<<<dim3(4, 8, NB), 256, 0, stream>>>(
        sel_actsb, (long)NS * KIN, KIN, sel_cwb, (long)NPROC * KIN, KIN,
        nullptr, nullptr, 0, 0,
        proc_acts, (long)NS * NPROC, NPROC, nullptr, 0, 0, nullptr, 0, NS, NPROC, KIN, 1);
    // 11. final scores + top-256
    maxpart_kernel<<<dim3(32, NB), 512, 0, stream>>>(proc_acts, maxpart);
    relevance_kernel<<<NB, 512, 0, stream>>>(maxpart, idx_in, a1w, a1b, a2w, a2b, finals);
    rank_proc_kernel<<<NB, 512, 0, stream>>>(finals, pidx);
    // 12. output gathers + GEMM + residual
    gather_sel_proc_b<<<dim3(NS, NB), KPROC, 0, stream>>>(proc_acts, pidx, sel_procb);
    gather_sel_projT<<<1024, 256, 0, stream>>>(out_proj_w, pidx, sel_projT);
    gemm_bf16<<<dim3(8, 8, NB), 256, 0, stream>>>(
        sel_procb, (long)NS * KPROC, KPROC, sel_projT, (long)ND * KPROC, KPROC,
        nullptr, x, (long)NS * ND, ND,
        out, (long)NS * ND, ND, nullptr, 0, 0, nullptr, 0, NS, ND, KPROC, 0);
    (void)in_sizes; (void)n_in; (void)out_size; (void)ws_size;
}